// Round 1
// baseline (2290.572 us; speedup 1.0000x reference)
//
#include <hip/hip_runtime.h>
#include <hip/hip_bf16.h>
#include <math.h>

#define NN 10000
#define NE 160000
#define HH 128
#define EPSBN 1e-5f

static constexpr int BM = 64, BN = 128, BK = 32, TM = 8, TN = 4, NT = 256;

__device__ __forceinline__ float silu_f(float x) { return x / (1.f + __expf(-x)); }
__device__ __forceinline__ float elu_f(float x)  { return x > 0.f ? x : expm1f(x); }

// ---------------- utility ----------------
__global__ void k_zero(float* __restrict__ p, int n) {
    int i = blockIdx.x * blockDim.x + threadIdx.x;
    if (i < n) p[i] = 0.f;
}

__global__ void k_copy(const float* __restrict__ a, float* __restrict__ b, int n) {
    int i = blockIdx.x * blockDim.x + threadIdx.x;
    if (i < n) b[i] = a[i];
}

// V = emb_nodes @ pre_Wn + pre_bn   (K=3)
__global__ void k_vinit(const float* __restrict__ en, const float* __restrict__ Wn,
                        const float* __restrict__ bn, float* __restrict__ V) {
    int idx = blockIdx.x * blockDim.x + threadIdx.x;
    if (idx >= NN * HH) return;
    int i = idx >> 7, j = idx & 127;
    float v = fmaf(en[i * 3 + 0], Wn[j], bn[j]);
    v = fmaf(en[i * 3 + 1], Wn[HH + j], v);
    v = fmaf(en[i * 3 + 2], Wn[2 * HH + j], v);
    V[idx] = v;
}

// diff = coords[dst]-coords[src]; dist = |diff|  -> float4(dx,dy,dz,dist)
__global__ void k_eprep(const float* __restrict__ coords, const int* __restrict__ src,
                        const int* __restrict__ dst, float4* __restrict__ diff4) {
    int e = blockIdx.x * blockDim.x + threadIdx.x;
    if (e >= NE) return;
    int s = src[e], d = dst[e];
    float dx = coords[d * 3 + 0] - coords[s * 3 + 0];
    float dy = coords[d * 3 + 1] - coords[s * 3 + 1];
    float dz = coords[d * 3 + 2] - coords[s * 3 + 2];
    float dist = sqrtf(dx * dx + dy * dy + dz * dz);
    diff4[e] = make_float4(dx, dy, dz, dist);
}

// ---------------- edge GEMM 1: t1 = silu([V[src],V[dst],dist,ee] @ We1 + be1) ----------------
__global__ __launch_bounds__(256)
void k_egemm1(const float* __restrict__ V, const int* __restrict__ src, const int* __restrict__ dst,
              const float4* __restrict__ diff4, const float* __restrict__ ee,
              const float* __restrict__ W, const float* __restrict__ bias,
              float* __restrict__ t1) {
    __shared__ float As[BK][BM + 4];
    __shared__ float Ws[BK][BN];
    __shared__ int sid[BM], did[BM];
    __shared__ float dd[BM], eA[BM], eB[BM];
    const int t = threadIdx.x;
    const int e0 = blockIdx.x * BM;
    if (t < BM) {
        int e = e0 + t;
        sid[t] = src[e];
        did[t] = dst[e];
        float4 q = diff4[e];
        dd[t] = q.w;
        eA[t] = ee[2 * e];
        eB[t] = ee[2 * e + 1];
    }
    __syncthreads();
    const int rg = t >> 5, cg = t & 31;
    float acc[TM][TN];
#pragma unroll
    for (int i = 0; i < TM; ++i)
#pragma unroll
        for (int j = 0; j < TN; ++j) acc[i][j] = 0.f;

    for (int ph = 0; ph < 2; ++ph) {
        const int* ids = ph ? did : sid;
        const int wbase = ph * HH;
        for (int kt = 0; kt < HH / BK; ++kt) {
            int k0 = kt * BK;
#pragma unroll
            for (int i = 0; i < (BM * BK) / NT; ++i) {
                int idx = t + i * NT;
                int m = idx >> 5, k = idx & 31;
                As[k][m] = V[ids[m] * HH + k0 + k];
            }
#pragma unroll
            for (int i = 0; i < (BK * BN) / NT; ++i) {
                int idx = t + i * NT;
                int k = idx >> 7, n = idx & 127;
                Ws[k][n] = W[(wbase + k0 + k) * BN + n];
            }
            __syncthreads();
#pragma unroll
            for (int k = 0; k < BK; ++k) {
                float4 a0 = *(const float4*)&As[k][rg * TM];
                float4 a1 = *(const float4*)&As[k][rg * TM + 4];
                float4 wv = *(const float4*)&Ws[k][cg * TN];
                float av[TM] = {a0.x, a0.y, a0.z, a0.w, a1.x, a1.y, a1.z, a1.w};
                float wj[TN] = {wv.x, wv.y, wv.z, wv.w};
#pragma unroll
                for (int i = 0; i < TM; ++i)
#pragma unroll
                    for (int j = 0; j < TN; ++j)
                        acc[i][j] = fmaf(av[i], wj[j], acc[i][j]);
            }
            __syncthreads();
        }
    }
    const int c0 = cg * TN;
    float w256[TN], w257[TN], w258[TN], bi[TN];
#pragma unroll
    for (int j = 0; j < TN; ++j) {
        w256[j] = W[256 * BN + c0 + j];
        w257[j] = W[257 * BN + c0 + j];
        w258[j] = W[258 * BN + c0 + j];
        bi[j]   = bias[c0 + j];
    }
#pragma unroll
    for (int i = 0; i < TM; ++i) {
        int m = rg * TM + i;
        float d = dd[m], ea = eA[m], eb = eB[m];
        float4 o;
        float* op = &o.x;
#pragma unroll
        for (int j = 0; j < TN; ++j) {
            float v = acc[i][j] + bi[j];
            v = fmaf(d, w256[j], v);
            v = fmaf(ea, w257[j], v);
            v = fmaf(eb, w258[j], v);
            op[j] = silu_f(v);
        }
        *(float4*)&t1[(size_t)(e0 + m) * HH + c0] = o;
    }
}

// ---------------- edge GEMM 2: mij = silu(t1 @ We2 + be2); atomic mi[dst] += mij ----------------
__global__ __launch_bounds__(256)
void k_egemm2(const float* __restrict__ A, const int* __restrict__ dst,
              const float* __restrict__ W, const float* __restrict__ bias,
              float* __restrict__ out, float* __restrict__ mi) {
    __shared__ float As[BK][BM + 4];
    __shared__ float Ws[BK][BN];
    __shared__ int did[BM];
    const int t = threadIdx.x;
    const int e0 = blockIdx.x * BM;
    if (t < BM) did[t] = dst[e0 + t];
    const int rg = t >> 5, cg = t & 31;
    float acc[TM][TN];
#pragma unroll
    for (int i = 0; i < TM; ++i)
#pragma unroll
        for (int j = 0; j < TN; ++j) acc[i][j] = 0.f;

    for (int kt = 0; kt < HH / BK; ++kt) {
        int k0 = kt * BK;
#pragma unroll
        for (int i = 0; i < (BM * BK) / NT; ++i) {
            int idx = t + i * NT;
            int m = idx >> 5, k = idx & 31;
            As[k][m] = A[(size_t)(e0 + m) * HH + k0 + k];
        }
#pragma unroll
        for (int i = 0; i < (BK * BN) / NT; ++i) {
            int idx = t + i * NT;
            int k = idx >> 7, n = idx & 127;
            Ws[k][n] = W[(k0 + k) * BN + n];
        }
        __syncthreads();
#pragma unroll
        for (int k = 0; k < BK; ++k) {
            float4 a0 = *(const float4*)&As[k][rg * TM];
            float4 a1 = *(const float4*)&As[k][rg * TM + 4];
            float4 wv = *(const float4*)&Ws[k][cg * TN];
            float av[TM] = {a0.x, a0.y, a0.z, a0.w, a1.x, a1.y, a1.z, a1.w};
            float wj[TN] = {wv.x, wv.y, wv.z, wv.w};
#pragma unroll
            for (int i = 0; i < TM; ++i)
#pragma unroll
                for (int j = 0; j < TN; ++j)
                    acc[i][j] = fmaf(av[i], wj[j], acc[i][j]);
        }
        __syncthreads();
    }
    const int c0 = cg * TN;
    float bi[TN];
#pragma unroll
    for (int j = 0; j < TN; ++j) bi[j] = bias[c0 + j];
#pragma unroll
    for (int i = 0; i < TM; ++i) {
        int m = rg * TM + i;
        int d = did[m];
        float4 o;
        float* op = &o.x;
#pragma unroll
        for (int j = 0; j < TN; ++j) {
            float v = silu_f(acc[i][j] + bi[j]);
            op[j] = v;
        }
        *(float4*)&out[(size_t)(e0 + m) * HH + c0] = o;
#pragma unroll
        for (int j = 0; j < TN; ++j)
            atomicAdd(&mi[d * HH + c0 + j], op[j]);
    }
}

// ---------------- edge GEMM 3: t2 = silu(mij @ Wx1 + bx1) (LDS only); px = t2 @ Wx2 + bx2;
//                  atomic coord_acc[dst] += diff * px ----------------
__global__ __launch_bounds__(256)
void k_egemm3(const float* __restrict__ A, const int* __restrict__ dst,
              const float4* __restrict__ diff4,
              const float* __restrict__ W, const float* __restrict__ bias,
              const float* __restrict__ W2, const float* __restrict__ b2,
              float* __restrict__ coord_acc) {
    __shared__ float As[BK][BM + 4];
    __shared__ float Ws[BK][BN];
    __shared__ float Ts[BM][BN + 5];   // pad 133 (odd-ish stride; px reads conflict-free)
    __shared__ float d3[3][BM];
    __shared__ float Wxs[HH * 3];
    __shared__ float b2s[3];
    __shared__ int did[BM];
    const int t = threadIdx.x;
    const int e0 = blockIdx.x * BM;
    if (t < BM) {
        did[t] = dst[e0 + t];
        float4 q = diff4[e0 + t];
        d3[0][t] = q.x; d3[1][t] = q.y; d3[2][t] = q.z;
    }
    for (int i = t; i < HH * 3; i += NT) Wxs[i] = W2[i];
    if (t < 3) b2s[t] = b2[t];
    const int rg = t >> 5, cg = t & 31;
    float acc[TM][TN];
#pragma unroll
    for (int i = 0; i < TM; ++i)
#pragma unroll
        for (int j = 0; j < TN; ++j) acc[i][j] = 0.f;

    for (int kt = 0; kt < HH / BK; ++kt) {
        int k0 = kt * BK;
#pragma unroll
        for (int i = 0; i < (BM * BK) / NT; ++i) {
            int idx = t + i * NT;
            int m = idx >> 5, k = idx & 31;
            As[k][m] = A[(size_t)(e0 + m) * HH + k0 + k];
        }
#pragma unroll
        for (int i = 0; i < (BK * BN) / NT; ++i) {
            int idx = t + i * NT;
            int k = idx >> 7, n = idx & 127;
            Ws[k][n] = W[(k0 + k) * BN + n];
        }
        __syncthreads();
#pragma unroll
        for (int k = 0; k < BK; ++k) {
            float4 a0 = *(const float4*)&As[k][rg * TM];
            float4 a1 = *(const float4*)&As[k][rg * TM + 4];
            float4 wv = *(const float4*)&Ws[k][cg * TN];
            float av[TM] = {a0.x, a0.y, a0.z, a0.w, a1.x, a1.y, a1.z, a1.w};
            float wj[TN] = {wv.x, wv.y, wv.z, wv.w};
#pragma unroll
            for (int i = 0; i < TM; ++i)
#pragma unroll
                for (int j = 0; j < TN; ++j)
                    acc[i][j] = fmaf(av[i], wj[j], acc[i][j]);
        }
        __syncthreads();
    }
    const int c0 = cg * TN;
#pragma unroll
    for (int i = 0; i < TM; ++i) {
        int m = rg * TM + i;
#pragma unroll
        for (int j = 0; j < TN; ++j)
            Ts[m][c0 + j] = silu_f(acc[i][j] + bias[c0 + j]);
    }
    __syncthreads();
    if (t < 192) {
        int r = t / 3;
        int col = t - 3 * r;
        float s = b2s[col];
#pragma unroll 16
        for (int k = 0; k < HH; ++k)
            s = fmaf(Ts[r][k], Wxs[k * 3 + col], s);
        atomicAdd(&coord_acc[did[r] * 3 + col], d3[col][r] * s);
    }
}

// ---------------- coords += acc/(N-1) ----------------
__global__ void k_coordupd(float* __restrict__ coords, const float* __restrict__ acc) {
    int i = blockIdx.x * blockDim.x + threadIdx.x;
    if (i < NN * 3) coords[i] += acc[i] * (1.f / (NN - 1));
}

// ---------------- node GEMM 1: u = silu([V,mi] @ Wh1 + bh1) ----------------
__global__ __launch_bounds__(256)
void k_ngemm1(const float* __restrict__ V, const float* __restrict__ mi,
              const float* __restrict__ W, const float* __restrict__ bias,
              float* __restrict__ u) {
    __shared__ float As[BK][BM + 4];
    __shared__ float Ws[BK][BN];
    const int t = threadIdx.x;
    const int r0 = blockIdx.x * BM;
    const int rg = t >> 5, cg = t & 31;
    float acc[TM][TN];
#pragma unroll
    for (int i = 0; i < TM; ++i)
#pragma unroll
        for (int j = 0; j < TN; ++j) acc[i][j] = 0.f;

    for (int ph = 0; ph < 2; ++ph) {
        const float* Ap = ph ? mi : V;
        const int wb = ph * HH;
        for (int kt = 0; kt < HH / BK; ++kt) {
            int k0 = kt * BK;
#pragma unroll
            for (int i = 0; i < (BM * BK) / NT; ++i) {
                int idx = t + i * NT;
                int m = idx >> 5, k = idx & 31;
                int row = r0 + m; if (row >= NN) row = NN - 1;
                As[k][m] = Ap[row * HH + k0 + k];
            }
#pragma unroll
            for (int i = 0; i < (BK * BN) / NT; ++i) {
                int idx = t + i * NT;
                int k = idx >> 7, n = idx & 127;
                Ws[k][n] = W[(wb + k0 + k) * BN + n];
            }
            __syncthreads();
#pragma unroll
            for (int k = 0; k < BK; ++k) {
                float4 a0 = *(const float4*)&As[k][rg * TM];
                float4 a1 = *(const float4*)&As[k][rg * TM + 4];
                float4 wv = *(const float4*)&Ws[k][cg * TN];
                float av[TM] = {a0.x, a0.y, a0.z, a0.w, a1.x, a1.y, a1.z, a1.w};
                float wj[TN] = {wv.x, wv.y, wv.z, wv.w};
#pragma unroll
                for (int i = 0; i < TM; ++i)
#pragma unroll
                    for (int j = 0; j < TN; ++j)
                        acc[i][j] = fmaf(av[i], wj[j], acc[i][j]);
            }
            __syncthreads();
        }
    }
    const int c0 = cg * TN;
#pragma unroll
    for (int i = 0; i < TM; ++i) {
        int row = r0 + rg * TM + i;
        if (row < NN) {
            float4 o;
            float* op = &o.x;
#pragma unroll
            for (int j = 0; j < TN; ++j)
                op[j] = silu_f(acc[i][j] + bias[c0 + j]);
            *(float4*)&u[(size_t)row * HH + c0] = o;
        }
    }
}

// ---------------- node GEMM 2: X = elu(u @ Wh2 + bh2); column stats ----------------
__global__ __launch_bounds__(256)
void k_ngemm2(const float* __restrict__ A, const float* __restrict__ W,
              const float* __restrict__ bias, float* __restrict__ X,
              float* __restrict__ ssum, float* __restrict__ ssq) {
    __shared__ float As[BK][BM + 4];
    __shared__ float Ws[BK][BN];
    const int t = threadIdx.x;
    const int r0 = blockIdx.x * BM;
    const int rg = t >> 5, cg = t & 31;
    float acc[TM][TN];
#pragma unroll
    for (int i = 0; i < TM; ++i)
#pragma unroll
        for (int j = 0; j < TN; ++j) acc[i][j] = 0.f;

    for (int kt = 0; kt < HH / BK; ++kt) {
        int k0 = kt * BK;
#pragma unroll
        for (int i = 0; i < (BM * BK) / NT; ++i) {
            int idx = t + i * NT;
            int m = idx >> 5, k = idx & 31;
            int row = r0 + m; if (row >= NN) row = NN - 1;
            As[k][m] = A[row * HH + k0 + k];
        }
#pragma unroll
        for (int i = 0; i < (BK * BN) / NT; ++i) {
            int idx = t + i * NT;
            int k = idx >> 7, n = idx & 127;
            Ws[k][n] = W[(k0 + k) * BN + n];
        }
        __syncthreads();
#pragma unroll
        for (int k = 0; k < BK; ++k) {
            float4 a0 = *(const float4*)&As[k][rg * TM];
            float4 a1 = *(const float4*)&As[k][rg * TM + 4];
            float4 wv = *(const float4*)&Ws[k][cg * TN];
            float av[TM] = {a0.x, a0.y, a0.z, a0.w, a1.x, a1.y, a1.z, a1.w};
            float wj[TN] = {wv.x, wv.y, wv.z, wv.w};
#pragma unroll
            for (int i = 0; i < TM; ++i)
#pragma unroll
                for (int j = 0; j < TN; ++j)
                    acc[i][j] = fmaf(av[i], wj[j], acc[i][j]);
        }
        __syncthreads();
    }
    const int c0 = cg * TN;
    float bi[TN];
#pragma unroll
    for (int j = 0; j < TN; ++j) bi[j] = bias[c0 + j];
    float s[TN], q[TN];
#pragma unroll
    for (int j = 0; j < TN; ++j) { s[j] = 0.f; q[j] = 0.f; }
#pragma unroll
    for (int i = 0; i < TM; ++i) {
        int row = r0 + rg * TM + i;
        float4 o;
        float* op = &o.x;
#pragma unroll
        for (int j = 0; j < TN; ++j)
            op[j] = elu_f(acc[i][j] + bi[j]);
        if (row < NN) {
            *(float4*)&X[(size_t)row * HH + c0] = o;
#pragma unroll
            for (int j = 0; j < TN; ++j) { s[j] += op[j]; q[j] += op[j] * op[j]; }
        }
    }
#pragma unroll
    for (int j = 0; j < TN; ++j) {
        s[j] += __shfl_down(s[j], 32);
        q[j] += __shfl_down(q[j], 32);
    }
    if ((t & 63) < 32) {
#pragma unroll
        for (int j = 0; j < TN; ++j) {
            atomicAdd(&ssum[c0 + j], s[j]);
            atomicAdd(&ssq[c0 + j], q[j]);
        }
    }
}

// ---------------- node batchnorm apply ----------------
__global__ void k_bnorm_nodes(const float* __restrict__ X, const float* __restrict__ ssum,
                              const float* __restrict__ ssq, const float* __restrict__ gam,
                              const float* __restrict__ bet, float* __restrict__ out) {
    int idx = blockIdx.x * blockDim.x + threadIdx.x;
    if (idx >= NN * HH) return;
    int c = idx & 127;
    float mu = ssum[c] * (1.f / NN);
    float var = ssq[c] * (1.f / NN) - mu * mu;
    out[idx] = fmaf(gam[c] * (X[idx] - mu), rsqrtf(var + EPSBN), bet[c]);
}

// ---------------- edge stats over elu(mij) (last layer only) ----------------
__global__ __launch_bounds__(256)
void k_estats(const float* __restrict__ mij, float* __restrict__ ssum, float* __restrict__ ssq) {
    const int t = threadIdx.x;
    const int col = t & 127;
    const int half = t >> 7;
    const int rbase = blockIdx.x * 250;
    float s = 0.f, q = 0.f;
    for (int r = rbase + half; r < rbase + 250; r += 2) {
        float x = elu_f(mij[(size_t)r * HH + col]);
        s += x; q += x * x;
    }
    atomicAdd(&ssum[col], s);
    atomicAdd(&ssq[col], q);
}

// ---------------- edge batchnorm apply -> output E ----------------
__global__ void k_bnorm_edges(const float* __restrict__ mij, const float* __restrict__ ssum,
                              const float* __restrict__ ssq, const float* __restrict__ gam,
                              const float* __restrict__ bet, float* __restrict__ out) {
    size_t stride = (size_t)gridDim.x * blockDim.x;
    for (size_t idx = (size_t)blockIdx.x * blockDim.x + threadIdx.x; idx < (size_t)NE * HH; idx += stride) {
        int c = (int)(idx & 127);
        float x = elu_f(mij[idx]);
        float mu = ssum[c] * (1.f / NE);
        float var = ssq[c] * (1.f / NE) - mu * mu;
        out[idx] = fmaf(gam[c] * (x - mu), rsqrtf(var + EPSBN), bet[c]);
    }
}

extern "C" void kernel_launch(void* const* d_in, const int* in_sizes, int n_in,
                              void* d_out, int out_size, void* d_ws, size_t ws_size,
                              hipStream_t stream) {
    (void)in_sizes; (void)n_in; (void)out_size; (void)ws_size;
    const float* emb_nodes = (const float*)d_in[0];
    const float* emb_edges = (const float*)d_in[1];
    const int*   eidx      = (const int*)d_in[2];
    const float* pre_Wn = (const float*)d_in[3];
    const float* pre_bn = (const float*)d_in[4];
    const float* We1 = (const float*)d_in[7];
    const float* be1 = (const float*)d_in[8];
    const float* We2 = (const float*)d_in[9];
    const float* be2 = (const float*)d_in[10];
    const float* Wx1 = (const float*)d_in[11];
    const float* bx1 = (const float*)d_in[12];
    const float* Wx2 = (const float*)d_in[13];
    const float* bx2 = (const float*)d_in[14];
    const float* Wh1 = (const float*)d_in[15];
    const float* bh1 = (const float*)d_in[16];
    const float* Wh2 = (const float*)d_in[17];
    const float* bh2 = (const float*)d_in[18];
    const float* gam_n = (const float*)d_in[19];
    const float* bet_n = (const float*)d_in[20];
    const float* gam_e = (const float*)d_in[21];
    const float* bet_e = (const float*)d_in[22];

    const int* src = eidx;
    const int* dst = eidx + NE;

    float* ws = (float*)d_ws;
    float*  coords = ws;                       // 30000
    float4* diff4  = (float4*)(ws + 30000);    // 640000 floats
    float*  V      = ws + 670000;              // 1280000
    float*  mi     = ws + 1950000;             // 1280000  <- zero zone start
    float*  cacc   = ws + 3230000;             // 30000
    float*  snN    = ws + 3260000;             // 128
    float*  sqN    = ws + 3260128;             // 128
    float*  snE    = ws + 3260256;             // 128
    float*  sqE    = ws + 3260384;             // 128    <- zero zone end (1310512 floats)
    float*  u      = ws + 3260512;             // 1280000
    float*  X      = ws + 4540512;             // 1280000
    float*  t1     = ws + 5820512;             // 20480000
    float*  mij    = ws + 26300512;            // 20480000

    float* outV = (float*)d_out;
    float* outE = (float*)d_out + (size_t)NN * HH;

    k_copy<<<(30000 + 255) / 256, 256, 0, stream>>>(emb_nodes, coords, 30000);
    k_vinit<<<(NN * HH + 255) / 256, 256, 0, stream>>>(emb_nodes, pre_Wn, pre_bn, V);

    for (int l = 0; l < 3; ++l) {
        const float* We1l = We1 + (size_t)l * 259 * 128;
        const float* be1l = be1 + l * 128;
        const float* We2l = We2 + (size_t)l * 128 * 128;
        const float* be2l = be2 + l * 128;
        const float* Wx1l = Wx1 + (size_t)l * 128 * 128;
        const float* bx1l = bx1 + l * 128;
        const float* Wx2l = Wx2 + (size_t)l * 128 * 3;
        const float* bx2l = bx2 + l * 3;
        const float* Wh1l = Wh1 + (size_t)l * 256 * 128;
        const float* bh1l = bh1 + l * 128;
        const float* Wh2l = Wh2 + (size_t)l * 128 * 128;
        const float* bh2l = bh2 + l * 128;

        k_zero<<<(1310512 + 255) / 256, 256, 0, stream>>>(mi, 1310512);
        k_eprep<<<(NE + 255) / 256, 256, 0, stream>>>(coords, src, dst, diff4);
        k_egemm1<<<NE / BM, NT, 0, stream>>>(V, src, dst, diff4, emb_edges, We1l, be1l, t1);
        k_egemm2<<<NE / BM, NT, 0, stream>>>(t1, dst, We2l, be2l, mij, mi);
        k_egemm3<<<NE / BM, NT, 0, stream>>>(mij, dst, diff4, Wx1l, bx1l, Wx2l, bx2l, cacc);
        k_coordupd<<<(NN * 3 + 255) / 256, 256, 0, stream>>>(coords, cacc);
        k_ngemm1<<<(NN + BM - 1) / BM, NT, 0, stream>>>(V, mi, Wh1l, bh1l, u);
        k_ngemm2<<<(NN + BM - 1) / BM, NT, 0, stream>>>(u, Wh2l, bh2l, X, snN, sqN);
        k_bnorm_nodes<<<(NN * HH + 255) / 256, 256, 0, stream>>>(X, snN, sqN, gam_n + l * 128, bet_n + l * 128,
                                                                 (l < 2) ? V : outV);
        if (l == 2) {
            k_estats<<<640, 256, 0, stream>>>(mij, snE, sqE);
            k_bnorm_edges<<<4096, 256, 0, stream>>>(mij, snE, sqE, gam_e + l * 128, bet_e + l * 128, outE);
        }
    }
}

// Round 2
// 2024.628 us; speedup vs baseline: 1.1314x; 1.1314x over previous
//
#include <hip/hip_runtime.h>
#include <hip/hip_bf16.h>
#include <math.h>

#define NN 10000
#define NE 160000
#define HH 128
#define EPSBN 1e-5f

static constexpr int NT = 256;

__device__ __forceinline__ float silu_f(float x) { return x / (1.f + __expf(-x)); }
__device__ __forceinline__ float elu_f(float x)  { return x > 0.f ? x : expm1f(x); }

// ---------------- utility ----------------
__global__ void k_zero(float* __restrict__ p, int n) {
    int i = blockIdx.x * blockDim.x + threadIdx.x;
    if (i < n) p[i] = 0.f;
}

__global__ void k_zero_int(int* __restrict__ p, int n) {
    int i = blockIdx.x * blockDim.x + threadIdx.x;
    if (i < n) p[i] = 0;
}

__global__ void k_copy(const float* __restrict__ a, float* __restrict__ b, int n) {
    int i = blockIdx.x * blockDim.x + threadIdx.x;
    if (i < n) b[i] = a[i];
}

// V = emb_nodes @ pre_Wn + pre_bn   (K=3)
__global__ void k_vinit(const float* __restrict__ en, const float* __restrict__ Wn,
                        const float* __restrict__ bn, float* __restrict__ V) {
    int idx = blockIdx.x * blockDim.x + threadIdx.x;
    if (idx >= NN * HH) return;
    int i = idx >> 7, j = idx & 127;
    float v = fmaf(en[i * 3 + 0], Wn[j], bn[j]);
    v = fmaf(en[i * 3 + 1], Wn[HH + j], v);
    v = fmaf(en[i * 3 + 2], Wn[2 * HH + j], v);
    V[idx] = v;
}

// ---------------- CSR build (per call; edges are fixed across layers) ----------------
__global__ void k_hist(const int* __restrict__ dst, int* __restrict__ deg) {
    int e = blockIdx.x * blockDim.x + threadIdx.x;
    if (e < NE) atomicAdd(&deg[dst[e]], 1);
}

__global__ __launch_bounds__(256)
void k_scan(const int* __restrict__ deg, int* __restrict__ offs, int* __restrict__ cur) {
    __shared__ int part[256];
    const int t = threadIdx.x;
    const int s0 = t * 40, s1 = min(s0 + 40, NN);
    int s = 0;
    for (int i = s0; i < s1; ++i) s += deg[i];
    part[t] = s;
    __syncthreads();
    if (t == 0) {
        int r = 0;
        for (int i = 0; i < 256; ++i) { int v = part[i]; part[i] = r; r += v; }
    }
    __syncthreads();
    int r = part[t];
    for (int i = s0; i < s1; ++i) { offs[i] = r; cur[i] = r; r += deg[i]; }
    if (t == 255) offs[NN] = r;
}

__global__ void k_fill(const int* __restrict__ dst, int* __restrict__ cur, int* __restrict__ eid) {
    int e = blockIdx.x * blockDim.x + threadIdx.x;
    if (e < NE) {
        int p = atomicAdd(&cur[dst[e]], 1);
        eid[p] = e;
    }
}

// diff = coords[dst]-coords[src]; dist = |diff|  -> float4(dx,dy,dz,dist)
__global__ void k_eprep(const float* __restrict__ coords, const int* __restrict__ src,
                        const int* __restrict__ dst, float4* __restrict__ diff4) {
    int e = blockIdx.x * blockDim.x + threadIdx.x;
    if (e >= NE) return;
    int s = src[e], d = dst[e];
    float dx = coords[d * 3 + 0] - coords[s * 3 + 0];
    float dy = coords[d * 3 + 1] - coords[s * 3 + 1];
    float dz = coords[d * 3 + 2] - coords[s * 3 + 2];
    float dist = sqrtf(dx * dx + dy * dy + dz * dz);
    diff4[e] = make_float4(dx, dy, dz, dist);
}

// ============ 128x128 fp32 tile, TM=8 x TN=8, 256 threads ============
// rg = t>>4 (16 row groups x 8 rows), cg = t&15 (16 col groups x 8 cols)

// ---------------- edge GEMM 1: t1 = silu([V[src],V[dst],dist,ee] @ We1 + be1) ----------------
__global__ __launch_bounds__(256)
void k_egemm1(const float* __restrict__ V, const int* __restrict__ src, const int* __restrict__ dst,
              const float4* __restrict__ diff4, const float* __restrict__ ee,
              const float* __restrict__ W, const float* __restrict__ bias,
              float* __restrict__ t1) {
    __shared__ float As[32][132];
    __shared__ float Ws[32][128];
    __shared__ int sid[128], did[128];
    __shared__ float dd[128], eA[128], eB[128];
    const int t = threadIdx.x;
    const int e0 = blockIdx.x * 128;
    if (t < 128) {
        int e = e0 + t;
        sid[t] = src[e];
        did[t] = dst[e];
        float4 q = diff4[e];
        dd[t] = q.w;
        eA[t] = ee[2 * e];
        eB[t] = ee[2 * e + 1];
    }
    __syncthreads();
    const int rg = t >> 4, cg = t & 15;
    float acc[8][8];
#pragma unroll
    for (int i = 0; i < 8; ++i)
#pragma unroll
        for (int j = 0; j < 8; ++j) acc[i][j] = 0.f;

    for (int ph = 0; ph < 2; ++ph) {
        const int* ids = ph ? did : sid;
        const int wbase = ph * HH;
        for (int kt = 0; kt < 4; ++kt) {
            int k0 = kt * 32;
#pragma unroll
            for (int i = 0; i < 16; ++i) {
                int idx = t + i * NT;
                int m = idx >> 5, k = idx & 31;
                As[k][m] = V[(size_t)ids[m] * HH + k0 + k];
            }
#pragma unroll
            for (int i = 0; i < 16; ++i) {
                int idx = t + i * NT;
                int k = idx >> 7, n = idx & 127;
                Ws[k][n] = W[(size_t)(wbase + k0 + k) * HH + n];
            }
            __syncthreads();
#pragma unroll
            for (int k = 0; k < 32; ++k) {
                float4 a0 = *(const float4*)&As[k][rg * 8];
                float4 a1 = *(const float4*)&As[k][rg * 8 + 4];
                float4 w0 = *(const float4*)&Ws[k][cg * 8];
                float4 w1 = *(const float4*)&Ws[k][cg * 8 + 4];
                float av[8] = {a0.x, a0.y, a0.z, a0.w, a1.x, a1.y, a1.z, a1.w};
                float wj[8] = {w0.x, w0.y, w0.z, w0.w, w1.x, w1.y, w1.z, w1.w};
#pragma unroll
                for (int i = 0; i < 8; ++i)
#pragma unroll
                    for (int j = 0; j < 8; ++j)
                        acc[i][j] = fmaf(av[i], wj[j], acc[i][j]);
            }
            __syncthreads();
        }
    }
    const int c0 = cg * 8;
    float w256[8], w257[8], w258[8], bi[8];
#pragma unroll
    for (int j = 0; j < 8; ++j) {
        w256[j] = W[256 * HH + c0 + j];
        w257[j] = W[257 * HH + c0 + j];
        w258[j] = W[258 * HH + c0 + j];
        bi[j]   = bias[c0 + j];
    }
#pragma unroll
    for (int i = 0; i < 8; ++i) {
        int m = rg * 8 + i;
        float d = dd[m], ea = eA[m], eb = eB[m];
        float o[8];
#pragma unroll
        for (int j = 0; j < 8; ++j) {
            float v = acc[i][j] + bi[j];
            v = fmaf(d, w256[j], v);
            v = fmaf(ea, w257[j], v);
            v = fmaf(eb, w258[j], v);
            o[j] = silu_f(v);
        }
        float* dstp = &t1[(size_t)(e0 + m) * HH + c0];
        *(float4*)dstp       = make_float4(o[0], o[1], o[2], o[3]);
        *(float4*)(dstp + 4) = make_float4(o[4], o[5], o[6], o[7]);
    }
}

// ---------------- edge GEMM 2: mij = silu(t1 @ We2 + be2) (pure GEMM) ----------------
__global__ __launch_bounds__(256)
void k_egemm2(const float* __restrict__ A, const float* __restrict__ W,
              const float* __restrict__ bias, float* __restrict__ out) {
    __shared__ float As[32][132];
    __shared__ float Ws[32][128];
    const int t = threadIdx.x;
    const int e0 = blockIdx.x * 128;
    const int rg = t >> 4, cg = t & 15;
    float acc[8][8];
#pragma unroll
    for (int i = 0; i < 8; ++i)
#pragma unroll
        for (int j = 0; j < 8; ++j) acc[i][j] = 0.f;

    for (int kt = 0; kt < 4; ++kt) {
        int k0 = kt * 32;
#pragma unroll
        for (int i = 0; i < 16; ++i) {
            int idx = t + i * NT;
            int m = idx >> 5, k = idx & 31;
            As[k][m] = A[(size_t)(e0 + m) * HH + k0 + k];
        }
#pragma unroll
        for (int i = 0; i < 16; ++i) {
            int idx = t + i * NT;
            int k = idx >> 7, n = idx & 127;
            Ws[k][n] = W[(size_t)(k0 + k) * HH + n];
        }
        __syncthreads();
#pragma unroll
        for (int k = 0; k < 32; ++k) {
            float4 a0 = *(const float4*)&As[k][rg * 8];
            float4 a1 = *(const float4*)&As[k][rg * 8 + 4];
            float4 w0 = *(const float4*)&Ws[k][cg * 8];
            float4 w1 = *(const float4*)&Ws[k][cg * 8 + 4];
            float av[8] = {a0.x, a0.y, a0.z, a0.w, a1.x, a1.y, a1.z, a1.w};
            float wj[8] = {w0.x, w0.y, w0.z, w0.w, w1.x, w1.y, w1.z, w1.w};
#pragma unroll
            for (int i = 0; i < 8; ++i)
#pragma unroll
                for (int j = 0; j < 8; ++j)
                    acc[i][j] = fmaf(av[i], wj[j], acc[i][j]);
        }
        __syncthreads();
    }
    const int c0 = cg * 8;
    float bi[8];
#pragma unroll
    for (int j = 0; j < 8; ++j) bi[j] = bias[c0 + j];
#pragma unroll
    for (int i = 0; i < 8; ++i) {
        int m = rg * 8 + i;
        float o[8];
#pragma unroll
        for (int j = 0; j < 8; ++j) o[j] = silu_f(acc[i][j] + bi[j]);
        float* dstp = &out[(size_t)(e0 + m) * HH + c0];
        *(float4*)dstp       = make_float4(o[0], o[1], o[2], o[3]);
        *(float4*)(dstp + 4) = make_float4(o[4], o[5], o[6], o[7]);
    }
}

// ---------------- mi = segment_sum(mij, dst) via CSR gather ----------------
__global__ __launch_bounds__(128)
void k_mi(const float* __restrict__ mij, const int* __restrict__ offs,
          const int* __restrict__ eid, float* __restrict__ mi) {
    const int n = blockIdx.x;
    const int t = threadIdx.x;   // 128 threads = one column each
    const int b = offs[n], e = offs[n + 1];
    float s = 0.f;
    for (int j = b; j < e; ++j)
        s += mij[(size_t)eid[j] * HH + t];
    mi[(size_t)n * HH + t] = s;
}

// ---------------- edge GEMM 3: t2 = silu(mij @ Wx1 + bx1) (LDS only); px = t2 @ Wx2 + bx2;
//                  cd4[e] = diff * px (per-edge, gathered later) ----------------
__global__ __launch_bounds__(256)
void k_egemm3(const float* __restrict__ A, const float4* __restrict__ diff4,
              const float* __restrict__ W, const float* __restrict__ bias,
              const float* __restrict__ W2, const float* __restrict__ b2,
              float4* __restrict__ cd4) {
    __shared__ float As[32][68];
    __shared__ float Ws[32][128];
    __shared__ float Ts[64][133];
    __shared__ float d3[3][64];
    __shared__ float Wxs[HH * 3];
    __shared__ float b2s[3];
    const int t = threadIdx.x;
    const int e0 = blockIdx.x * 64;
    if (t < 64) {
        float4 q = diff4[e0 + t];
        d3[0][t] = q.x; d3[1][t] = q.y; d3[2][t] = q.z;
    }
    for (int i = t; i < HH * 3; i += NT) Wxs[i] = W2[i];
    if (t < 3) b2s[t] = b2[t];
    const int rg = t >> 5, cg = t & 31;
    float acc[8][4];
#pragma unroll
    for (int i = 0; i < 8; ++i)
#pragma unroll
        for (int j = 0; j < 4; ++j) acc[i][j] = 0.f;

    for (int kt = 0; kt < 4; ++kt) {
        int k0 = kt * 32;
#pragma unroll
        for (int i = 0; i < 8; ++i) {
            int idx = t + i * NT;
            int m = idx >> 5, k = idx & 31;
            As[k][m] = A[(size_t)(e0 + m) * HH + k0 + k];
        }
#pragma unroll
        for (int i = 0; i < 16; ++i) {
            int idx = t + i * NT;
            int k = idx >> 7, n = idx & 127;
            Ws[k][n] = W[(size_t)(k0 + k) * HH + n];
        }
        __syncthreads();
#pragma unroll
        for (int k = 0; k < 32; ++k) {
            float4 a0 = *(const float4*)&As[k][rg * 8];
            float4 a1 = *(const float4*)&As[k][rg * 8 + 4];
            float4 wv = *(const float4*)&Ws[k][cg * 4];
            float av[8] = {a0.x, a0.y, a0.z, a0.w, a1.x, a1.y, a1.z, a1.w};
            float wj[4] = {wv.x, wv.y, wv.z, wv.w};
#pragma unroll
            for (int i = 0; i < 8; ++i)
#pragma unroll
                for (int j = 0; j < 4; ++j)
                    acc[i][j] = fmaf(av[i], wj[j], acc[i][j]);
        }
        __syncthreads();
    }
    const int c0 = cg * 4;
#pragma unroll
    for (int i = 0; i < 8; ++i) {
        int m = rg * 8 + i;
#pragma unroll
        for (int j = 0; j < 4; ++j)
            Ts[m][c0 + j] = silu_f(acc[i][j] + bias[c0 + j]);
    }
    __syncthreads();
    if (t < 192) {
        int r = t / 3;
        int col = t - 3 * r;
        float s = b2s[col];
#pragma unroll 16
        for (int k = 0; k < HH; ++k)
            s = fmaf(Ts[r][k], Wxs[k * 3 + col], s);
        ((float*)&cd4[e0 + r])[col] = d3[col][r] * s;
    }
}

// ---------------- coords += CSR-gather(cd4)/(N-1) ----------------
__global__ void k_coordupd(float* __restrict__ coords, const float4* __restrict__ cd4,
                           const int* __restrict__ offs, const int* __restrict__ eid) {
    int idx = blockIdx.x * blockDim.x + threadIdx.x;
    if (idx >= NN * 3) return;
    int n = idx / 3, c = idx - 3 * n;
    int b = offs[n], e = offs[n + 1];
    float s = 0.f;
    for (int j = b; j < e; ++j)
        s += ((const float*)&cd4[eid[j]])[c];
    coords[idx] += s * (1.f / (NN - 1));
}

// ---------------- node GEMM 1: u = silu([V,mi] @ Wh1 + bh1) ----------------
__global__ __launch_bounds__(256)
void k_ngemm1(const float* __restrict__ V, const float* __restrict__ mi,
              const float* __restrict__ W, const float* __restrict__ bias,
              float* __restrict__ u) {
    __shared__ float As[32][132];
    __shared__ float Ws[32][128];
    const int t = threadIdx.x;
    const int r0 = blockIdx.x * 128;
    const int rg = t >> 4, cg = t & 15;
    float acc[8][8];
#pragma unroll
    for (int i = 0; i < 8; ++i)
#pragma unroll
        for (int j = 0; j < 8; ++j) acc[i][j] = 0.f;

    for (int ph = 0; ph < 2; ++ph) {
        const float* Ap = ph ? mi : V;
        const int wb = ph * HH;
        for (int kt = 0; kt < 4; ++kt) {
            int k0 = kt * 32;
#pragma unroll
            for (int i = 0; i < 16; ++i) {
                int idx = t + i * NT;
                int m = idx >> 5, k = idx & 31;
                int row = r0 + m; if (row >= NN) row = NN - 1;
                As[k][m] = Ap[(size_t)row * HH + k0 + k];
            }
#pragma unroll
            for (int i = 0; i < 16; ++i) {
                int idx = t + i * NT;
                int k = idx >> 7, n = idx & 127;
                Ws[k][n] = W[(size_t)(wb + k0 + k) * HH + n];
            }
            __syncthreads();
#pragma unroll
            for (int k = 0; k < 32; ++k) {
                float4 a0 = *(const float4*)&As[k][rg * 8];
                float4 a1 = *(const float4*)&As[k][rg * 8 + 4];
                float4 w0 = *(const float4*)&Ws[k][cg * 8];
                float4 w1 = *(const float4*)&Ws[k][cg * 8 + 4];
                float av[8] = {a0.x, a0.y, a0.z, a0.w, a1.x, a1.y, a1.z, a1.w};
                float wj[8] = {w0.x, w0.y, w0.z, w0.w, w1.x, w1.y, w1.z, w1.w};
#pragma unroll
                for (int i = 0; i < 8; ++i)
#pragma unroll
                    for (int j = 0; j < 8; ++j)
                        acc[i][j] = fmaf(av[i], wj[j], acc[i][j]);
            }
            __syncthreads();
        }
    }
    const int c0 = cg * 8;
#pragma unroll
    for (int i = 0; i < 8; ++i) {
        int row = r0 + rg * 8 + i;
        if (row < NN) {
            float o[8];
#pragma unroll
            for (int j = 0; j < 8; ++j) o[j] = silu_f(acc[i][j] + bias[c0 + j]);
            float* dstp = &u[(size_t)row * HH + c0];
            *(float4*)dstp       = make_float4(o[0], o[1], o[2], o[3]);
            *(float4*)(dstp + 4) = make_float4(o[4], o[5], o[6], o[7]);
        }
    }
}

// ---------------- node GEMM 2: X = elu(u @ Wh2 + bh2); column stats ----------------
__global__ __launch_bounds__(256)
void k_ngemm2(const float* __restrict__ A, const float* __restrict__ W,
              const float* __restrict__ bias, float* __restrict__ X,
              float* __restrict__ ssum, float* __restrict__ ssq) {
    __shared__ float As[32][132];
    __shared__ float Ws[32][128];
    const int t = threadIdx.x;
    const int r0 = blockIdx.x * 128;
    const int rg = t >> 4, cg = t & 15;
    float acc[8][8];
#pragma unroll
    for (int i = 0; i < 8; ++i)
#pragma unroll
        for (int j = 0; j < 8; ++j) acc[i][j] = 0.f;

    for (int kt = 0; kt < 4; ++kt) {
        int k0 = kt * 32;
#pragma unroll
        for (int i = 0; i < 16; ++i) {
            int idx = t + i * NT;
            int m = idx >> 5, k = idx & 31;
            int row = r0 + m; if (row >= NN) row = NN - 1;
            As[k][m] = A[(size_t)row * HH + k0 + k];
        }
#pragma unroll
        for (int i = 0; i < 16; ++i) {
            int idx = t + i * NT;
            int k = idx >> 7, n = idx & 127;
            Ws[k][n] = W[(size_t)(k0 + k) * HH + n];
        }
        __syncthreads();
#pragma unroll
        for (int k = 0; k < 32; ++k) {
            float4 a0 = *(const float4*)&As[k][rg * 8];
            float4 a1 = *(const float4*)&As[k][rg * 8 + 4];
            float4 w0 = *(const float4*)&Ws[k][cg * 8];
            float4 w1 = *(const float4*)&Ws[k][cg * 8 + 4];
            float av[8] = {a0.x, a0.y, a0.z, a0.w, a1.x, a1.y, a1.z, a1.w};
            float wj[8] = {w0.x, w0.y, w0.z, w0.w, w1.x, w1.y, w1.z, w1.w};
#pragma unroll
            for (int i = 0; i < 8; ++i)
#pragma unroll
                for (int j = 0; j < 8; ++j)
                    acc[i][j] = fmaf(av[i], wj[j], acc[i][j]);
        }
        __syncthreads();
    }
    const int c0 = cg * 8;
    float bi[8];
#pragma unroll
    for (int j = 0; j < 8; ++j) bi[j] = bias[c0 + j];
    float s[8], q[8];
#pragma unroll
    for (int j = 0; j < 8; ++j) { s[j] = 0.f; q[j] = 0.f; }
#pragma unroll
    for (int i = 0; i < 8; ++i) {
        int row = r0 + rg * 8 + i;
        float o[8];
#pragma unroll
        for (int j = 0; j < 8; ++j) o[j] = elu_f(acc[i][j] + bi[j]);
        if (row < NN) {
            float* dstp = &X[(size_t)row * HH + c0];
            *(float4*)dstp       = make_float4(o[0], o[1], o[2], o[3]);
            *(float4*)(dstp + 4) = make_float4(o[4], o[5], o[6], o[7]);
#pragma unroll
            for (int j = 0; j < 8; ++j) { s[j] += o[j]; q[j] += o[j] * o[j]; }
        }
    }
#pragma unroll
    for (int j = 0; j < 8; ++j) {
        s[j] += __shfl_xor(s[j], 16);
        s[j] += __shfl_xor(s[j], 32);
        q[j] += __shfl_xor(q[j], 16);
        q[j] += __shfl_xor(q[j], 32);
    }
    if ((t & 63) < 16) {
#pragma unroll
        for (int j = 0; j < 8; ++j) {
            atomicAdd(&ssum[c0 + j], s[j]);
            atomicAdd(&ssq[c0 + j], q[j]);
        }
    }
}

// ---------------- node batchnorm apply ----------------
__global__ void k_bnorm_nodes(const float* __restrict__ X, const float* __restrict__ ssum,
                              const float* __restrict__ ssq, const float* __restrict__ gam,
                              const float* __restrict__ bet, float* __restrict__ out) {
    int idx = blockIdx.x * blockDim.x + threadIdx.x;
    if (idx >= NN * HH) return;
    int c = idx & 127;
    float mu = ssum[c] * (1.f / NN);
    float var = ssq[c] * (1.f / NN) - mu * mu;
    out[idx] = fmaf(gam[c] * (X[idx] - mu), rsqrtf(var + EPSBN), bet[c]);
}

// ---------------- edge stats over elu(mij) (last layer only) ----------------
__global__ __launch_bounds__(256)
void k_estats(const float* __restrict__ mij, float* __restrict__ ssum, float* __restrict__ ssq) {
    const int t = threadIdx.x;
    const int col = t & 127;
    const int half = t >> 7;
    const int rbase = blockIdx.x * 250;
    float s = 0.f, q = 0.f;
    for (int r = rbase + half; r < rbase + 250; r += 2) {
        float x = elu_f(mij[(size_t)r * HH + col]);
        s += x; q += x * x;
    }
    atomicAdd(&ssum[col], s);
    atomicAdd(&ssq[col], q);
}

// ---------------- edge batchnorm apply -> output E ----------------
__global__ void k_bnorm_edges(const float* __restrict__ mij, const float* __restrict__ ssum,
                              const float* __restrict__ ssq, const float* __restrict__ gam,
                              const float* __restrict__ bet, float* __restrict__ out) {
    size_t stride = (size_t)gridDim.x * blockDim.x;
    for (size_t idx = (size_t)blockIdx.x * blockDim.x + threadIdx.x; idx < (size_t)NE * HH; idx += stride) {
        int c = (int)(idx & 127);
        float x = elu_f(mij[idx]);
        float mu = ssum[c] * (1.f / NE);
        float var = ssq[c] * (1.f / NE) - mu * mu;
        out[idx] = fmaf(gam[c] * (x - mu), rsqrtf(var + EPSBN), bet[c]);
    }
}

extern "C" void kernel_launch(void* const* d_in, const int* in_sizes, int n_in,
                              void* d_out, int out_size, void* d_ws, size_t ws_size,
                              hipStream_t stream) {
    (void)in_sizes; (void)n_in; (void)out_size; (void)ws_size;
    const float* emb_nodes = (const float*)d_in[0];
    const float* emb_edges = (const float*)d_in[1];
    const int*   eidx      = (const int*)d_in[2];
    const float* pre_Wn = (const float*)d_in[3];
    const float* pre_bn = (const float*)d_in[4];
    const float* We1 = (const float*)d_in[7];
    const float* be1 = (const float*)d_in[8];
    const float* We2 = (const float*)d_in[9];
    const float* be2 = (const float*)d_in[10];
    const float* Wx1 = (const float*)d_in[11];
    const float* bx1 = (const float*)d_in[12];
    const float* Wx2 = (const float*)d_in[13];
    const float* bx2 = (const float*)d_in[14];
    const float* Wh1 = (const float*)d_in[15];
    const float* bh1 = (const float*)d_in[16];
    const float* Wh2 = (const float*)d_in[17];
    const float* bh2 = (const float*)d_in[18];
    const float* gam_n = (const float*)d_in[19];
    const float* bet_n = (const float*)d_in[20];
    const float* gam_e = (const float*)d_in[21];
    const float* bet_e = (const float*)d_in[22];

    const int* src = eidx;
    const int* dst = eidx + NE;

    float* ws = (float*)d_ws;
    float*  coords = ws;                          // 30000
    float4* diff4  = (float4*)(ws + 30000);       // 640000 floats
    float*  V      = ws + 670000;                 // 1.28M
    float*  mi     = ws + 1950000;                // 1.28M
    float*  t1     = ws + 3230000;                // 20.48M
    float*  mij    = ws + 23710000;               // 20.48M
    float*  snN    = ws + 44190000;               // 128
    float*  sqN    = ws + 44190128;               // 128
    float*  snE    = ws + 44190256;               // 128
    float*  sqE    = ws + 44190384;               // 128
    int*    I0     = (int*)(ws + 44190512);
    int*    deg    = I0;                          // 10000
    int*    offs   = I0 + 10000;                  // 10001
    int*    cur    = I0 + 20001;                  // 10000
    int*    eid    = I0 + 30001;                  // 160000
    // aliases inside dead t1 region (t1 only live egemm1->egemm2):
    float4* cd4 = (float4*)t1;                    // 640000 floats
    float*  u   = t1 + 640000;                    // 1.28M
    float*  X   = t1 + 1920000;                   // 1.28M

    float* outV = (float*)d_out;
    float* outE = (float*)d_out + (size_t)NN * HH;

    k_copy<<<(30000 + 255) / 256, 256, 0, stream>>>(emb_nodes, coords, 30000);
    k_vinit<<<(NN * HH + 255) / 256, 256, 0, stream>>>(emb_nodes, pre_Wn, pre_bn, V);

    // CSR build (edges fixed across layers)
    k_zero_int<<<(NN + 255) / 256, 256, 0, stream>>>(deg, NN);
    k_hist<<<(NE + 255) / 256, 256, 0, stream>>>(dst, deg);
    k_scan<<<1, 256, 0, stream>>>(deg, offs, cur);
    k_fill<<<(NE + 255) / 256, 256, 0, stream>>>(dst, cur, eid);

    for (int l = 0; l < 3; ++l) {
        const float* We1l = We1 + (size_t)l * 259 * 128;
        const float* be1l = be1 + l * 128;
        const float* We2l = We2 + (size_t)l * 128 * 128;
        const float* be2l = be2 + l * 128;
        const float* Wx1l = Wx1 + (size_t)l * 128 * 128;
        const float* bx1l = bx1 + l * 128;
        const float* Wx2l = Wx2 + (size_t)l * 128 * 3;
        const float* bx2l = bx2 + l * 3;
        const float* Wh1l = Wh1 + (size_t)l * 256 * 128;
        const float* bh1l = bh1 + l * 128;
        const float* Wh2l = Wh2 + (size_t)l * 128 * 128;
        const float* bh2l = bh2 + l * 128;

        k_zero<<<2, 256, 0, stream>>>(snN, 512);
        k_eprep<<<(NE + 255) / 256, 256, 0, stream>>>(coords, src, dst, diff4);
        k_egemm1<<<NE / 128, NT, 0, stream>>>(V, src, dst, diff4, emb_edges, We1l, be1l, t1);
        k_egemm2<<<NE / 128, NT, 0, stream>>>(t1, We2l, be2l, mij);
        k_egemm3<<<NE / 64, NT, 0, stream>>>(mij, diff4, Wx1l, bx1l, Wx2l, bx2l, cd4);
        k_mi<<<NN, 128, 0, stream>>>(mij, offs, eid, mi);
        k_coordupd<<<(NN * 3 + 255) / 256, 256, 0, stream>>>(coords, cd4, offs, eid);
        k_ngemm1<<<(NN + 127) / 128, NT, 0, stream>>>(V, mi, Wh1l, bh1l, u);
        k_ngemm2<<<(NN + 127) / 128, NT, 0, stream>>>(u, Wh2l, bh2l, X, snN, sqN);
        k_bnorm_nodes<<<(NN * HH + 255) / 256, 256, 0, stream>>>(X, snN, sqN, gam_n + l * 128, bet_n + l * 128,
                                                                 (l < 2) ? V : outV);
        if (l == 2) {
            k_estats<<<640, 256, 0, stream>>>(mij, snE, sqE);
            k_bnorm_edges<<<4096, 256, 0, stream>>>(mij, snE, sqE, gam_e + l * 128, bet_e + l * 128, outE);
        }
    }
}

// Round 5
// 1208.467 us; speedup vs baseline: 1.8954x; 1.6754x over previous
//
#include <hip/hip_runtime.h>
#include <hip/hip_bf16.h>
#include <math.h>

#define NN 10000
#define NE 160000
#define HH 128
#define EPSBN 1e-5f

static constexpr int NT = 256;

typedef __attribute__((ext_vector_type(8))) short s8b;   // 8 bf16 (as shorts)
typedef __attribute__((ext_vector_type(4))) float f32x4;

#define MFMA16 __builtin_amdgcn_mfma_f32_16x16x32_bf16

__device__ __forceinline__ float silu_f(float x) { return x / (1.f + __expf(-x)); }
__device__ __forceinline__ float elu_f(float x)  { return x > 0.f ? x : expm1f(x); }

// split fp32 -> hi/lo bf16 (truncation; hi+lo ~ 16-bit-mantissa accurate)
__device__ __forceinline__ void splitf(float x, ushort& h, ushort& l) {
    unsigned u = __float_as_uint(x) & 0xffff0000u;
    h = (ushort)(u >> 16);
    float lo = x - __uint_as_float(u);
    l = (ushort)(__float_as_uint(lo) >> 16);
}

__device__ __forceinline__ void split8(const float* p, s8b& h8, s8b& l8) {
    float4 f0 = *(const float4*)p;
    float4 f1 = *(const float4*)(p + 4);
    float v[8] = {f0.x, f0.y, f0.z, f0.w, f1.x, f1.y, f1.z, f1.w};
#pragma unroll
    for (int i = 0; i < 8; ++i) { ushort h, l; splitf(v[i], h, l); h8[i] = (short)h; l8[i] = (short)l; }
}

__device__ __forceinline__ s8b ldg8(const ushort* p) { return *(const s8b*)p; }

// ---------------- utility ----------------
__global__ void k_zero(float* __restrict__ p, int n) {
    int i = blockIdx.x * blockDim.x + threadIdx.x;
    if (i < n) p[i] = 0.f;
}
__global__ void k_zero_int(int* __restrict__ p, int n) {
    int i = blockIdx.x * blockDim.x + threadIdx.x;
    if (i < n) p[i] = 0;
}
__global__ void k_copy(const float* __restrict__ a, float* __restrict__ b, int n) {
    int i = blockIdx.x * blockDim.x + threadIdx.x;
    if (i < n) b[i] = a[i];
}

// V = emb_nodes @ pre_Wn + pre_bn   -> split planes
__global__ void k_vinit(const float* __restrict__ en, const float* __restrict__ Wn,
                        const float* __restrict__ bn, ushort* __restrict__ Vhi,
                        ushort* __restrict__ Vlo) {
    int idx = blockIdx.x * blockDim.x + threadIdx.x;
    if (idx >= NN * HH) return;
    int i = idx >> 7, j = idx & 127;
    float v = fmaf(en[i * 3 + 0], Wn[j], bn[j]);
    v = fmaf(en[i * 3 + 1], Wn[HH + j], v);
    v = fmaf(en[i * 3 + 2], Wn[2 * HH + j], v);
    ushort h, l; splitf(v, h, l);
    Vhi[idx] = h; Vlo[idx] = l;
}

// ---------------- weight transpose+split: dest [n][K] hi/lo planes ----------------
// per layer (shorts): We1t @0 (K=256), We2t @32768 (K=128), Wx1t @49152 (K=128),
//                     Wh1t @65536 (K=256), Wh2t @98304 (K=128). layer stride 114688.
__global__ void k_wprep(const float* __restrict__ We1, const float* __restrict__ We2,
                        const float* __restrict__ Wx1, const float* __restrict__ Wh1,
                        const float* __restrict__ Wh2, ushort* __restrict__ hi,
                        ushort* __restrict__ lo) {
    int idx = blockIdx.x * 256 + threadIdx.x;
    if (idx >= 344064) return;
    int layer = idx / 114688;
    int r = idx - layer * 114688;
    const float* src; int K; int roff;
    if (r < 32768)      { src = We1 + (size_t)layer * 33152; K = 256; roff = r; }
    else if (r < 49152) { src = We2 + (size_t)layer * 16384; K = 128; roff = r - 32768; }
    else if (r < 65536) { src = Wx1 + (size_t)layer * 16384; K = 128; roff = r - 49152; }
    else if (r < 98304) { src = Wh1 + (size_t)layer * 32768; K = 256; roff = r - 65536; }
    else                { src = Wh2 + (size_t)layer * 16384; K = 128; roff = r - 98304; }
    int n = roff / K, k = roff - n * K;
    ushort h, l; splitf(src[k * 128 + n], h, l);
    hi[idx] = h; lo[idx] = l;
}

// ---------------- CSR build ----------------
__global__ void k_hist(const int* __restrict__ dst, int* __restrict__ deg) {
    int e = blockIdx.x * blockDim.x + threadIdx.x;
    if (e < NE) atomicAdd(&deg[dst[e]], 1);
}
__global__ __launch_bounds__(256)
void k_scan(const int* __restrict__ deg, int* __restrict__ offs, int* __restrict__ cur) {
    __shared__ int part[256];
    const int t = threadIdx.x;
    const int s0 = t * 40, s1 = min(s0 + 40, NN);
    int s = 0;
    for (int i = s0; i < s1; ++i) s += deg[i];
    part[t] = s;
    __syncthreads();
    if (t == 0) {
        int r = 0;
        for (int i = 0; i < 256; ++i) { int v = part[i]; part[i] = r; r += v; }
    }
    __syncthreads();
    int r = part[t];
    for (int i = s0; i < s1; ++i) { offs[i] = r; cur[i] = r; r += deg[i]; }
    if (t == 255) offs[NN] = r;
}
__global__ void k_fill(const int* __restrict__ dst, int* __restrict__ cur, int* __restrict__ eid) {
    int e = blockIdx.x * blockDim.x + threadIdx.x;
    if (e < NE) {
        int p = atomicAdd(&cur[dst[e]], 1);
        eid[p] = e;
    }
}

// diff4 = (dx,dy,dz,dist)
__global__ void k_eprep(const float* __restrict__ coords, const int* __restrict__ src,
                        const int* __restrict__ dst, float4* __restrict__ diff4) {
    int e = blockIdx.x * blockDim.x + threadIdx.x;
    if (e >= NE) return;
    int s = src[e], d = dst[e];
    float dx = coords[d * 3 + 0] - coords[s * 3 + 0];
    float dy = coords[d * 3 + 1] - coords[s * 3 + 1];
    float dz = coords[d * 3 + 2] - coords[s * 3 + 2];
    float dist = sqrtf(dx * dx + dy * dy + dz * dz);
    diff4[e] = make_float4(dx, dy, dz, dist);
}

// ================= fused edge kernel: mij = silu(silu(h@We1+be1)@We2+be2) =================
// 64 edge rows/block, 256 thr (4 waves, 2x2 wave grid; wave tile 32x64, M_rep=2,N_rep=4)
__global__ __launch_bounds__(256, 3)
void k_efused(const ushort* __restrict__ Vhi, const ushort* __restrict__ Vlo,
              const int* __restrict__ src, const int* __restrict__ dst,
              const float4* __restrict__ diff4, const float* __restrict__ ee,
              const ushort* __restrict__ W1hi, const ushort* __restrict__ W1lo,  // [128][256]
              const float* __restrict__ We1f, const float* __restrict__ be1,
              const ushort* __restrict__ W2hi, const ushort* __restrict__ W2lo,  // [128][128]
              const float* __restrict__ be2, float* __restrict__ mij) {
    __shared__ ushort t1h[4][64][40];
    __shared__ ushort t1l[4][64][40];
    __shared__ int sid[64], did[64];
    __shared__ float dd[64], eAa[64], eBb[64];
    const int t = threadIdx.x;
    const int lane = t & 63;
    const int w = t >> 6;
    const int wr = w >> 1, wc = w & 1;
    const int e0 = blockIdx.x * 64;
    if (t < 64) {
        int e = e0 + t;
        sid[t] = src[e]; did[t] = dst[e];
        float4 q = diff4[e];
        dd[t] = q.w; eAa[t] = ee[2 * e]; eBb[t] = ee[2 * e + 1];
    }
    __syncthreads();
    const int l15 = lane & 15, lq = lane >> 4;
    f32x4 acc[2][4];
#pragma unroll
    for (int i = 0; i < 2; ++i)
#pragma unroll
        for (int j = 0; j < 4; ++j) acc[i][j] = (f32x4){0.f, 0.f, 0.f, 0.f};

    // ---- phase A: K=256 over [V[src] | V[dst]] ----
    for (int kk = 0; kk < 8; ++kk) {
        const int* ids = (kk < 4) ? sid : did;
        const int k0 = (kk & 3) * 32;
        const int wk = kk * 32;
        s8b ah[2], al[2], bh[4], bl[4];
#pragma unroll
        for (int mi = 0; mi < 2; ++mi) {
            int row = ids[wr * 32 + mi * 16 + l15];
            size_t off = (size_t)row * HH + k0 + lq * 8;
            ah[mi] = ldg8(Vhi + off);
            al[mi] = ldg8(Vlo + off);
        }
#pragma unroll
        for (int ni = 0; ni < 4; ++ni) {
            int col = wc * 64 + ni * 16 + l15;
            size_t off = (size_t)col * 256 + wk + lq * 8;
            bh[ni] = ldg8(W1hi + off);
            bl[ni] = ldg8(W1lo + off);
        }
#pragma unroll
        for (int mi = 0; mi < 2; ++mi)
#pragma unroll
            for (int ni = 0; ni < 4; ++ni) {
                acc[mi][ni] = MFMA16(al[mi], bh[ni], acc[mi][ni], 0, 0, 0);
                acc[mi][ni] = MFMA16(ah[mi], bl[ni], acc[mi][ni], 0, 0, 0);
                acc[mi][ni] = MFMA16(ah[mi], bh[ni], acc[mi][ni], 0, 0, 0);
            }
    }
    // ---- phase A epilogue: rank-1 fixups (dist, ee) + bias + silu -> t1 LDS (split) ----
#pragma unroll
    for (int mi = 0; mi < 2; ++mi)
#pragma unroll
        for (int ni = 0; ni < 4; ++ni) {
            int col = wc * 64 + ni * 16 + l15;
            float w256 = We1f[256 * HH + col];
            float w257 = We1f[257 * HH + col];
            float w258 = We1f[258 * HH + col];
            float bi = be1[col];
            int kt = col >> 5, c = col & 31;
#pragma unroll
            for (int r = 0; r < 4; ++r) {
                int m = wr * 32 + mi * 16 + lq * 4 + r;
                float v = acc[mi][ni][r] + bi;
                v = fmaf(dd[m], w256, v);
                v = fmaf(eAa[m], w257, v);
                v = fmaf(eBb[m], w258, v);
                v = silu_f(v);
                ushort h, l; splitf(v, h, l);
                t1h[kt][m][c] = h;
                t1l[kt][m][c] = l;
                acc[mi][ni][r] = 0.f;
            }
        }
    __syncthreads();
    // ---- phase B: K=128 over t1 ----
    for (int kt = 0; kt < 4; ++kt) {
        s8b ah[2], al[2], bh[4], bl[4];
#pragma unroll
        for (int mi = 0; mi < 2; ++mi) {
            int row = wr * 32 + mi * 16 + l15;
            ah[mi] = *(const s8b*)&t1h[kt][row][lq * 8];
            al[mi] = *(const s8b*)&t1l[kt][row][lq * 8];
        }
#pragma unroll
        for (int ni = 0; ni < 4; ++ni) {
            int col = wc * 64 + ni * 16 + l15;
            size_t off = (size_t)col * 128 + kt * 32 + lq * 8;
            bh[ni] = ldg8(W2hi + off);
            bl[ni] = ldg8(W2lo + off);
        }
#pragma unroll
        for (int mi = 0; mi < 2; ++mi)
#pragma unroll
            for (int ni = 0; ni < 4; ++ni) {
                acc[mi][ni] = MFMA16(al[mi], bh[ni], acc[mi][ni], 0, 0, 0);
                acc[mi][ni] = MFMA16(ah[mi], bl[ni], acc[mi][ni], 0, 0, 0);
                acc[mi][ni] = MFMA16(ah[mi], bh[ni], acc[mi][ni], 0, 0, 0);
            }
    }
    // ---- phase B epilogue: silu -> mij (fp32, global) ----
#pragma unroll
    for (int mi = 0; mi < 2; ++mi)
#pragma unroll
        for (int ni = 0; ni < 4; ++ni) {
            int col = wc * 64 + ni * 16 + l15;
            float bi = be2[col];
#pragma unroll
            for (int r = 0; r < 4; ++r) {
                int m = wr * 32 + mi * 16 + lq * 4 + r;
                mij[(size_t)(e0 + m) * HH + col] = silu_f(acc[mi][ni][r] + bi);
            }
        }
}

// ---------------- mi = segment_sum(mij, dst) via CSR gather (fp32) ----------------
__global__ __launch_bounds__(128)
void k_mi(const float* __restrict__ mij, const int* __restrict__ offs,
          const int* __restrict__ eid, float* __restrict__ mi) {
    const int n = blockIdx.x;
    const int t = threadIdx.x;
    const int b = offs[n], e = offs[n + 1];
    float s = 0.f;
    for (int j = b; j < e; ++j)
        s += mij[(size_t)eid[j] * HH + t];
    mi[(size_t)n * HH + t] = s;
}

// ---------------- egemm3: t2 = silu(mij @ Wx1 + bx1) (MFMA, Ts in LDS); px = t2@Wx2+bx2 ----------------
__global__ __launch_bounds__(256, 3)
void k_egemm3(const float* __restrict__ A, const float4* __restrict__ diff4,
              const ushort* __restrict__ Bhi, const ushort* __restrict__ Blo,  // Wx1t [128][128]
              const float* __restrict__ bias, const float* __restrict__ W2,
              const float* __restrict__ b2, float4* __restrict__ cd4) {
    __shared__ float Ts[64][133];
    __shared__ float d3[3][64];
    __shared__ float Wxs[HH * 3];
    __shared__ float b2s[3];
    const int t = threadIdx.x;
    const int lane = t & 63;
    const int w = t >> 6;
    const int wr = w >> 1, wc = w & 1;
    const int e0 = blockIdx.x * 64;
    if (t < 64) {
        float4 q = diff4[e0 + t];
        d3[0][t] = q.x; d3[1][t] = q.y; d3[2][t] = q.z;
    }
    for (int i = t; i < HH * 3; i += NT) Wxs[i] = W2[i];
    if (t < 3) b2s[t] = b2[t];
    const int l15 = lane & 15, lq = lane >> 4;
    f32x4 acc[2][4];
#pragma unroll
    for (int i = 0; i < 2; ++i)
#pragma unroll
        for (int j = 0; j < 4; ++j) acc[i][j] = (f32x4){0.f, 0.f, 0.f, 0.f};

    for (int kt = 0; kt < 4; ++kt) {
        s8b ah[2], al[2], bh[4], bl[4];
#pragma unroll
        for (int mi = 0; mi < 2; ++mi) {
            int row = e0 + wr * 32 + mi * 16 + l15;
            split8(A + (size_t)row * HH + kt * 32 + lq * 8, ah[mi], al[mi]);
        }
#pragma unroll
        for (int ni = 0; ni < 4; ++ni) {
            int col = wc * 64 + ni * 16 + l15;
            size_t off = (size_t)col * 128 + kt * 32 + lq * 8;
            bh[ni] = ldg8(Bhi + off);
            bl[ni] = ldg8(Blo + off);
        }
#pragma unroll
        for (int mi = 0; mi < 2; ++mi)
#pragma unroll
            for (int ni = 0; ni < 4; ++ni) {
                acc[mi][ni] = MFMA16(al[mi], bh[ni], acc[mi][ni], 0, 0, 0);
                acc[mi][ni] = MFMA16(ah[mi], bl[ni], acc[mi][ni], 0, 0, 0);
                acc[mi][ni] = MFMA16(ah[mi], bh[ni], acc[mi][ni], 0, 0, 0);
            }
    }
#pragma unroll
    for (int mi = 0; mi < 2; ++mi)
#pragma unroll
        for (int ni = 0; ni < 4; ++ni) {
            int col = wc * 64 + ni * 16 + l15;
            float bi = bias[col];
#pragma unroll
            for (int r = 0; r < 4; ++r) {
                int m = wr * 32 + mi * 16 + lq * 4 + r;
                Ts[m][col] = silu_f(acc[mi][ni][r] + bi);
            }
        }
    __syncthreads();
    if (t < 192) {
        int r = t / 3;
        int col = t - 3 * r;
        float s = b2s[col];
#pragma unroll 16
        for (int k = 0; k < HH; ++k)
            s = fmaf(Ts[r][k], Wxs[k * 3 + col], s);
        ((float*)&cd4[e0 + r])[col] = d3[col][r] * s;
    }
}

// ---------------- coords += CSR-gather(cd4)/(N-1) ----------------
__global__ void k_coordupd(float* __restrict__ coords, const float4* __restrict__ cd4,
                           const int* __restrict__ offs, const int* __restrict__ eid) {
    int idx = blockIdx.x * blockDim.x + threadIdx.x;
    if (idx >= NN * 3) return;
    int n = idx / 3, c = idx - 3 * n;
    int b = offs[n], e = offs[n + 1];
    float s = 0.f;
    for (int j = b; j < e; ++j)
        s += ((const float*)&cd4[eid[j]])[c];
    coords[idx] += s * (1.f / (NN - 1));
}

// ---------------- node GEMM 1: u = silu([V,mi] @ Wh1 + bh1)  (MFMA) ----------------
__global__ __launch_bounds__(256, 3)
void k_ngemm1(const ushort* __restrict__ Vhi, const ushort* __restrict__ Vlo,
              const float* __restrict__ mi,
              const ushort* __restrict__ Bhi, const ushort* __restrict__ Blo,  // Wh1t [128][256]
              const float* __restrict__ bias, float* __restrict__ u) {
    const int t = threadIdx.x;
    const int lane = t & 63;
    const int w = t >> 6;
    const int wr = w >> 1, wc = w & 1;
    const int r0 = blockIdx.x * 64;
    const int l15 = lane & 15, lq = lane >> 4;
    f32x4 acc[2][4];
#pragma unroll
    for (int i = 0; i < 2; ++i)
#pragma unroll
        for (int j = 0; j < 4; ++j) acc[i][j] = (f32x4){0.f, 0.f, 0.f, 0.f};

    for (int kk = 0; kk < 8; ++kk) {
        const int wk = kk * 32;
        s8b ah[2], al[2], bh[4], bl[4];
#pragma unroll
        for (int mi_ = 0; mi_ < 2; ++mi_) {
            int row = r0 + wr * 32 + mi_ * 16 + l15;
            if (row >= NN) row = NN - 1;
            if (kk < 4) {
                size_t off = (size_t)row * HH + kk * 32 + lq * 8;
                ah[mi_] = ldg8(Vhi + off);
                al[mi_] = ldg8(Vlo + off);
            } else {
                split8(mi + (size_t)row * HH + (kk - 4) * 32 + lq * 8, ah[mi_], al[mi_]);
            }
        }
#pragma unroll
        for (int ni = 0; ni < 4; ++ni) {
            int col = wc * 64 + ni * 16 + l15;
            size_t off = (size_t)col * 256 + wk + lq * 8;
            bh[ni] = ldg8(Bhi + off);
            bl[ni] = ldg8(Blo + off);
        }
#pragma unroll
        for (int mi_ = 0; mi_ < 2; ++mi_)
#pragma unroll
            for (int ni = 0; ni < 4; ++ni) {
                acc[mi_][ni] = MFMA16(al[mi_], bh[ni], acc[mi_][ni], 0, 0, 0);
                acc[mi_][ni] = MFMA16(ah[mi_], bl[ni], acc[mi_][ni], 0, 0, 0);
                acc[mi_][ni] = MFMA16(ah[mi_], bh[ni], acc[mi_][ni], 0, 0, 0);
            }
    }
#pragma unroll
    for (int mi_ = 0; mi_ < 2; ++mi_)
#pragma unroll
        for (int ni = 0; ni < 4; ++ni) {
            int col = wc * 64 + ni * 16 + l15;
            float bi = bias[col];
#pragma unroll
            for (int r = 0; r < 4; ++r) {
                int m = r0 + wr * 32 + mi_ * 16 + lq * 4 + r;
                if (m < NN) u[(size_t)m * HH + col] = silu_f(acc[mi_][ni][r] + bi);
            }
        }
}

// ---------------- node GEMM 2: X = elu(u @ Wh2 + bh2) + column stats (MFMA) ----------------
__global__ __launch_bounds__(256, 3)
void k_ngemm2(const float* __restrict__ A,
              const ushort* __restrict__ Bhi, const ushort* __restrict__ Blo,  // Wh2t [128][128]
              const float* __restrict__ bias, float* __restrict__ X,
              float* __restrict__ ssum, float* __restrict__ ssq) {
    const int t = threadIdx.x;
    const int lane = t & 63;
    const int w = t >> 6;
    const int wr = w >> 1, wc = w & 1;
    const int r0 = blockIdx.x * 64;
    const int l15 = lane & 15, lq = lane >> 4;
    f32x4 acc[2][4];
#pragma unroll
    for (int i = 0; i < 2; ++i)
#pragma unroll
        for (int j = 0; j < 4; ++j) acc[i][j] = (f32x4){0.f, 0.f, 0.f, 0.f};

    for (int kt = 0; kt < 4; ++kt) {
        s8b ah[2], al[2], bh[4], bl[4];
#pragma unroll
        for (int mi_ = 0; mi_ < 2; ++mi_) {
            int row = r0 + wr * 32 + mi_ * 16 + l15;
            if (row >= NN) row = NN - 1;
            split8(A + (size_t)row * HH + kt * 32 + lq * 8, ah[mi_], al[mi_]);
        }
#pragma unroll
        for (int ni = 0; ni < 4; ++ni) {
            int col = wc * 64 + ni * 16 + l15;
            size_t off = (size_t)col * 128 + kt * 32 + lq * 8;
            bh[ni] = ldg8(Bhi + off);
            bl[ni] = ldg8(Blo + off);
        }
#pragma unroll
        for (int mi_ = 0; mi_ < 2; ++mi_)
#pragma unroll
            for (int ni = 0; ni < 4; ++ni) {
                acc[mi_][ni] = MFMA16(al[mi_], bh[ni], acc[mi_][ni], 0, 0, 0);
                acc[mi_][ni] = MFMA16(ah[mi_], bl[ni], acc[mi_][ni], 0, 0, 0);
                acc[mi_][ni] = MFMA16(ah[mi_], bh[ni], acc[mi_][ni], 0, 0, 0);
            }
    }
    float s[4] = {0.f, 0.f, 0.f, 0.f}, q[4] = {0.f, 0.f, 0.f, 0.f};
#pragma unroll
    for (int mi_ = 0; mi_ < 2; ++mi_)
#pragma unroll
        for (int ni = 0; ni < 4; ++ni) {
            int col = wc * 64 + ni * 16 + l15;
            float bi = bias[col];
#pragma unroll
            for (int r = 0; r < 4; ++r) {
                int m = r0 + wr * 32 + mi_ * 16 + lq * 4 + r;
                float v = elu_f(acc[mi_][ni][r] + bi);
                if (m < NN) {
                    X[(size_t)m * HH + col] = v;
                    s[ni] += v; q[ni] += v * v;
                }
            }
        }
#pragma unroll
    for (int j = 0; j < 4; ++j) {
        s[j] += __shfl_xor(s[j], 16);
        s[j] += __shfl_xor(s[j], 32);
        q[j] += __shfl_xor(q[j], 16);
        q[j] += __shfl_xor(q[j], 32);
    }
    if (lane < 16) {
#pragma unroll
        for (int j = 0; j < 4; ++j) {
            int col = wc * 64 + j * 16 + l15;
            atomicAdd(&ssum[col], s[j]);
            atomicAdd(&ssq[col], q[j]);
        }
    }
}

// ---------------- node batchnorm apply (-> split planes or fp32 out) ----------------
__global__ void k_bnorm_nodes(const float* __restrict__ X, const float* __restrict__ ssum,
                              const float* __restrict__ ssq, const float* __restrict__ gam,
                              const float* __restrict__ bet, float* __restrict__ outf,
                              ushort* __restrict__ outhi, ushort* __restrict__ outlo,
                              int writeplanes) {
    int idx = blockIdx.x * blockDim.x + threadIdx.x;
    if (idx >= NN * HH) return;
    int c = idx & 127;
    float mu = ssum[c] * (1.f / NN);
    float var = ssq[c] * (1.f / NN) - mu * mu;
    float v = fmaf(gam[c] * (X[idx] - mu), rsqrtf(var + EPSBN), bet[c]);
    if (writeplanes) {
        ushort h, l; splitf(v, h, l);
        outhi[idx] = h; outlo[idx] = l;
    } else {
        outf[idx] = v;
    }
}

// ---------------- edge stats over elu(mij) (last layer only) ----------------
__global__ __launch_bounds__(256)
void k_estats(const float* __restrict__ mij, float* __restrict__ ssum, float* __restrict__ ssq) {
    const int t = threadIdx.x;
    const int col = t & 127;
    const int half = t >> 7;
    const int rbase = blockIdx.x * 250;
    float s = 0.f, q = 0.f;
    for (int r = rbase + half; r < rbase + 250; r += 2) {
        float x = elu_f(mij[(size_t)r * HH + col]);
        s += x; q += x * x;
    }
    atomicAdd(&ssum[col], s);
    atomicAdd(&ssq[col], q);
}

// ---------------- edge batchnorm apply -> output E ----------------
__global__ void k_bnorm_edges(const float* __restrict__ mij, const float* __restrict__ ssum,
                              const float* __restrict__ ssq, const float* __restrict__ gam,
                              const float* __restrict__ bet, float* __restrict__ out) {
    size_t stride = (size_t)gridDim.x * blockDim.x;
    for (size_t idx = (size_t)blockIdx.x * blockDim.x + threadIdx.x; idx < (size_t)NE * HH; idx += stride) {
        int c = (int)(idx & 127);
        float x = elu_f(mij[idx]);
        float mu = ssum[c] * (1.f / NE);
        float var = ssq[c] * (1.f / NE) - mu * mu;
        out[idx] = fmaf(gam[c] * (x - mu), rsqrtf(var + EPSBN), bet[c]);
    }
}

extern "C" void kernel_launch(void* const* d_in, const int* in_sizes, int n_in,
                              void* d_out, int out_size, void* d_ws, size_t ws_size,
                              hipStream_t stream) {
    (void)in_sizes; (void)n_in; (void)out_size; (void)ws_size;
    const float* emb_nodes = (const float*)d_in[0];
    const float* emb_edges = (const float*)d_in[1];
    const int*   eidx      = (const int*)d_in[2];
    const float* pre_Wn = (const float*)d_in[3];
    const float* pre_bn = (const float*)d_in[4];
    const float* We1 = (const float*)d_in[7];
    const float* be1 = (const float*)d_in[8];
    const float* We2 = (const float*)d_in[9];
    const float* be2 = (const float*)d_in[10];
    const float* Wx1 = (const float*)d_in[11];
    const float* bx1 = (const float*)d_in[12];
    const float* Wx2 = (const float*)d_in[13];
    const float* bx2 = (const float*)d_in[14];
    const float* Wh1 = (const float*)d_in[15];
    const float* bh1 = (const float*)d_in[16];
    const float* Wh2 = (const float*)d_in[17];
    const float* bh2 = (const float*)d_in[18];
    const float* gam_n = (const float*)d_in[19];
    const float* bet_n = (const float*)d_in[20];
    const float* gam_e = (const float*)d_in[21];
    const float* bet_e = (const float*)d_in[22];

    const int* src = eidx;
    const int* dst = eidx + NE;

    // Workspace layout (floats). NOTE: Vhi/Vlo are NN*HH USHORTS = 640,000 floats EACH
    // (round-3 bug was sizing them at 320,000 -> overlap -> NaN).
    float* ws = (float*)d_ws;
    float*   coords = ws;                         // [0, 30000)
    float4*  diff4  = (float4*)(ws + 30000);      // [30000, 670000)
    ushort*  Vhi    = (ushort*)(ws + 670000);     // [670000, 1310000)
    ushort*  Vlo    = (ushort*)(ws + 1310000);    // [1310000, 1950000)
    float*   mi     = ws + 1950000;               // [1950000, 3230000)
    float*   u      = ws + 3230000;               // [3230000, 4510000)
    float*   X      = ws + 4510000;               // [4510000, 5790000)
    float4*  cd4    = (float4*)(ws + 5790000);    // [5790000, 6430000)
    float*   mij    = ws + 6430000;               // [6430000, 26910000)
    float*   snN    = ws + 26910000;              // 128
    float*   sqN    = ws + 26910128;
    float*   snE    = ws + 26910256;
    float*   sqE    = ws + 26910384;
    ushort*  Whi    = (ushort*)(ws + 26910512);   // 344064 ush = [26910512, 27082544)
    ushort*  Wlo    = (ushort*)(ws + 27082544);   // [27082544, 27254576)
    int*     I0     = (int*)(ws + 27254576);
    int*     deg    = I0;
    int*     offs   = I0 + 10000;
    int*     cur    = I0 + 20001;
    int*     eid    = I0 + 30001;

    float* outV = (float*)d_out;
    float* outE = (float*)d_out + (size_t)NN * HH;

    k_copy<<<(30000 + 255) / 256, 256, 0, stream>>>(emb_nodes, coords, 30000);
    k_vinit<<<(NN * HH + 255) / 256, 256, 0, stream>>>(emb_nodes, pre_Wn, pre_bn, Vhi, Vlo);
    k_wprep<<<1344, 256, 0, stream>>>(We1, We2, Wx1, Wh1, Wh2, Whi, Wlo);

    k_zero_int<<<(NN + 255) / 256, 256, 0, stream>>>(deg, NN);
    k_hist<<<(NE + 255) / 256, 256, 0, stream>>>(dst, deg);
    k_scan<<<1, 256, 0, stream>>>(deg, offs, cur);
    k_fill<<<(NE + 255) / 256, 256, 0, stream>>>(dst, cur, eid);

    for (int l = 0; l < 3; ++l) {
        const float* We1l = We1 + (size_t)l * 259 * 128;
        const float* be1l = be1 + l * 128;
        const float* be2l = be2 + l * 128;
        const float* bx1l = bx1 + l * 128;
        const float* Wx2l = Wx2 + (size_t)l * 128 * 3;
        const float* bx2l = bx2 + l * 3;
        const float* bh1l = bh1 + l * 128;
        const float* bh2l = bh2 + l * 128;
        const size_t L = (size_t)l * 114688;
        const ushort* W1hi = Whi + L,          *W1lo = Wlo + L;           // We1t [128][256]
        const ushort* W2hi = Whi + L + 32768,  *W2lo = Wlo + L + 32768;   // We2t [128][128]
        const ushort* Wxhi = Whi + L + 49152,  *Wxlo = Wlo + L + 49152;   // Wx1t [128][128]
        const ushort* Whhi = Whi + L + 65536,  *Whlo = Wlo + L + 65536;   // Wh1t [128][256]
        const ushort* Wghi = Whi + L + 98304,  *Wglo = Wlo + L + 98304;   // Wh2t [128][128]

        k_zero<<<2, 256, 0, stream>>>(snN, 512);
        k_eprep<<<(NE + 255) / 256, 256, 0, stream>>>(coords, src, dst, diff4);
        k_efused<<<NE / 64, NT, 0, stream>>>(Vhi, Vlo, src, dst, diff4, emb_edges,
                                             W1hi, W1lo, We1l, be1l, W2hi, W2lo, be2l, mij);
        k_egemm3<<<NE / 64, NT, 0, stream>>>(mij, diff4, Wxhi, Wxlo, bx1l, Wx2l, bx2l, cd4);
        k_mi<<<NN, 128, 0, stream>>>(mij, offs, eid, mi);
        k_coordupd<<<(NN * 3 + 255) / 256, 256, 0, stream>>>(coords, cd4, offs, eid);
        k_ngemm1<<<(NN + 63) / 64, NT, 0, stream>>>(Vhi, Vlo, mi, Whhi, Whlo, bh1l, u);
        k_ngemm2<<<(NN + 63) / 64, NT, 0, stream>>>(u, Wghi, Wglo, bh2l, X, snN, sqN);
        k_bnorm_nodes<<<(NN * HH + 255) / 256, 256, 0, stream>>>(X, snN, sqN, gam_n + l * 128,
                                                                 bet_n + l * 128,
                                                                 outV, Vhi, Vlo, (l < 2) ? 1 : 0);
        if (l == 2) {
            k_estats<<<640, 256, 0, stream>>>(mij, snE, sqE);
            k_bnorm_edges<<<4096, 256, 0, stream>>>(mij, snE, sqE, gam_e + l * 128, bet_e + l * 128, outE);
        }
    }
}

// Round 6
// 870.733 us; speedup vs baseline: 2.6306x; 1.3879x over previous
//
#include <hip/hip_runtime.h>
#include <hip/hip_bf16.h>
#include <math.h>

#define NN 10000
#define NE 160000
#define HH 128
#define EPSBN 1e-5f

static constexpr int NT = 256;

typedef __attribute__((ext_vector_type(8))) short s8b;   // 8 bf16 (as shorts)
typedef __attribute__((ext_vector_type(4))) float f32x4;

#define MFMA16 __builtin_amdgcn_mfma_f32_16x16x32_bf16

__device__ __forceinline__ float silu_f(float x) { return x / (1.f + __expf(-x)); }
__device__ __forceinline__ float elu_f(float x)  { return x > 0.f ? x : expm1f(x); }

// fp32 -> bf16 round-to-nearest-even
__device__ __forceinline__ ushort rnb(float x) {
    unsigned u = __float_as_uint(x);
    unsigned r = (u + 0x7fffu + ((u >> 16) & 1u)) >> 16;
    return (ushort)r;
}
__device__ __forceinline__ float bf2f(ushort u) {
    return __uint_as_float(((unsigned)u) << 16);
}
__device__ __forceinline__ s8b ldg8(const ushort* p) { return *(const s8b*)p; }

// ---------------- utility ----------------
__global__ void k_zero(float* __restrict__ p, int n) {
    int i = blockIdx.x * blockDim.x + threadIdx.x;
    if (i < n) p[i] = 0.f;
}
__global__ void k_zero_int(int* __restrict__ p, int n) {
    int i = blockIdx.x * blockDim.x + threadIdx.x;
    if (i < n) p[i] = 0;
}
__global__ void k_copy(const float* __restrict__ a, float* __restrict__ b, int n) {
    int i = blockIdx.x * blockDim.x + threadIdx.x;
    if (i < n) b[i] = a[i];
}

// V = emb_nodes @ pre_Wn + pre_bn -> bf16
__global__ void k_vinit(const float* __restrict__ en, const float* __restrict__ Wn,
                        const float* __restrict__ bn, ushort* __restrict__ Vb) {
    int idx = blockIdx.x * blockDim.x + threadIdx.x;
    if (idx >= NN * HH) return;
    int i = idx >> 7, j = idx & 127;
    float v = fmaf(en[i * 3 + 0], Wn[j], bn[j]);
    v = fmaf(en[i * 3 + 1], Wn[HH + j], v);
    v = fmaf(en[i * 3 + 2], Wn[2 * HH + j], v);
    Vb[idx] = rnb(v);
}

// ---------------- weight transpose -> bf16, dest [n][K] ----------------
// per layer (shorts): We1t @0 (K=256), We2t @32768 (K=128), Wx1t @49152 (K=128),
//                     Wh1t @65536 (K=256), Wh2t @98304 (K=128). layer stride 114688.
__global__ void k_wprep(const float* __restrict__ We1, const float* __restrict__ We2,
                        const float* __restrict__ Wx1, const float* __restrict__ Wh1,
                        const float* __restrict__ Wh2, ushort* __restrict__ Wb) {
    int idx = blockIdx.x * 256 + threadIdx.x;
    if (idx >= 344064) return;
    int layer = idx / 114688;
    int r = idx - layer * 114688;
    const float* src; int K; int roff;
    if (r < 32768)      { src = We1 + (size_t)layer * 33152; K = 256; roff = r; }
    else if (r < 49152) { src = We2 + (size_t)layer * 16384; K = 128; roff = r - 32768; }
    else if (r < 65536) { src = Wx1 + (size_t)layer * 16384; K = 128; roff = r - 49152; }
    else if (r < 98304) { src = Wh1 + (size_t)layer * 32768; K = 256; roff = r - 65536; }
    else                { src = Wh2 + (size_t)layer * 16384; K = 128; roff = r - 98304; }
    int n = roff / K, k = roff - n * K;
    Wb[idx] = rnb(src[k * 128 + n]);
}

// ---------------- CSR build ----------------
__global__ void k_hist(const int* __restrict__ dst, int* __restrict__ deg) {
    int e = blockIdx.x * blockDim.x + threadIdx.x;
    if (e < NE) atomicAdd(&deg[dst[e]], 1);
}
__global__ __launch_bounds__(256)
void k_scan(const int* __restrict__ deg, int* __restrict__ offs, int* __restrict__ cur) {
    __shared__ int part[256];
    const int t = threadIdx.x;
    const int s0 = t * 40, s1 = min(s0 + 40, NN);
    int s = 0;
    for (int i = s0; i < s1; ++i) s += deg[i];
    part[t] = s;
    __syncthreads();
    if (t == 0) {
        int r = 0;
        for (int i = 0; i < 256; ++i) { int v = part[i]; part[i] = r; r += v; }
    }
    __syncthreads();
    int r = part[t];
    for (int i = s0; i < s1; ++i) { offs[i] = r; cur[i] = r; r += deg[i]; }
    if (t == 255) offs[NN] = r;
}
__global__ void k_fill(const int* __restrict__ dst, int* __restrict__ cur, int* __restrict__ eid) {
    int e = blockIdx.x * blockDim.x + threadIdx.x;
    if (e < NE) {
        int p = atomicAdd(&cur[dst[e]], 1);
        eid[p] = e;
    }
}

// diff4 = (dx,dy,dz,dist)
__global__ void k_eprep(const float* __restrict__ coords, const int* __restrict__ src,
                        const int* __restrict__ dst, float4* __restrict__ diff4) {
    int e = blockIdx.x * blockDim.x + threadIdx.x;
    if (e >= NE) return;
    int s = src[e], d = dst[e];
    float dx = coords[d * 3 + 0] - coords[s * 3 + 0];
    float dy = coords[d * 3 + 1] - coords[s * 3 + 1];
    float dz = coords[d * 3 + 2] - coords[s * 3 + 2];
    float dist = sqrtf(dx * dx + dy * dy + dz * dz);
    diff4[e] = make_float4(dx, dy, dz, dist);
}

// ================= fused edge kernel: mij = silu(silu(h@We1+be1)@We2+be2) =================
// 64 edge rows/block, 256 thr (4 waves, 2x2 wave grid; wave tile 32x64, M_rep=2,N_rep=4)
// pure-bf16 operands, fp32 accum; 5 blocks/CU (LDS ~21.8KB)
__global__ __launch_bounds__(256, 5)
void k_efused(const ushort* __restrict__ Vb,
              const int* __restrict__ src, const int* __restrict__ dst,
              const float4* __restrict__ diff4, const float* __restrict__ ee,
              const ushort* __restrict__ W1b,   // [128][256]
              const float* __restrict__ We1f, const float* __restrict__ be1,
              const ushort* __restrict__ W2b,   // [128][128]
              const float* __restrict__ be2, ushort* __restrict__ mijb) {
    __shared__ ushort t1b[4][64][40];
    __shared__ int sid[64], did[64];
    __shared__ float dd[64], eAa[64], eBb[64];
    const int t = threadIdx.x;
    const int lane = t & 63;
    const int w = t >> 6;
    const int wr = w >> 1, wc = w & 1;
    const int e0 = blockIdx.x * 64;
    if (t < 64) {
        int e = e0 + t;
        sid[t] = src[e]; did[t] = dst[e];
        float4 q = diff4[e];
        dd[t] = q.w; eAa[t] = ee[2 * e]; eBb[t] = ee[2 * e + 1];
    }
    __syncthreads();
    const int l15 = lane & 15, lq = lane >> 4;
    f32x4 acc[2][4];
#pragma unroll
    for (int i = 0; i < 2; ++i)
#pragma unroll
        for (int j = 0; j < 4; ++j) acc[i][j] = (f32x4){0.f, 0.f, 0.f, 0.f};

    // ---- phase A: K=256 over [V[src] | V[dst]] ----
#pragma unroll
    for (int half = 0; half < 2; ++half) {
        const int* ids = half ? did : sid;
#pragma unroll
        for (int kt = 0; kt < 4; ++kt) {
            const int wk = half * 128 + kt * 32;
            s8b a[2], b[4];
#pragma unroll
            for (int mi = 0; mi < 2; ++mi) {
                int row = ids[wr * 32 + mi * 16 + l15];
                a[mi] = ldg8(Vb + (size_t)row * HH + kt * 32 + lq * 8);
            }
#pragma unroll
            for (int ni = 0; ni < 4; ++ni) {
                int col = wc * 64 + ni * 16 + l15;
                b[ni] = ldg8(W1b + (size_t)col * 256 + wk + lq * 8);
            }
#pragma unroll
            for (int mi = 0; mi < 2; ++mi)
#pragma unroll
                for (int ni = 0; ni < 4; ++ni)
                    acc[mi][ni] = MFMA16(a[mi], b[ni], acc[mi][ni], 0, 0, 0);
        }
    }
    // ---- phase A epilogue: rank-1 fixups (dist, ee) + bias + silu -> t1 LDS (bf16) ----
#pragma unroll
    for (int mi = 0; mi < 2; ++mi)
#pragma unroll
        for (int ni = 0; ni < 4; ++ni) {
            int col = wc * 64 + ni * 16 + l15;
            float w256 = We1f[256 * HH + col];
            float w257 = We1f[257 * HH + col];
            float w258 = We1f[258 * HH + col];
            float bi = be1[col];
            int kt = col >> 5, c = col & 31;
#pragma unroll
            for (int r = 0; r < 4; ++r) {
                int m = wr * 32 + mi * 16 + lq * 4 + r;
                float v = acc[mi][ni][r] + bi;
                v = fmaf(dd[m], w256, v);
                v = fmaf(eAa[m], w257, v);
                v = fmaf(eBb[m], w258, v);
                t1b[kt][m][c] = rnb(silu_f(v));
                acc[mi][ni][r] = 0.f;
            }
        }
    __syncthreads();
    // ---- phase B: K=128 over t1 ----
#pragma unroll
    for (int kt = 0; kt < 4; ++kt) {
        s8b a[2], b[4];
#pragma unroll
        for (int mi = 0; mi < 2; ++mi) {
            int row = wr * 32 + mi * 16 + l15;
            a[mi] = *(const s8b*)&t1b[kt][row][lq * 8];
        }
#pragma unroll
        for (int ni = 0; ni < 4; ++ni) {
            int col = wc * 64 + ni * 16 + l15;
            b[ni] = ldg8(W2b + (size_t)col * 128 + kt * 32 + lq * 8);
        }
#pragma unroll
        for (int mi = 0; mi < 2; ++mi)
#pragma unroll
            for (int ni = 0; ni < 4; ++ni)
                acc[mi][ni] = MFMA16(a[mi], b[ni], acc[mi][ni], 0, 0, 0);
    }
    // ---- phase B epilogue: silu -> mij (bf16, global) ----
#pragma unroll
    for (int mi = 0; mi < 2; ++mi)
#pragma unroll
        for (int ni = 0; ni < 4; ++ni) {
            int col = wc * 64 + ni * 16 + l15;
            float bi = be2[col];
#pragma unroll
            for (int r = 0; r < 4; ++r) {
                int m = wr * 32 + mi * 16 + lq * 4 + r;
                mijb[(size_t)(e0 + m) * HH + col] = rnb(silu_f(acc[mi][ni][r] + bi));
            }
        }
}

// ---------------- mi = segment_sum(mij, dst) via CSR gather (bf16 in/out, fp32 accum) ----------------
__global__ __launch_bounds__(128)
void k_mi(const ushort* __restrict__ mijb, const int* __restrict__ offs,
          const int* __restrict__ eid, ushort* __restrict__ mib) {
    const int n = blockIdx.x;
    const int t = threadIdx.x;
    const int b = offs[n], e = offs[n + 1];
    float s = 0.f;
    for (int j = b; j < e; ++j)
        s += bf2f(mijb[(size_t)eid[j] * HH + t]);
    mib[(size_t)n * HH + t] = rnb(s);
}

// ---------------- egemm3: t2 = silu(mij @ Wx1 + bx1) (MFMA, Ts in LDS); px = t2@Wx2+bx2 ----------------
__global__ __launch_bounds__(256, 4)
void k_egemm3(const ushort* __restrict__ mijb, const float4* __restrict__ diff4,
              const ushort* __restrict__ Bb,   // Wx1t [128][128]
              const float* __restrict__ bias, const float* __restrict__ W2,
              const float* __restrict__ b2, float4* __restrict__ cd4) {
    __shared__ float Ts[64][133];
    __shared__ float d3[3][64];
    __shared__ float Wxs[HH * 3];
    __shared__ float b2s[3];
    const int t = threadIdx.x;
    const int lane = t & 63;
    const int w = t >> 6;
    const int wr = w >> 1, wc = w & 1;
    const int e0 = blockIdx.x * 64;
    if (t < 64) {
        float4 q = diff4[e0 + t];
        d3[0][t] = q.x; d3[1][t] = q.y; d3[2][t] = q.z;
    }
    for (int i = t; i < HH * 3; i += NT) Wxs[i] = W2[i];
    if (t < 3) b2s[t] = b2[t];
    const int l15 = lane & 15, lq = lane >> 4;
    f32x4 acc[2][4];
#pragma unroll
    for (int i = 0; i < 2; ++i)
#pragma unroll
        for (int j = 0; j < 4; ++j) acc[i][j] = (f32x4){0.f, 0.f, 0.f, 0.f};

#pragma unroll
    for (int kt = 0; kt < 4; ++kt) {
        s8b a[2], b[4];
#pragma unroll
        for (int mi = 0; mi < 2; ++mi) {
            int row = e0 + wr * 32 + mi * 16 + l15;
            a[mi] = ldg8(mijb + (size_t)row * HH + kt * 32 + lq * 8);
        }
#pragma unroll
        for (int ni = 0; ni < 4; ++ni) {
            int col = wc * 64 + ni * 16 + l15;
            b[ni] = ldg8(Bb + (size_t)col * 128 + kt * 32 + lq * 8);
        }
#pragma unroll
        for (int mi = 0; mi < 2; ++mi)
#pragma unroll
            for (int ni = 0; ni < 4; ++ni)
                acc[mi][ni] = MFMA16(a[mi], b[ni], acc[mi][ni], 0, 0, 0);
    }
#pragma unroll
    for (int mi = 0; mi < 2; ++mi)
#pragma unroll
        for (int ni = 0; ni < 4; ++ni) {
            int col = wc * 64 + ni * 16 + l15;
            float bi = bias[col];
#pragma unroll
            for (int r = 0; r < 4; ++r) {
                int m = wr * 32 + mi * 16 + lq * 4 + r;
                Ts[m][col] = silu_f(acc[mi][ni][r] + bi);
            }
        }
    __syncthreads();
    if (t < 192) {
        int r = t / 3;
        int col = t - 3 * r;
        float s = b2s[col];
#pragma unroll 16
        for (int k = 0; k < HH; ++k)
            s = fmaf(Ts[r][k], Wxs[k * 3 + col], s);
        ((float*)&cd4[e0 + r])[col] = d3[col][r] * s;
    }
}

// ---------------- coords += CSR-gather(cd4)/(N-1) ----------------
__global__ void k_coordupd(float* __restrict__ coords, const float4* __restrict__ cd4,
                           const int* __restrict__ offs, const int* __restrict__ eid) {
    int idx = blockIdx.x * blockDim.x + threadIdx.x;
    if (idx >= NN * 3) return;
    int n = idx / 3, c = idx - 3 * n;
    int b = offs[n], e = offs[n + 1];
    float s = 0.f;
    for (int j = b; j < e; ++j)
        s += ((const float*)&cd4[eid[j]])[c];
    coords[idx] += s * (1.f / (NN - 1));
}

// ---------------- node GEMM 1: u = silu([V,mi] @ Wh1 + bh1)  (MFMA, bf16) ----------------
__global__ __launch_bounds__(256, 4)
void k_ngemm1(const ushort* __restrict__ Vb, const ushort* __restrict__ mib,
              const ushort* __restrict__ Bb,   // Wh1t [128][256]
              const float* __restrict__ bias, ushort* __restrict__ ub) {
    const int t = threadIdx.x;
    const int lane = t & 63;
    const int w = t >> 6;
    const int wr = w >> 1, wc = w & 1;
    const int r0 = blockIdx.x * 64;
    const int l15 = lane & 15, lq = lane >> 4;
    f32x4 acc[2][4];
#pragma unroll
    for (int i = 0; i < 2; ++i)
#pragma unroll
        for (int j = 0; j < 4; ++j) acc[i][j] = (f32x4){0.f, 0.f, 0.f, 0.f};

#pragma unroll
    for (int kk = 0; kk < 8; ++kk) {
        const ushort* Ap = (kk < 4) ? Vb : mib;
        const int k0 = (kk & 3) * 32;
        s8b a[2], b[4];
#pragma unroll
        for (int mi_ = 0; mi_ < 2; ++mi_) {
            int row = r0 + wr * 32 + mi_ * 16 + l15;
            if (row >= NN) row = NN - 1;
            a[mi_] = ldg8(Ap + (size_t)row * HH + k0 + lq * 8);
        }
#pragma unroll
        for (int ni = 0; ni < 4; ++ni) {
            int col = wc * 64 + ni * 16 + l15;
            b[ni] = ldg8(Bb + (size_t)col * 256 + kk * 32 + lq * 8);
        }
#pragma unroll
        for (int mi_ = 0; mi_ < 2; ++mi_)
#pragma unroll
            for (int ni = 0; ni < 4; ++ni)
                acc[mi_][ni] = MFMA16(a[mi_], b[ni], acc[mi_][ni], 0, 0, 0);
    }
#pragma unroll
    for (int mi_ = 0; mi_ < 2; ++mi_)
#pragma unroll
        for (int ni = 0; ni < 4; ++ni) {
            int col = wc * 64 + ni * 16 + l15;
            float bi = bias[col];
#pragma unroll
            for (int r = 0; r < 4; ++r) {
                int m = r0 + wr * 32 + mi_ * 16 + lq * 4 + r;
                if (m < NN) ub[(size_t)m * HH + col] = rnb(silu_f(acc[mi_][ni][r] + bi));
            }
        }
}

// ---------------- node GEMM 2: X = elu(u @ Wh2 + bh2) + column stats (MFMA, bf16) ----------------
__global__ __launch_bounds__(256, 4)
void k_ngemm2(const ushort* __restrict__ ub,
              const ushort* __restrict__ Bb,   // Wh2t [128][128]
              const float* __restrict__ bias, float* __restrict__ X,
              float* __restrict__ ssum, float* __restrict__ ssq) {
    const int t = threadIdx.x;
    const int lane = t & 63;
    const int w = t >> 6;
    const int wr = w >> 1, wc = w & 1;
    const int r0 = blockIdx.x * 64;
    const int l15 = lane & 15, lq = lane >> 4;
    f32x4 acc[2][4];
#pragma unroll
    for (int i = 0; i < 2; ++i)
#pragma unroll
        for (int j = 0; j < 4; ++j) acc[i][j] = (f32x4){0.f, 0.f, 0.f, 0.f};

#pragma unroll
    for (int kt = 0; kt < 4; ++kt) {
        s8b a[2], b[4];
#pragma unroll
        for (int mi_ = 0; mi_ < 2; ++mi_) {
            int row = r0 + wr * 32 + mi_ * 16 + l15;
            if (row >= NN) row = NN - 1;
            a[mi_] = ldg8(ub + (size_t)row * HH + kt * 32 + lq * 8);
        }
#pragma unroll
        for (int ni = 0; ni < 4; ++ni) {
            int col = wc * 64 + ni * 16 + l15;
            b[ni] = ldg8(Bb + (size_t)col * 128 + kt * 32 + lq * 8);
        }
#pragma unroll
        for (int mi_ = 0; mi_ < 2; ++mi_)
#pragma unroll
            for (int ni = 0; ni < 4; ++ni)
                acc[mi_][ni] = MFMA16(a[mi_], b[ni], acc[mi_][ni], 0, 0, 0);
    }
    float s[4] = {0.f, 0.f, 0.f, 0.f}, q[4] = {0.f, 0.f, 0.f, 0.f};
#pragma unroll
    for (int mi_ = 0; mi_ < 2; ++mi_)
#pragma unroll
        for (int ni = 0; ni < 4; ++ni) {
            int col = wc * 64 + ni * 16 + l15;
            float bi = bias[col];
#pragma unroll
            for (int r = 0; r < 4; ++r) {
                int m = r0 + wr * 32 + mi_ * 16 + lq * 4 + r;
                float v = elu_f(acc[mi_][ni][r] + bi);
                if (m < NN) {
                    X[(size_t)m * HH + col] = v;
                    s[ni] += v; q[ni] += v * v;
                }
            }
        }
#pragma unroll
    for (int j = 0; j < 4; ++j) {
        s[j] += __shfl_xor(s[j], 16);
        s[j] += __shfl_xor(s[j], 32);
        q[j] += __shfl_xor(q[j], 16);
        q[j] += __shfl_xor(q[j], 32);
    }
    if (lane < 16) {
#pragma unroll
        for (int j = 0; j < 4; ++j) {
            int col = wc * 64 + j * 16 + l15;
            atomicAdd(&ssum[col], s[j]);
            atomicAdd(&ssq[col], q[j]);
        }
    }
}

// ---------------- node batchnorm apply (-> bf16 V or fp32 out) ----------------
__global__ void k_bnorm_nodes(const float* __restrict__ X, const float* __restrict__ ssum,
                              const float* __restrict__ ssq, const float* __restrict__ gam,
                              const float* __restrict__ bet, float* __restrict__ outf,
                              ushort* __restrict__ outb, int writeb) {
    int idx = blockIdx.x * blockDim.x + threadIdx.x;
    if (idx >= NN * HH) return;
    int c = idx & 127;
    float mu = ssum[c] * (1.f / NN);
    float var = ssq[c] * (1.f / NN) - mu * mu;
    float v = fmaf(gam[c] * (X[idx] - mu), rsqrtf(var + EPSBN), bet[c]);
    if (writeb) outb[idx] = rnb(v);
    else        outf[idx] = v;
}

// ---------------- edge stats over elu(mij) (last layer only) ----------------
__global__ __launch_bounds__(256)
void k_estats(const ushort* __restrict__ mijb, float* __restrict__ ssum, float* __restrict__ ssq) {
    const int t = threadIdx.x;
    const int col = t & 127;
    const int half = t >> 7;
    const int rbase = blockIdx.x * 250;
    float s = 0.f, q = 0.f;
    for (int r = rbase + half; r < rbase + 250; r += 2) {
        float x = elu_f(bf2f(mijb[(size_t)r * HH + col]));
        s += x; q += x * x;
    }
    atomicAdd(&ssum[col], s);
    atomicAdd(&ssq[col], q);
}

// ---------------- edge batchnorm apply -> output E ----------------
__global__ void k_bnorm_edges(const ushort* __restrict__ mijb, const float* __restrict__ ssum,
                              const float* __restrict__ ssq, const float* __restrict__ gam,
                              const float* __restrict__ bet, float* __restrict__ out) {
    size_t stride = (size_t)gridDim.x * blockDim.x;
    for (size_t idx = (size_t)blockIdx.x * blockDim.x + threadIdx.x; idx < (size_t)NE * HH; idx += stride) {
        int c = (int)(idx & 127);
        float x = elu_f(bf2f(mijb[idx]));
        float mu = ssum[c] * (1.f / NE);
        float var = ssq[c] * (1.f / NE) - mu * mu;
        out[idx] = fmaf(gam[c] * (x - mu), rsqrtf(var + EPSBN), bet[c]);
    }
}

extern "C" void kernel_launch(void* const* d_in, const int* in_sizes, int n_in,
                              void* d_out, int out_size, void* d_ws, size_t ws_size,
                              hipStream_t stream) {
    (void)in_sizes; (void)n_in; (void)out_size; (void)ws_size;
    const float* emb_nodes = (const float*)d_in[0];
    const float* emb_edges = (const float*)d_in[1];
    const int*   eidx      = (const int*)d_in[2];
    const float* pre_Wn = (const float*)d_in[3];
    const float* pre_bn = (const float*)d_in[4];
    const float* We1 = (const float*)d_in[7];
    const float* be1 = (const float*)d_in[8];
    const float* We2 = (const float*)d_in[9];
    const float* be2 = (const float*)d_in[10];
    const float* Wx1 = (const float*)d_in[11];
    const float* bx1 = (const float*)d_in[12];
    const float* Wx2 = (const float*)d_in[13];
    const float* bx2 = (const float*)d_in[14];
    const float* Wh1 = (const float*)d_in[15];
    const float* bh1 = (const float*)d_in[16];
    const float* Wh2 = (const float*)d_in[17];
    const float* bh2 = (const float*)d_in[18];
    const float* gam_n = (const float*)d_in[19];
    const float* bet_n = (const float*)d_in[20];
    const float* gam_e = (const float*)d_in[21];
    const float* bet_e = (const float*)d_in[22];

    const int* src = eidx;
    const int* dst = eidx + NE;

    // Workspace layout (float offsets). bf16 buffers sized as elems/2 floats.
    float* ws = (float*)d_ws;
    float*   coords = ws;                         // [0, 30000)
    float4*  diff4  = (float4*)(ws + 30000);      // [30000, 670000)
    ushort*  Vb     = (ushort*)(ws + 670000);     // 1.28M ush -> [670000, 1310000)
    ushort*  mib    = (ushort*)(ws + 1310000);    // [1310000, 1950000)
    ushort*  ub     = (ushort*)(ws + 1950000);    // [1950000, 2590000)
    float*   X      = ws + 2590000;               // [2590000, 3870000)
    float4*  cd4    = (float4*)(ws + 3870000);    // [3870000, 4510000)
    ushort*  mijb   = (ushort*)(ws + 4510000);    // 20.48M ush -> [4510000, 14750000)
    float*   snN    = ws + 14750000;              // 128
    float*   sqN    = ws + 14750128;
    float*   snE    = ws + 14750256;
    float*   sqE    = ws + 14750384;
    ushort*  Wb     = (ushort*)(ws + 14750512);   // 344064 ush -> [14750512, 14922544)
    int*     I0     = (int*)(ws + 14922544);
    int*     deg    = I0;
    int*     offs   = I0 + 10000;
    int*     cur    = I0 + 20001;
    int*     eid    = I0 + 30001;

    float* outV = (float*)d_out;
    float* outE = (float*)d_out + (size_t)NN * HH;

    k_copy<<<(30000 + 255) / 256, 256, 0, stream>>>(emb_nodes, coords, 30000);
    k_vinit<<<(NN * HH + 255) / 256, 256, 0, stream>>>(emb_nodes, pre_Wn, pre_bn, Vb);
    k_wprep<<<1344, 256, 0, stream>>>(We1, We2, Wx1, Wh1, Wh2, Wb);

    k_zero_int<<<(NN + 255) / 256, 256, 0, stream>>>(deg, NN);
    k_hist<<<(NE + 255) / 256, 256, 0, stream>>>(dst, deg);
    k_scan<<<1, 256, 0, stream>>>(deg, offs, cur);
    k_fill<<<(NE + 255) / 256, 256, 0, stream>>>(dst, cur, eid);

    for (int l = 0; l < 3; ++l) {
        const float* We1l = We1 + (size_t)l * 259 * 128;
        const float* be1l = be1 + l * 128;
        const float* be2l = be2 + l * 128;
        const float* bx1l = bx1 + l * 128;
        const float* Wx2l = Wx2 + (size_t)l * 128 * 3;
        const float* bx2l = bx2 + l * 3;
        const float* bh1l = bh1 + l * 128;
        const float* bh2l = bh2 + l * 128;
        const size_t L = (size_t)l * 114688;
        const ushort* W1b = Wb + L;              // We1t [128][256]
        const ushort* W2b = Wb + L + 32768;      // We2t [128][128]
        const ushort* Wxb = Wb + L + 49152;      // Wx1t [128][128]
        const ushort* Whb = Wb + L + 65536;      // Wh1t [128][256]
        const ushort* Wgb = Wb + L + 98304;      // Wh2t [128][128]

        k_zero<<<2, 256, 0, stream>>>(snN, 512);
        k_eprep<<<(NE + 255) / 256, 256, 0, stream>>>(coords, src, dst, diff4);
        k_efused<<<NE / 64, NT, 0, stream>>>(Vb, src, dst, diff4, emb_edges,
                                             W1b, We1l, be1l, W2b, be2l, mijb);
        k_egemm3<<<NE / 64, NT, 0, stream>>>(mijb, diff4, Wxb, bx1l, Wx2l, bx2l, cd4);
        k_mi<<<NN, 128, 0, stream>>>(mijb, offs, eid, mib);
        k_coordupd<<<(NN * 3 + 255) / 256, 256, 0, stream>>>(coords, cd4, offs, eid);
        k_ngemm1<<<(NN + 63) / 64, NT, 0, stream>>>(Vb, mib, Whb, bh1l, ub);
        k_ngemm2<<<(NN + 63) / 64, NT, 0, stream>>>(ub, Wgb, bh2l, X, snN, sqN);
        k_bnorm_nodes<<<(NN * HH + 255) / 256, 256, 0, stream>>>(X, snN, sqN, gam_n + l * 128,
                                                                 bet_n + l * 128,
                                                                 outV, Vb, (l < 2) ? 1 : 0);
        if (l == 2) {
            k_estats<<<640, 256, 0, stream>>>(mijb, snE, sqE);
            k_bnorm_edges<<<4096, 256, 0, stream>>>(mijb, snE, sqE, gam_e + l * 128, bet_e + l * 128, outE);
        }
    }
}

// Round 7
// 852.167 us; speedup vs baseline: 2.6879x; 1.0218x over previous
//
#include <hip/hip_runtime.h>
#include <hip/hip_bf16.h>
#include <math.h>

#define NN 10000
#define NE 160000
#define HH 128
#define EPSBN 1e-5f

typedef __attribute__((ext_vector_type(8))) short s8b;   // 8 bf16 (as shorts)
typedef __attribute__((ext_vector_type(4))) float f32x4;

#define MFMA16 __builtin_amdgcn_mfma_f32_16x16x32_bf16

__device__ __forceinline__ float silu_f(float x) { return x / (1.f + __expf(-x)); }
__device__ __forceinline__ float elu_f(float x)  { return x > 0.f ? x : expm1f(x); }

// fp32 -> bf16 round-to-nearest-even
__device__ __forceinline__ ushort rnb(float x) {
    unsigned u = __float_as_uint(x);
    unsigned r = (u + 0x7fffu + ((u >> 16) & 1u)) >> 16;
    return (ushort)r;
}
__device__ __forceinline__ float bf2f(ushort u) {
    return __uint_as_float(((unsigned)u) << 16);
}
__device__ __forceinline__ s8b ldg8(const ushort* p) { return *(const s8b*)p; }

// ---------------- utility ----------------
__global__ void k_zero(float* __restrict__ p, int n) {
    int i = blockIdx.x * blockDim.x + threadIdx.x;
    if (i < n) p[i] = 0.f;
}
__global__ void k_zero_int(int* __restrict__ p, int n) {
    int i = blockIdx.x * blockDim.x + threadIdx.x;
    if (i < n) p[i] = 0;
}
__global__ void k_copy(const float* __restrict__ a, float* __restrict__ b, int n) {
    int i = blockIdx.x * blockDim.x + threadIdx.x;
    if (i < n) b[i] = a[i];
}

// V = emb_nodes @ pre_Wn + pre_bn -> bf16
__global__ void k_vinit(const float* __restrict__ en, const float* __restrict__ Wn,
                        const float* __restrict__ bn, ushort* __restrict__ Vb) {
    int idx = blockIdx.x * blockDim.x + threadIdx.x;
    if (idx >= NN * HH) return;
    int i = idx >> 7, j = idx & 127;
    float v = fmaf(en[i * 3 + 0], Wn[j], bn[j]);
    v = fmaf(en[i * 3 + 1], Wn[HH + j], v);
    v = fmaf(en[i * 3 + 2], Wn[2 * HH + j], v);
    Vb[idx] = rnb(v);
}

// ---------------- weight transpose -> bf16, dest [n][K] ----------------
// per layer (shorts): We1t @0 (K=256), We2t @32768 (K=128), Wx1t @49152 (K=128),
//                     Wh1t @65536 (K=256), Wh2t @98304 (K=128). layer stride 114688.
__global__ void k_wprep(const float* __restrict__ We1, const float* __restrict__ We2,
                        const float* __restrict__ Wx1, const float* __restrict__ Wh1,
                        const float* __restrict__ Wh2, ushort* __restrict__ Wb) {
    int idx = blockIdx.x * 256 + threadIdx.x;
    if (idx >= 344064) return;
    int layer = idx / 114688;
    int r = idx - layer * 114688;
    const float* src; int K; int roff;
    if (r < 32768)      { src = We1 + (size_t)layer * 33152; K = 256; roff = r; }
    else if (r < 49152) { src = We2 + (size_t)layer * 16384; K = 128; roff = r - 32768; }
    else if (r < 65536) { src = Wx1 + (size_t)layer * 16384; K = 128; roff = r - 49152; }
    else if (r < 98304) { src = Wh1 + (size_t)layer * 32768; K = 256; roff = r - 65536; }
    else                { src = Wh2 + (size_t)layer * 16384; K = 128; roff = r - 98304; }
    int n = roff / K, k = roff - n * K;
    Wb[idx] = rnb(src[k * 128 + n]);
}

// Wx2t: [layer][16][128] bf16, rows >=3 zero-padded
__global__ void k_wx2prep(const float* __restrict__ Wx2, ushort* __restrict__ Wx2b) {
    int idx = blockIdx.x * 256 + threadIdx.x;
    if (idx >= 3 * 16 * 128) return;
    int layer = idx / 2048;
    int r = idx - layer * 2048;
    int n = r >> 7, k = r & 127;
    Wx2b[idx] = (n < 3) ? rnb(Wx2[layer * 384 + k * 3 + n]) : (ushort)0;
}

// ---------------- CSR build ----------------
__global__ void k_hist(const int* __restrict__ dst, int* __restrict__ deg) {
    int e = blockIdx.x * blockDim.x + threadIdx.x;
    if (e < NE) atomicAdd(&deg[dst[e]], 1);
}
__global__ __launch_bounds__(256)
void k_scan(const int* __restrict__ deg, int* __restrict__ offs, int* __restrict__ cur) {
    __shared__ int part[256];
    const int t = threadIdx.x;
    const int s0 = t * 40, s1 = min(s0 + 40, NN);
    int s = 0;
    for (int i = s0; i < s1; ++i) s += deg[i];
    part[t] = s;
    __syncthreads();
    if (t == 0) {
        int r = 0;
        for (int i = 0; i < 256; ++i) { int v = part[i]; part[i] = r; r += v; }
    }
    __syncthreads();
    int r = part[t];
    for (int i = s0; i < s1; ++i) { offs[i] = r; cur[i] = r; r += deg[i]; }
    if (t == 255) offs[NN] = r;
}
__global__ void k_fill(const int* __restrict__ dst, int* __restrict__ cur, int* __restrict__ eid) {
    int e = blockIdx.x * blockDim.x + threadIdx.x;
    if (e < NE) {
        int p = atomicAdd(&cur[dst[e]], 1);
        eid[p] = e;
    }
}

// ================= mega edge kernel =================
// per block: 128 edges, 512 thr (8 waves: 4 row-groups x 2 col-halves)
// phase A: h @ We1 (K=256 gather) ; B: @We2 -> mij ; C: mij @ Wx1 -> t2 ; D: t2 @ Wx2 -> px -> cd4
__global__ __launch_bounds__(512, 4)
void k_efused(const ushort* __restrict__ Vb,
              const int* __restrict__ src, const int* __restrict__ dst,
              const float* __restrict__ coords, const float* __restrict__ ee,
              const ushort* __restrict__ W1b,   // We1t [128][256]
              const float* __restrict__ We1f, const float* __restrict__ be1,
              const ushort* __restrict__ W2b,   // We2t [128][128]
              const float* __restrict__ be2,
              const ushort* __restrict__ Wxb,   // Wx1t [128][128]
              const float* __restrict__ bx1,
              const ushort* __restrict__ Wx2b,  // Wx2t [16][128]
              const float* __restrict__ bx2,
              ushort* __restrict__ mijb, float4* __restrict__ cd4) {
    __shared__ ushort t1b[4][128][40];
    __shared__ int sid[128], did[128];
    __shared__ float dd[128], eAa[128], eBb[128];
    __shared__ float d3[3][128];
    const int t = threadIdx.x;
    const int lane = t & 63;
    const int w = t >> 6;            // 0..7
    const int wr = w >> 1, wc = w & 1;
    const int e0 = blockIdx.x * 128;
    if (t < 128) {
        int e = e0 + t;
        int s = src[e], d = dst[e];
        sid[t] = s; did[t] = d;
        float dx = coords[d * 3 + 0] - coords[s * 3 + 0];
        float dy = coords[d * 3 + 1] - coords[s * 3 + 1];
        float dz = coords[d * 3 + 2] - coords[s * 3 + 2];
        dd[t] = sqrtf(dx * dx + dy * dy + dz * dz);
        d3[0][t] = dx; d3[1][t] = dy; d3[2][t] = dz;
        eAa[t] = ee[2 * e]; eBb[t] = ee[2 * e + 1];
    }
    __syncthreads();
    const int l15 = lane & 15, lq = lane >> 4;
    f32x4 acc[2][4];
#pragma unroll
    for (int i = 0; i < 2; ++i)
#pragma unroll
        for (int j = 0; j < 4; ++j) acc[i][j] = (f32x4){0.f, 0.f, 0.f, 0.f};

    // ---- phase A: K=256 over [V[src] | V[dst]] ----
#pragma unroll
    for (int half = 0; half < 2; ++half) {
        const int* ids = half ? did : sid;
#pragma unroll
        for (int kt = 0; kt < 4; ++kt) {
            const int wk = half * 128 + kt * 32;
            s8b a[2], b[4];
#pragma unroll
            for (int mi = 0; mi < 2; ++mi) {
                int row = ids[wr * 32 + mi * 16 + l15];
                a[mi] = ldg8(Vb + (size_t)row * HH + kt * 32 + lq * 8);
            }
#pragma unroll
            for (int ni = 0; ni < 4; ++ni) {
                int col = wc * 64 + ni * 16 + l15;
                b[ni] = ldg8(W1b + (size_t)col * 256 + wk + lq * 8);
            }
#pragma unroll
            for (int mi = 0; mi < 2; ++mi)
#pragma unroll
                for (int ni = 0; ni < 4; ++ni)
                    acc[mi][ni] = MFMA16(a[mi], b[ni], acc[mi][ni], 0, 0, 0);
        }
    }
    // ---- epilogue A: rank-1 fixups + bias + silu -> t1 (bf16 LDS) ----
#pragma unroll
    for (int mi = 0; mi < 2; ++mi)
#pragma unroll
        for (int ni = 0; ni < 4; ++ni) {
            int col = wc * 64 + ni * 16 + l15;
            float w256 = We1f[256 * HH + col];
            float w257 = We1f[257 * HH + col];
            float w258 = We1f[258 * HH + col];
            float bi = be1[col];
            int kt = col >> 5, c = col & 31;
#pragma unroll
            for (int r = 0; r < 4; ++r) {
                int m = wr * 32 + mi * 16 + lq * 4 + r;
                float v = acc[mi][ni][r] + bi;
                v = fmaf(dd[m], w256, v);
                v = fmaf(eAa[m], w257, v);
                v = fmaf(eBb[m], w258, v);
                t1b[kt][m][c] = rnb(silu_f(v));
                acc[mi][ni][r] = 0.f;
            }
        }
    __syncthreads();
    // ---- phase B: mij = silu(t1 @ We2 + be2) ----
#pragma unroll
    for (int kt = 0; kt < 4; ++kt) {
        s8b a[2], b[4];
#pragma unroll
        for (int mi = 0; mi < 2; ++mi) {
            int row = wr * 32 + mi * 16 + l15;
            a[mi] = *(const s8b*)&t1b[kt][row][lq * 8];
        }
#pragma unroll
        for (int ni = 0; ni < 4; ++ni) {
            int col = wc * 64 + ni * 16 + l15;
            b[ni] = ldg8(W2b + (size_t)col * 128 + kt * 32 + lq * 8);
        }
#pragma unroll
        for (int mi = 0; mi < 2; ++mi)
#pragma unroll
            for (int ni = 0; ni < 4; ++ni)
                acc[mi][ni] = MFMA16(a[mi], b[ni], acc[mi][ni], 0, 0, 0);
    }
    __syncthreads();   // all t1 reads done before overwrite
    // ---- epilogue B: mij -> global + LDS ----
#pragma unroll
    for (int mi = 0; mi < 2; ++mi)
#pragma unroll
        for (int ni = 0; ni < 4; ++ni) {
            int col = wc * 64 + ni * 16 + l15;
            float bi = be2[col];
            int kt = col >> 5, c = col & 31;
#pragma unroll
            for (int r = 0; r < 4; ++r) {
                int m = wr * 32 + mi * 16 + lq * 4 + r;
                ushort mv = rnb(silu_f(acc[mi][ni][r] + bi));
                mijb[(size_t)(e0 + m) * HH + col] = mv;
                t1b[kt][m][c] = mv;
                acc[mi][ni][r] = 0.f;
            }
        }
    __syncthreads();
    // ---- phase C: t2 = silu(mij @ Wx1 + bx1) ----
#pragma unroll
    for (int kt = 0; kt < 4; ++kt) {
        s8b a[2], b[4];
#pragma unroll
        for (int mi = 0; mi < 2; ++mi) {
            int row = wr * 32 + mi * 16 + l15;
            a[mi] = *(const s8b*)&t1b[kt][row][lq * 8];
        }
#pragma unroll
        for (int ni = 0; ni < 4; ++ni) {
            int col = wc * 64 + ni * 16 + l15;
            b[ni] = ldg8(Wxb + (size_t)col * 128 + kt * 32 + lq * 8);
        }
#pragma unroll
        for (int mi = 0; mi < 2; ++mi)
#pragma unroll
            for (int ni = 0; ni < 4; ++ni)
                acc[mi][ni] = MFMA16(a[mi], b[ni], acc[mi][ni], 0, 0, 0);
    }
    __syncthreads();   // mij reads done
    // ---- epilogue C: t2 -> LDS ----
#pragma unroll
    for (int mi = 0; mi < 2; ++mi)
#pragma unroll
        for (int ni = 0; ni < 4; ++ni) {
            int col = wc * 64 + ni * 16 + l15;
            float bi = bx1[col];
            int kt = col >> 5, c = col & 31;
#pragma unroll
            for (int r = 0; r < 4; ++r) {
                int m = wr * 32 + mi * 16 + lq * 4 + r;
                t1b[kt][m][c] = rnb(silu_f(acc[mi][ni][r] + bi));
            }
        }
    __syncthreads();
    // ---- phase D: px = t2 @ Wx2 + bx2 ; cd4 = diff * px ----
    // each wave owns 16 rows: w*16..w*16+15
    f32x4 accd = (f32x4){0.f, 0.f, 0.f, 0.f};
#pragma unroll
    for (int kt = 0; kt < 4; ++kt) {
        s8b a = *(const s8b*)&t1b[kt][w * 16 + l15][lq * 8];
        s8b b = ldg8(Wx2b + (size_t)l15 * 128 + kt * 32 + lq * 8);
        accd = MFMA16(a, b, accd, 0, 0, 0);
    }
    if (l15 < 3) {
        float bi = bx2[l15];
#pragma unroll
        for (int r = 0; r < 4; ++r) {
            int row = w * 16 + lq * 4 + r;
            float px = accd[r] + bi;
            ((float*)&cd4[e0 + row])[l15] = d3[l15][row] * px;
        }
    }
}

// ---------------- mi = segment_sum(mij, dst) via CSR gather (bf16 in/out, fp32 accum) ----------------
__global__ __launch_bounds__(128)
void k_mi(const ushort* __restrict__ mijb, const int* __restrict__ offs,
          const int* __restrict__ eid, ushort* __restrict__ mib) {
    const int n = blockIdx.x;
    const int t = threadIdx.x;
    const int b = offs[n], e = offs[n + 1];
    float s = 0.f;
    for (int j = b; j < e; ++j)
        s += bf2f(mijb[(size_t)eid[j] * HH + t]);
    mib[(size_t)n * HH + t] = rnb(s);
}

// ---------------- coords += CSR-gather(cd4)/(N-1) ----------------
__global__ void k_coordupd(float* __restrict__ coords, const float4* __restrict__ cd4,
                           const int* __restrict__ offs, const int* __restrict__ eid) {
    int idx = blockIdx.x * blockDim.x + threadIdx.x;
    if (idx >= NN * 3) return;
    int n = idx / 3, c = idx - 3 * n;
    int b = offs[n], e = offs[n + 1];
    float s = 0.f;
    for (int j = b; j < e; ++j)
        s += ((const float*)&cd4[eid[j]])[c];
    coords[idx] += s * (1.f / (NN - 1));
}

// ================= fused node kernel: X = elu(silu([V,mi]@Wh1+bh1)@Wh2+bh2) + stats =================
// 64 rows/block, 256 thr (4 waves, 2x2)
__global__ __launch_bounds__(256, 5)
void k_nfused(const ushort* __restrict__ Vb, const ushort* __restrict__ mib,
              const ushort* __restrict__ Whb,   // Wh1t [128][256]
              const float* __restrict__ bh1,
              const ushort* __restrict__ Wgb,   // Wh2t [128][128]
              const float* __restrict__ bh2,
              float* __restrict__ X,
              float* __restrict__ ssum, float* __restrict__ ssq) {
    __shared__ ushort tb[4][64][40];
    const int t = threadIdx.x;
    const int lane = t & 63;
    const int w = t >> 6;
    const int wr = w >> 1, wc = w & 1;
    const int r0 = blockIdx.x * 64;
    const int l15 = lane & 15, lq = lane >> 4;
    f32x4 acc[2][4];
#pragma unroll
    for (int i = 0; i < 2; ++i)
#pragma unroll
        for (int j = 0; j < 4; ++j) acc[i][j] = (f32x4){0.f, 0.f, 0.f, 0.f};

    // phase A: K=256 over [V | mi]
#pragma unroll
    for (int kk = 0; kk < 8; ++kk) {
        const ushort* Ap = (kk < 4) ? Vb : mib;
        const int k0 = (kk & 3) * 32;
        s8b a[2], b[4];
#pragma unroll
        for (int mi_ = 0; mi_ < 2; ++mi_) {
            int row = r0 + wr * 32 + mi_ * 16 + l15;
            if (row >= NN) row = NN - 1;
            a[mi_] = ldg8(Ap + (size_t)row * HH + k0 + lq * 8);
        }
#pragma unroll
        for (int ni = 0; ni < 4; ++ni) {
            int col = wc * 64 + ni * 16 + l15;
            b[ni] = ldg8(Whb + (size_t)col * 256 + kk * 32 + lq * 8);
        }
#pragma unroll
        for (int mi_ = 0; mi_ < 2; ++mi_)
#pragma unroll
            for (int ni = 0; ni < 4; ++ni)
                acc[mi_][ni] = MFMA16(a[mi_], b[ni], acc[mi_][ni], 0, 0, 0);
    }
    // epilogue A: u = silu -> LDS
#pragma unroll
    for (int mi_ = 0; mi_ < 2; ++mi_)
#pragma unroll
        for (int ni = 0; ni < 4; ++ni) {
            int col = wc * 64 + ni * 16 + l15;
            float bi = bh1[col];
            int kt = col >> 5, c = col & 31;
#pragma unroll
            for (int r = 0; r < 4; ++r) {
                int m = wr * 32 + mi_ * 16 + lq * 4 + r;
                tb[kt][m][c] = rnb(silu_f(acc[mi_][ni][r] + bi));
                acc[mi_][ni][r] = 0.f;
            }
        }
    __syncthreads();
    // phase B: X = elu(u @ Wh2 + bh2)
#pragma unroll
    for (int kt = 0; kt < 4; ++kt) {
        s8b a[2], b[4];
#pragma unroll
        for (int mi_ = 0; mi_ < 2; ++mi_) {
            int row = wr * 32 + mi_ * 16 + l15;
            a[mi_] = *(const s8b*)&tb[kt][row][lq * 8];
        }
#pragma unroll
        for (int ni = 0; ni < 4; ++ni) {
            int col = wc * 64 + ni * 16 + l15;
            b[ni] = ldg8(Wgb + (size_t)col * 128 + kt * 32 + lq * 8);
        }
#pragma unroll
        for (int mi_ = 0; mi_ < 2; ++mi_)
#pragma unroll
            for (int ni = 0; ni < 4; ++ni)
                acc[mi_][ni] = MFMA16(a[mi_], b[ni], acc[mi_][ni], 0, 0, 0);
    }
    float s[4] = {0.f, 0.f, 0.f, 0.f}, q[4] = {0.f, 0.f, 0.f, 0.f};
#pragma unroll
    for (int mi_ = 0; mi_ < 2; ++mi_)
#pragma unroll
        for (int ni = 0; ni < 4; ++ni) {
            int col = wc * 64 + ni * 16 + l15;
            float bi = bh2[col];
#pragma unroll
            for (int r = 0; r < 4; ++r) {
                int m = r0 + wr * 32 + mi_ * 16 + lq * 4 + r;
                float v = elu_f(acc[mi_][ni][r] + bi);
                if (m < NN) {
                    X[(size_t)m * HH + col] = v;
                    s[ni] += v; q[ni] += v * v;
                }
            }
        }
#pragma unroll
    for (int j = 0; j < 4; ++j) {
        s[j] += __shfl_xor(s[j], 16);
        s[j] += __shfl_xor(s[j], 32);
        q[j] += __shfl_xor(q[j], 16);
        q[j] += __shfl_xor(q[j], 32);
    }
    if (lane < 16) {
#pragma unroll
        for (int j = 0; j < 4; ++j) {
            int col = wc * 64 + j * 16 + l15;
            atomicAdd(&ssum[col], s[j]);
            atomicAdd(&ssq[col], q[j]);
        }
    }
}

// ---------------- node batchnorm apply (-> bf16 V or fp32 out) ----------------
__global__ void k_bnorm_nodes(const float* __restrict__ X, const float* __restrict__ ssum,
                              const float* __restrict__ ssq, const float* __restrict__ gam,
                              const float* __restrict__ bet, float* __restrict__ outf,
                              ushort* __restrict__ outb, int writeb) {
    int idx = blockIdx.x * blockDim.x + threadIdx.x;
    if (idx >= NN * HH) return;
    int c = idx & 127;
    float mu = ssum[c] * (1.f / NN);
    float var = ssq[c] * (1.f / NN) - mu * mu;
    float v = fmaf(gam[c] * (X[idx] - mu), rsqrtf(var + EPSBN), bet[c]);
    if (writeb) outb[idx] = rnb(v);
    else        outf[idx] = v;
}

// ---------------- edge stats over elu(mij) (last layer only) ----------------
__global__ __launch_bounds__(256)
void k_estats(const ushort* __restrict__ mijb, float* __restrict__ ssum, float* __restrict__ ssq) {
    const int t = threadIdx.x;
    const int col = t & 127;
    const int half = t >> 7;
    const int rbase = blockIdx.x * 250;
    float s = 0.f, q = 0.f;
    for (int r = rbase + half; r < rbase + 250; r += 2) {
        float x = elu_f(bf2f(mijb[(size_t)r * HH + col]));
        s += x; q += x * x;
    }
    atomicAdd(&ssum[col], s);
    atomicAdd(&ssq[col], q);
}

// ---------------- edge batchnorm apply -> output E ----------------
__global__ void k_bnorm_edges(const ushort* __restrict__ mijb, const float* __restrict__ ssum,
                              const float* __restrict__ ssq, const float* __restrict__ gam,
                              const float* __restrict__ bet, float* __restrict__ out) {
    size_t stride = (size_t)gridDim.x * blockDim.x;
    for (size_t idx = (size_t)blockIdx.x * blockDim.x + threadIdx.x; idx < (size_t)NE * HH; idx += stride) {
        int c = (int)(idx & 127);
        float x = elu_f(bf2f(mijb[idx]));
        float mu = ssum[c] * (1.f / NE);
        float var = ssq[c] * (1.f / NE) - mu * mu;
        out[idx] = fmaf(gam[c] * (x - mu), rsqrtf(var + EPSBN), bet[c]);
    }
}

extern "C" void kernel_launch(void* const* d_in, const int* in_sizes, int n_in,
                              void* d_out, int out_size, void* d_ws, size_t ws_size,
                              hipStream_t stream) {
    (void)in_sizes; (void)n_in; (void)out_size; (void)ws_size;
    const float* emb_nodes = (const float*)d_in[0];
    const float* emb_edges = (const float*)d_in[1];
    const int*   eidx      = (const int*)d_in[2];
    const float* pre_Wn = (const float*)d_in[3];
    const float* pre_bn = (const float*)d_in[4];
    const float* We1 = (const float*)d_in[7];
    const float* be1 = (const float*)d_in[8];
    const float* We2 = (const float*)d_in[9];
    const float* be2 = (const float*)d_in[10];
    const float* Wx1 = (const float*)d_in[11];
    const float* bx1 = (const float*)d_in[12];
    const float* Wx2 = (const float*)d_in[13];
    const float* bx2 = (const float*)d_in[14];
    const float* Wh1 = (const float*)d_in[15];
    const float* bh1 = (const float*)d_in[16];
    const float* Wh2 = (const float*)d_in[17];
    const float* bh2 = (const float*)d_in[18];
    const float* gam_n = (const float*)d_in[19];
    const float* bet_n = (const float*)d_in[20];
    const float* gam_e = (const float*)d_in[21];
    const float* bet_e = (const float*)d_in[22];

    const int* src = eidx;
    const int* dst = eidx + NE;

    // Workspace layout (float offsets); bf16 buffers counted as elems/2 floats.
    float* ws = (float*)d_ws;
    float*   coords = ws;                         // [0, 30000)
    ushort*  Vb     = (ushort*)(ws + 30000);      // [30000, 670000)
    ushort*  mib    = (ushort*)(ws + 670000);     // [670000, 1310000)
    float*   X      = ws + 1310000;               // [1310000, 2590000)
    float4*  cd4    = (float4*)(ws + 2590000);    // [2590000, 3230000)
    ushort*  mijb   = (ushort*)(ws + 3230000);    // [3230000, 13470000)
    float*   snN    = ws + 13470000;              // 128
    float*   sqN    = ws + 13470128;
    float*   snE    = ws + 13470256;
    float*   sqE    = ws + 13470384;
    ushort*  Wb     = (ushort*)(ws + 13470512);   // 344064 ush -> [13470512, 13642544)
    ushort*  Wx2b   = (ushort*)(ws + 13642544);   // 6144 ush -> [13642544, 13645616)
    int*     I0     = (int*)(ws + 13645616);
    int*     deg    = I0;
    int*     offs   = I0 + 10000;
    int*     cur    = I0 + 20001;
    int*     eid    = I0 + 30001;

    float* outV = (float*)d_out;
    float* outE = (float*)d_out + (size_t)NN * HH;

    k_copy<<<(30000 + 255) / 256, 256, 0, stream>>>(emb_nodes, coords, 30000);
    k_vinit<<<(NN * HH + 255) / 256, 256, 0, stream>>>(emb_nodes, pre_Wn, pre_bn, Vb);
    k_wprep<<<1344, 256, 0, stream>>>(We1, We2, Wx1, Wh1, Wh2, Wb);
    k_wx2prep<<<24, 256, 0, stream>>>(Wx2, Wx2b);

    k_zero_int<<<(NN + 255) / 256, 256, 0, stream>>>(deg, NN);
    k_hist<<<(NE + 255) / 256, 256, 0, stream>>>(dst, deg);
    k_scan<<<1, 256, 0, stream>>>(deg, offs, cur);
    k_fill<<<(NE + 255) / 256, 256, 0, stream>>>(dst, cur, eid);

    for (int l = 0; l < 3; ++l) {
        const float* We1l = We1 + (size_t)l * 259 * 128;
        const float* be1l = be1 + l * 128;
        const float* be2l = be2 + l * 128;
        const float* bx1l = bx1 + l * 128;
        const float* bx2l = bx2 + l * 3;
        const float* bh1l = bh1 + l * 128;
        const float* bh2l = bh2 + l * 128;
        const size_t L = (size_t)l * 114688;
        const ushort* W1b = Wb + L;              // We1t [128][256]
        const ushort* W2b = Wb + L + 32768;      // We2t [128][128]
        const ushort* Wxb = Wb + L + 49152;      // Wx1t [128][128]
        const ushort* Whb = Wb + L + 65536;      // Wh1t [128][256]
        const ushort* Wgb = Wb + L + 98304;      // Wh2t [128][128]
        const ushort* Wx2bl = Wx2b + (size_t)l * 2048;

        k_zero<<<2, 256, 0, stream>>>(snN, 512);
        k_efused<<<NE / 128, 512, 0, stream>>>(Vb, src, dst, coords, emb_edges,
                                               W1b, We1l, be1l, W2b, be2l,
                                               Wxb, bx1l, Wx2bl, bx2l, mijb, cd4);
        k_mi<<<NN, 128, 0, stream>>>(mijb, offs, eid, mib);
        k_coordupd<<<(NN * 3 + 255) / 256, 256, 0, stream>>>(coords, cd4, offs, eid);
        k_nfused<<<(NN + 63) / 64, 256, 0, stream>>>(Vb, mib, Whb, bh1l, Wgb, bh2l, X, snN, sqN);
        k_bnorm_nodes<<<(NN * HH + 255) / 256, 256, 0, stream>>>(X, snN, sqN, gam_n + l * 128,
                                                                 bet_n + l * 128,
                                                                 outV, Vb, (l < 2) ? 1 : 0);
        if (l == 2) {
            k_estats<<<640, 256, 0, stream>>>(mijb, snE, sqE);
            k_bnorm_edges<<<4096, 256, 0, stream>>>(mijb, snE, sqE, gam_e + l * 128, bet_e + l * 128, outE);
        }
    }
}

// Round 8
// 843.627 us; speedup vs baseline: 2.7151x; 1.0101x over previous
//
#include <hip/hip_runtime.h>
#include <hip/hip_bf16.h>
#include <math.h>

#define NN 10000
#define NE 160000
#define HH 128
#define EPSBN 1e-5f

typedef __attribute__((ext_vector_type(8))) short s8b;   // 8 bf16 (as shorts)
typedef __attribute__((ext_vector_type(4))) float f32x4;

#define MFMA16 __builtin_amdgcn_mfma_f32_16x16x32_bf16

__device__ __forceinline__ float silu_f(float x) { return x / (1.f + __expf(-x)); }
__device__ __forceinline__ float elu_f(float x)  { return x > 0.f ? x : expm1f(x); }

// fp32 -> bf16 round-to-nearest-even
__device__ __forceinline__ ushort rnb(float x) {
    unsigned u = __float_as_uint(x);
    unsigned r = (u + 0x7fffu + ((u >> 16) & 1u)) >> 16;
    return (ushort)r;
}
__device__ __forceinline__ float bf2f(ushort u) {
    return __uint_as_float(((unsigned)u) << 16);
}
__device__ __forceinline__ s8b ldg8(const ushort* p) { return *(const s8b*)p; }

// ---------------- utility ----------------
__global__ void k_zero(float* __restrict__ p, int n) {
    int i = blockIdx.x * blockDim.x + threadIdx.x;
    if (i < n) p[i] = 0.f;
}
__global__ void k_zero_int(int* __restrict__ p, int n) {
    int i = blockIdx.x * blockDim.x + threadIdx.x;
    if (i < n) p[i] = 0;
}
__global__ void k_copy(const float* __restrict__ a, float* __restrict__ b, int n) {
    int i = blockIdx.x * blockDim.x + threadIdx.x;
    if (i < n) b[i] = a[i];
}

// V = emb_nodes @ pre_Wn + pre_bn -> bf16
__global__ void k_vinit(const float* __restrict__ en, const float* __restrict__ Wn,
                        const float* __restrict__ bn, ushort* __restrict__ Vb) {
    int idx = blockIdx.x * blockDim.x + threadIdx.x;
    if (idx >= NN * HH) return;
    int i = idx >> 7, j = idx & 127;
    float v = fmaf(en[i * 3 + 0], Wn[j], bn[j]);
    v = fmaf(en[i * 3 + 1], Wn[HH + j], v);
    v = fmaf(en[i * 3 + 2], Wn[2 * HH + j], v);
    Vb[idx] = rnb(v);
}

// ---------------- weight transpose -> bf16, dest [n][K] ----------------
// per layer (shorts): We1t @0 (K=256), We2t @32768 (K=128), Wx1t @49152 (K=128),
//                     Wh1t @65536 (K=256), Wh2t @98304 (K=128). layer stride 114688.
__global__ void k_wprep(const float* __restrict__ We1, const float* __restrict__ We2,
                        const float* __restrict__ Wx1, const float* __restrict__ Wh1,
                        const float* __restrict__ Wh2, ushort* __restrict__ Wb) {
    int idx = blockIdx.x * 256 + threadIdx.x;
    if (idx >= 344064) return;
    int layer = idx / 114688;
    int r = idx - layer * 114688;
    const float* src; int K; int roff;
    if (r < 32768)      { src = We1 + (size_t)layer * 33152; K = 256; roff = r; }
    else if (r < 49152) { src = We2 + (size_t)layer * 16384; K = 128; roff = r - 32768; }
    else if (r < 65536) { src = Wx1 + (size_t)layer * 16384; K = 128; roff = r - 49152; }
    else if (r < 98304) { src = Wh1 + (size_t)layer * 32768; K = 256; roff = r - 65536; }
    else                { src = Wh2 + (size_t)layer * 16384; K = 128; roff = r - 98304; }
    int n = roff / K, k = roff - n * K;
    Wb[idx] = rnb(src[k * 128 + n]);
}

// Wx2t: [layer][16][128] bf16, rows >=3 zero-padded
__global__ void k_wx2prep(const float* __restrict__ Wx2, ushort* __restrict__ Wx2b) {
    int idx = blockIdx.x * 256 + threadIdx.x;
    if (idx >= 3 * 16 * 128) return;
    int layer = idx / 2048;
    int r = idx - layer * 2048;
    int n = r >> 7, k = r & 127;
    Wx2b[idx] = (n < 3) ? rnb(Wx2[layer * 384 + k * 3 + n]) : (ushort)0;
}

// ---------------- CSR build ----------------
__global__ void k_hist(const int* __restrict__ dst, int* __restrict__ deg) {
    int e = blockIdx.x * blockDim.x + threadIdx.x;
    if (e < NE) atomicAdd(&deg[dst[e]], 1);
}
__global__ __launch_bounds__(256)
void k_scan(const int* __restrict__ deg, int* __restrict__ offs, int* __restrict__ cur) {
    __shared__ int part[256];
    const int t = threadIdx.x;
    const int s0 = t * 40, s1 = min(s0 + 40, NN);
    int s = 0;
    for (int i = s0; i < s1; ++i) s += deg[i];
    part[t] = s;
    __syncthreads();
    if (t == 0) {
        int r = 0;
        for (int i = 0; i < 256; ++i) { int v = part[i]; part[i] = r; r += v; }
    }
    __syncthreads();
    int r = part[t];
    for (int i = s0; i < s1; ++i) { offs[i] = r; cur[i] = r; r += deg[i]; }
    if (t == 255) offs[NN] = r;
}
__global__ void k_fill(const int* __restrict__ dst, int* __restrict__ cur, int* __restrict__ eid) {
    int e = blockIdx.x * blockDim.x + threadIdx.x;
    if (e < NE) {
        int p = atomicAdd(&cur[dst[e]], 1);
        eid[p] = e;
    }
}

// ================= mega edge kernel =================
// per block: 128 edges, 512 thr (8 waves: 4 row-groups x 2 col-halves)
// phase A: h @ We1 (K=256 gather) ; B: @We2 -> mij ; C: mij @ Wx1 -> t2 ; D: t2 @ Wx2 -> px -> cd4
// NOTE: launch_bounds min-blocks=2 (NOT 4): min=4 capped VGPR at 64 (measured VGPR_Count=60),
// which serialized every load->MFMA chain (MfmaUtil 6.6%, all pipes idle). LDS (45KB) limits
// to 3 blocks/CU regardless, so min=2 costs nothing and un-starves the register allocator.
__global__ __launch_bounds__(512, 2)
void k_efused(const ushort* __restrict__ Vb,
              const int* __restrict__ src, const int* __restrict__ dst,
              const float* __restrict__ coords, const float* __restrict__ ee,
              const ushort* __restrict__ W1b,   // We1t [128][256]
              const float* __restrict__ We1f, const float* __restrict__ be1,
              const ushort* __restrict__ W2b,   // We2t [128][128]
              const float* __restrict__ be2,
              const ushort* __restrict__ Wxb,   // Wx1t [128][128]
              const float* __restrict__ bx1,
              const ushort* __restrict__ Wx2b,  // Wx2t [16][128]
              const float* __restrict__ bx2,
              ushort* __restrict__ mijb, float4* __restrict__ cd4) {
    __shared__ ushort t1b[4][128][40];
    __shared__ int sid[128], did[128];
    __shared__ float dd[128], eAa[128], eBb[128];
    __shared__ float d3[3][128];
    const int t = threadIdx.x;
    const int lane = t & 63;
    const int w = t >> 6;            // 0..7
    const int wr = w >> 1, wc = w & 1;
    const int e0 = blockIdx.x * 128;
    if (t < 128) {
        int e = e0 + t;
        int s = src[e], d = dst[e];
        sid[t] = s; did[t] = d;
        float dx = coords[d * 3 + 0] - coords[s * 3 + 0];
        float dy = coords[d * 3 + 1] - coords[s * 3 + 1];
        float dz = coords[d * 3 + 2] - coords[s * 3 + 2];
        dd[t] = sqrtf(dx * dx + dy * dy + dz * dz);
        d3[0][t] = dx; d3[1][t] = dy; d3[2][t] = dz;
        eAa[t] = ee[2 * e]; eBb[t] = ee[2 * e + 1];
    }
    __syncthreads();
    const int l15 = lane & 15, lq = lane >> 4;
    f32x4 acc[2][4];
#pragma unroll
    for (int i = 0; i < 2; ++i)
#pragma unroll
        for (int j = 0; j < 4; ++j) acc[i][j] = (f32x4){0.f, 0.f, 0.f, 0.f};

    // ---- phase A: K=256 over [V[src] | V[dst]] ----
#pragma unroll
    for (int half = 0; half < 2; ++half) {
        const int* ids = half ? did : sid;
#pragma unroll
        for (int kt = 0; kt < 4; ++kt) {
            const int wk = half * 128 + kt * 32;
            s8b a[2], b[4];
#pragma unroll
            for (int mi = 0; mi < 2; ++mi) {
                int row = ids[wr * 32 + mi * 16 + l15];
                a[mi] = ldg8(Vb + (size_t)row * HH + kt * 32 + lq * 8);
            }
#pragma unroll
            for (int ni = 0; ni < 4; ++ni) {
                int col = wc * 64 + ni * 16 + l15;
                b[ni] = ldg8(W1b + (size_t)col * 256 + wk + lq * 8);
            }
#pragma unroll
            for (int mi = 0; mi < 2; ++mi)
#pragma unroll
                for (int ni = 0; ni < 4; ++ni)
                    acc[mi][ni] = MFMA16(a[mi], b[ni], acc[mi][ni], 0, 0, 0);
        }
    }
    // ---- epilogue A: rank-1 fixups + bias + silu -> t1 (bf16 LDS) ----
#pragma unroll
    for (int mi = 0; mi < 2; ++mi)
#pragma unroll
        for (int ni = 0; ni < 4; ++ni) {
            int col = wc * 64 + ni * 16 + l15;
            float w256 = We1f[256 * HH + col];
            float w257 = We1f[257 * HH + col];
            float w258 = We1f[258 * HH + col];
            float bi = be1[col];
            int kt = col >> 5, c = col & 31;
#pragma unroll
            for (int r = 0; r < 4; ++r) {
                int m = wr * 32 + mi * 16 + lq * 4 + r;
                float v = acc[mi][ni][r] + bi;
                v = fmaf(dd[m], w256, v);
                v = fmaf(eAa[m], w257, v);
                v = fmaf(eBb[m], w258, v);
                t1b[kt][m][c] = rnb(silu_f(v));
                acc[mi][ni][r] = 0.f;
            }
        }
    __syncthreads();
    // ---- phase B: mij = silu(t1 @ We2 + be2) ----
#pragma unroll
    for (int kt = 0; kt < 4; ++kt) {
        s8b a[2], b[4];
#pragma unroll
        for (int mi = 0; mi < 2; ++mi) {
            int row = wr * 32 + mi * 16 + l15;
            a[mi] = *(const s8b*)&t1b[kt][row][lq * 8];
        }
#pragma unroll
        for (int ni = 0; ni < 4; ++ni) {
            int col = wc * 64 + ni * 16 + l15;
            b[ni] = ldg8(W2b + (size_t)col * 128 + kt * 32 + lq * 8);
        }
#pragma unroll
        for (int mi = 0; mi < 2; ++mi)
#pragma unroll
            for (int ni = 0; ni < 4; ++ni)
                acc[mi][ni] = MFMA16(a[mi], b[ni], acc[mi][ni], 0, 0, 0);
    }
    __syncthreads();   // all t1 reads done before overwrite
    // ---- epilogue B: mij -> global + LDS ----
#pragma unroll
    for (int mi = 0; mi < 2; ++mi)
#pragma unroll
        for (int ni = 0; ni < 4; ++ni) {
            int col = wc * 64 + ni * 16 + l15;
            float bi = be2[col];
            int kt = col >> 5, c = col & 31;
#pragma unroll
            for (int r = 0; r < 4; ++r) {
                int m = wr * 32 + mi * 16 + lq * 4 + r;
                ushort mv = rnb(silu_f(acc[mi][ni][r] + bi));
                mijb[(size_t)(e0 + m) * HH + col] = mv;
                t1b[kt][m][c] = mv;
                acc[mi][ni][r] = 0.f;
            }
        }
    __syncthreads();
    // ---- phase C: t2 = silu(mij @ Wx1 + bx1) ----
#pragma unroll
    for (int kt = 0; kt < 4; ++kt) {
        s8b a[2], b[4];
#pragma unroll
        for (int mi = 0; mi < 2; ++mi) {
            int row = wr * 32 + mi * 16 + l15;
            a[mi] = *(const s8b*)&t1b[kt][row][lq * 8];
        }
#pragma unroll
        for (int ni = 0; ni < 4; ++ni) {
            int col = wc * 64 + ni * 16 + l15;
            b[ni] = ldg8(Wxb + (size_t)col * 128 + kt * 32 + lq * 8);
        }
#pragma unroll
        for (int mi = 0; mi < 2; ++mi)
#pragma unroll
            for (int ni = 0; ni < 4; ++ni)
                acc[mi][ni] = MFMA16(a[mi], b[ni], acc[mi][ni], 0, 0, 0);
    }
    __syncthreads();   // mij reads done
    // ---- epilogue C: t2 -> LDS ----
#pragma unroll
    for (int mi = 0; mi < 2; ++mi)
#pragma unroll
        for (int ni = 0; ni < 4; ++ni) {
            int col = wc * 64 + ni * 16 + l15;
            float bi = bx1[col];
            int kt = col >> 5, c = col & 31;
#pragma unroll
            for (int r = 0; r < 4; ++r) {
                int m = wr * 32 + mi * 16 + lq * 4 + r;
                t1b[kt][m][c] = rnb(silu_f(acc[mi][ni][r] + bi));
            }
        }
    __syncthreads();
    // ---- phase D: px = t2 @ Wx2 + bx2 ; cd4 = diff * px ----
    // each wave owns 16 rows: w*16..w*16+15
    f32x4 accd = (f32x4){0.f, 0.f, 0.f, 0.f};
#pragma unroll
    for (int kt = 0; kt < 4; ++kt) {
        s8b a = *(const s8b*)&t1b[kt][w * 16 + l15][lq * 8];
        s8b b = ldg8(Wx2b + (size_t)l15 * 128 + kt * 32 + lq * 8);
        accd = MFMA16(a, b, accd, 0, 0, 0);
    }
    if (l15 < 3) {
        float bi = bx2[l15];
#pragma unroll
        for (int r = 0; r < 4; ++r) {
            int row = w * 16 + lq * 4 + r;
            float px = accd[r] + bi;
            ((float*)&cd4[e0 + row])[l15] = d3[l15][row] * px;
        }
    }
}

// ---------------- mi = segment_sum(mij, dst) via CSR gather (bf16 in/out, fp32 accum) ----------------
__global__ __launch_bounds__(128)
void k_mi(const ushort* __restrict__ mijb, const int* __restrict__ offs,
          const int* __restrict__ eid, ushort* __restrict__ mib) {
    const int n = blockIdx.x;
    const int t = threadIdx.x;
    const int b = offs[n], e = offs[n + 1];
    float s = 0.f;
    for (int j = b; j < e; ++j)
        s += bf2f(mijb[(size_t)eid[j] * HH + t]);
    mib[(size_t)n * HH + t] = rnb(s);
}

// ---------------- coords += CSR-gather(cd4)/(N-1) ----------------
__global__ void k_coordupd(float* __restrict__ coords, const float4* __restrict__ cd4,
                           const int* __restrict__ offs, const int* __restrict__ eid) {
    int idx = blockIdx.x * blockDim.x + threadIdx.x;
    if (idx >= NN * 3) return;
    int n = idx / 3, c = idx - 3 * n;
    int b = offs[n], e = offs[n + 1];
    float s = 0.f;
    for (int j = b; j < e; ++j)
        s += ((const float*)&cd4[eid[j]])[c];
    coords[idx] += s * (1.f / (NN - 1));
}

// ================= fused node kernel: X = elu(silu([V,mi]@Wh1+bh1)@Wh2+bh2) + stats =================
// 64 rows/block, 256 thr (4 waves, 2x2). min-blocks=4 -> VGPR cap 128 (was 5 -> cap ~102).
__global__ __launch_bounds__(256, 4)
void k_nfused(const ushort* __restrict__ Vb, const ushort* __restrict__ mib,
              const ushort* __restrict__ Whb,   // Wh1t [128][256]
              const float* __restrict__ bh1,
              const ushort* __restrict__ Wgb,   // Wh2t [128][128]
              const float* __restrict__ bh2,
              float* __restrict__ X,
              float* __restrict__ ssum, float* __restrict__ ssq) {
    __shared__ ushort tb[4][64][40];
    const int t = threadIdx.x;
    const int lane = t & 63;
    const int w = t >> 6;
    const int wr = w >> 1, wc = w & 1;
    const int r0 = blockIdx.x * 64;
    const int l15 = lane & 15, lq = lane >> 4;
    f32x4 acc[2][4];
#pragma unroll
    for (int i = 0; i < 2; ++i)
#pragma unroll
        for (int j = 0; j < 4; ++j) acc[i][j] = (f32x4){0.f, 0.f, 0.f, 0.f};

    // phase A: K=256 over [V | mi]
#pragma unroll
    for (int kk = 0; kk < 8; ++kk) {
        const ushort* Ap = (kk < 4) ? Vb : mib;
        const int k0 = (kk & 3) * 32;
        s8b a[2], b[4];
#pragma unroll
        for (int mi_ = 0; mi_ < 2; ++mi_) {
            int row = r0 + wr * 32 + mi_ * 16 + l15;
            if (row >= NN) row = NN - 1;
            a[mi_] = ldg8(Ap + (size_t)row * HH + k0 + lq * 8);
        }
#pragma unroll
        for (int ni = 0; ni < 4; ++ni) {
            int col = wc * 64 + ni * 16 + l15;
            b[ni] = ldg8(Whb + (size_t)col * 256 + kk * 32 + lq * 8);
        }
#pragma unroll
        for (int mi_ = 0; mi_ < 2; ++mi_)
#pragma unroll
            for (int ni = 0; ni < 4; ++ni)
                acc[mi_][ni] = MFMA16(a[mi_], b[ni], acc[mi_][ni], 0, 0, 0);
    }
    // epilogue A: u = silu -> LDS
#pragma unroll
    for (int mi_ = 0; mi_ < 2; ++mi_)
#pragma unroll
        for (int ni = 0; ni < 4; ++ni) {
            int col = wc * 64 + ni * 16 + l15;
            float bi = bh1[col];
            int kt = col >> 5, c = col & 31;
#pragma unroll
            for (int r = 0; r < 4; ++r) {
                int m = wr * 32 + mi_ * 16 + lq * 4 + r;
                tb[kt][m][c] = rnb(silu_f(acc[mi_][ni][r] + bi));
                acc[mi_][ni][r] = 0.f;
            }
        }
    __syncthreads();
    // phase B: X = elu(u @ Wh2 + bh2)
#pragma unroll
    for (int kt = 0; kt < 4; ++kt) {
        s8b a[2], b[4];
#pragma unroll
        for (int mi_ = 0; mi_ < 2; ++mi_) {
            int row = wr * 32 + mi_ * 16 + l15;
            a[mi_] = *(const s8b*)&tb[kt][row][lq * 8];
        }
#pragma unroll
        for (int ni = 0; ni < 4; ++ni) {
            int col = wc * 64 + ni * 16 + l15;
            b[ni] = ldg8(Wgb + (size_t)col * 128 + kt * 32 + lq * 8);
        }
#pragma unroll
        for (int mi_ = 0; mi_ < 2; ++mi_)
#pragma unroll
            for (int ni = 0; ni < 4; ++ni)
                acc[mi_][ni] = MFMA16(a[mi_], b[ni], acc[mi_][ni], 0, 0, 0);
    }
    float s[4] = {0.f, 0.f, 0.f, 0.f}, q[4] = {0.f, 0.f, 0.f, 0.f};
#pragma unroll
    for (int mi_ = 0; mi_ < 2; ++mi_)
#pragma unroll
        for (int ni = 0; ni < 4; ++ni) {
            int col = wc * 64 + ni * 16 + l15;
            float bi = bh2[col];
#pragma unroll
            for (int r = 0; r < 4; ++r) {
                int m = r0 + wr * 32 + mi_ * 16 + lq * 4 + r;
                float v = elu_f(acc[mi_][ni][r] + bi);
                if (m < NN) {
                    X[(size_t)m * HH + col] = v;
                    s[ni] += v; q[ni] += v * v;
                }
            }
        }
#pragma unroll
    for (int j = 0; j < 4; ++j) {
        s[j] += __shfl_xor(s[j], 16);
        s[j] += __shfl_xor(s[j], 32);
        q[j] += __shfl_xor(q[j], 16);
        q[j] += __shfl_xor(q[j], 32);
    }
    if (lane < 16) {
#pragma unroll
        for (int j = 0; j < 4; ++j) {
            int col = wc * 64 + j * 16 + l15;
            atomicAdd(&ssum[col], s[j]);
            atomicAdd(&ssq[col], q[j]);
        }
    }
}

// ---------------- node batchnorm apply (-> bf16 V or fp32 out) ----------------
__global__ void k_bnorm_nodes(const float* __restrict__ X, const float* __restrict__ ssum,
                              const float* __restrict__ ssq, const float* __restrict__ gam,
                              const float* __restrict__ bet, float* __restrict__ outf,
                              ushort* __restrict__ outb, int writeb) {
    int idx = blockIdx.x * blockDim.x + threadIdx.x;
    if (idx >= NN * HH) return;
    int c = idx & 127;
    float mu = ssum[c] * (1.f / NN);
    float var = ssq[c] * (1.f / NN) - mu * mu;
    float v = fmaf(gam[c] * (X[idx] - mu), rsqrtf(var + EPSBN), bet[c]);
    if (writeb) outb[idx] = rnb(v);
    else        outf[idx] = v;
}

// ---------------- edge stats over elu(mij) (last layer only) ----------------
__global__ __launch_bounds__(256)
void k_estats(const ushort* __restrict__ mijb, float* __restrict__ ssum, float* __restrict__ ssq) {
    const int t = threadIdx.x;
    const int col = t & 127;
    const int half = t >> 7;
    const int rbase = blockIdx.x * 250;
    float s = 0.f, q = 0.f;
    for (int r = rbase + half; r < rbase + 250; r += 2) {
        float x = elu_f(bf2f(mijb[(size_t)r * HH + col]));
        s += x; q += x * x;
    }
    atomicAdd(&ssum[col], s);
    atomicAdd(&ssq[col], q);
}

// ---------------- edge batchnorm apply -> output E ----------------
__global__ void k_bnorm_edges(const ushort* __restrict__ mijb, const float* __restrict__ ssum,
                              const float* __restrict__ ssq, const float* __restrict__ gam,
                              const float* __restrict__ bet, float* __restrict__ out) {
    size_t stride = (size_t)gridDim.x * blockDim.x;
    for (size_t idx = (size_t)blockIdx.x * blockDim.x + threadIdx.x; idx < (size_t)NE * HH; idx += stride) {
        int c = (int)(idx & 127);
        float x = elu_f(bf2f(mijb[idx]));
        float mu = ssum[c] * (1.f / NE);
        float var = ssq[c] * (1.f / NE) - mu * mu;
        out[idx] = fmaf(gam[c] * (x - mu), rsqrtf(var + EPSBN), bet[c]);
    }
}

extern "C" void kernel_launch(void* const* d_in, const int* in_sizes, int n_in,
                              void* d_out, int out_size, void* d_ws, size_t ws_size,
                              hipStream_t stream) {
    (void)in_sizes; (void)n_in; (void)out_size; (void)ws_size;
    const float* emb_nodes = (const float*)d_in[0];
    const float* emb_edges = (const float*)d_in[1];
    const int*   eidx      = (const int*)d_in[2];
    const float* pre_Wn = (const float*)d_in[3];
    const float* pre_bn = (const float*)d_in[4];
    const float* We1 = (const float*)d_in[7];
    const float* be1 = (const float*)d_in[8];
    const float* We2 = (const float*)d_in[9];
    const float* be2 = (const float*)d_in[10];
    const float* Wx1 = (const float*)d_in[11];
    const float* bx1 = (const float*)d_in[12];
    const float* Wx2 = (const float*)d_in[13];
    const float* bx2 = (const float*)d_in[14];
    const float* Wh1 = (const float*)d_in[15];
    const float* bh1 = (const float*)d_in[16];
    const float* Wh2 = (const float*)d_in[17];
    const float* bh2 = (const float*)d_in[18];
    const float* gam_n = (const float*)d_in[19];
    const float* bet_n = (const float*)d_in[20];
    const float* gam_e = (const float*)d_in[21];
    const float* bet_e = (const float*)d_in[22];

    const int* src = eidx;
    const int* dst = eidx + NE;

    // Workspace layout (float offsets); bf16 buffers counted as elems/2 floats.
    float* ws = (float*)d_ws;
    float*   coords = ws;                         // [0, 30000)
    ushort*  Vb     = (ushort*)(ws + 30000);      // [30000, 670000)
    ushort*  mib    = (ushort*)(ws + 670000);     // [670000, 1310000)
    float*   X      = ws + 1310000;               // [1310000, 2590000)
    float4*  cd4    = (float4*)(ws + 2590000);    // [2590000, 3230000)
    ushort*  mijb   = (ushort*)(ws + 3230000);    // [3230000, 13470000)
    float*   snN    = ws + 13470000;              // 128
    float*   sqN    = ws + 13470128;
    float*   snE    = ws + 13470256;
    float*   sqE    = ws + 13470384;
    ushort*  Wb     = (ushort*)(ws + 13470512);   // 344064 ush -> [13470512, 13642544)
    ushort*  Wx2b   = (ushort*)(ws + 13642544);   // 6144 ush -> [13642544, 13645616)
    int*     I0     = (int*)(ws + 13645616);
    int*     deg    = I0;
    int*     offs   = I0 + 10000;
    int*     cur    = I0 + 20001;
    int*     eid    = I0 + 30001;

    float* outV = (float*)d_out;
    float* outE = (float*)d_out + (size_t)NN * HH;

    k_copy<<<(30000 + 255) / 256, 256, 0, stream>>>(emb_nodes, coords, 30000);
    k_vinit<<<(NN * HH + 255) / 256, 256, 0, stream>>>(emb_nodes, pre_Wn, pre_bn, Vb);
    k_wprep<<<1344, 256, 0, stream>>>(We1, We2, Wx1, Wh1, Wh2, Wb);
    k_wx2prep<<<24, 256, 0, stream>>>(Wx2, Wx2b);

    k_zero_int<<<(NN + 255) / 256, 256, 0, stream>>>(deg, NN);
    k_hist<<<(NE + 255) / 256, 256, 0, stream>>>(dst, deg);
    k_scan<<<1, 256, 0, stream>>>(deg, offs, cur);
    k_fill<<<(NE + 255) / 256, 256, 0, stream>>>(dst, cur, eid);

    for (int l = 0; l < 3; ++l) {
        const float* We1l = We1 + (size_t)l * 259 * 128;
        const float* be1l = be1 + l * 128;
        const float* be2l = be2 + l * 128;
        const float* bx1l = bx1 + l * 128;
        const float* bx2l = bx2 + l * 3;
        const float* bh1l = bh1 + l * 128;
        const float* bh2l = bh2 + l * 128;
        const size_t L = (size_t)l * 114688;
        const ushort* W1b = Wb + L;              // We1t [128][256]
        const ushort* W2b = Wb + L + 32768;      // We2t [128][128]
        const ushort* Wxb = Wb + L + 49152;      // Wx1t [128][128]
        const ushort* Whb = Wb + L + 65536;      // Wh1t [128][256]
        const ushort* Wgb = Wb + L + 98304;      // Wh2t [128][128]
        const ushort* Wx2bl = Wx2b + (size_t)l * 2048;

        k_zero<<<2, 256, 0, stream>>>(snN, 512);
        k_efused<<<NE / 128, 512, 0, stream>>>(Vb, src, dst, coords, emb_edges,
                                               W1b, We1l, be1l, W2b, be2l,
                                               Wxb, bx1l, Wx2bl, bx2l, mijb, cd4);
        k_mi<<<NN, 128, 0, stream>>>(mijb, offs, eid, mib);
        k_coordupd<<<(NN * 3 + 255) / 256, 256, 0, stream>>>(coords, cd4, offs, eid);
        k_nfused<<<(NN + 63) / 64, 256, 0, stream>>>(Vb, mib, Whb, bh1l, Wgb, bh2l, X, snN, sqN);
        k_bnorm_nodes<<<(NN * HH + 255) / 256, 256, 0, stream>>>(X, snN, sqN, gam_n + l * 128,
                                                                 bet_n + l * 128,
                                                                 outV, Vb, (l < 2) ? 1 : 0);
        if (l == 2) {
            k_estats<<<640, 256, 0, stream>>>(mijb, snE, sqE);
            k_bnorm_edges<<<4096, 256, 0, stream>>>(mijb, snE, sqE, gam_e + l * 128, bet_e + l * 128, outE);
        }
    }
}

// Round 9
// 837.088 us; speedup vs baseline: 2.7364x; 1.0078x over previous
//
#include <hip/hip_runtime.h>
#include <hip/hip_bf16.h>
#include <math.h>

#define NN 10000
#define NE 160000
#define HH 128
#define EPSBN 1e-5f

typedef __attribute__((ext_vector_type(8))) short s8b;   // 8 bf16 (as shorts)
typedef __attribute__((ext_vector_type(4))) float f32x4;

#define MFMA16 __builtin_amdgcn_mfma_f32_16x16x32_bf16

__device__ __forceinline__ float silu_f(float x) { return x / (1.f + __expf(-x)); }
__device__ __forceinline__ float elu_f(float x)  { return x > 0.f ? x : expm1f(x); }

// fp32 -> bf16 RNE via HIP intrinsic (compiler emits v_cvt; cheaper than bit-twiddle)
__device__ __forceinline__ ushort f2b(float x) {
    __hip_bfloat16 h = __float2bfloat16(x);
    return *reinterpret_cast<ushort*>(&h);
}
__device__ __forceinline__ float bf2f(ushort u) {
    return __uint_as_float(((unsigned)u) << 16);
}
__device__ __forceinline__ s8b ldg8(const ushort* p) { return *(const s8b*)(p); }

// ---------------- utility ----------------
__global__ void k_zero(float* __restrict__ p, int n) {
    int i = blockIdx.x * blockDim.x + threadIdx.x;
    if (i < n) p[i] = 0.f;
}
__global__ void k_zero_int(int* __restrict__ p, int n) {
    int i = blockIdx.x * blockDim.x + threadIdx.x;
    if (i < n) p[i] = 0;
}
__global__ void k_copy(const float* __restrict__ a, float* __restrict__ b, int n) {
    int i = blockIdx.x * blockDim.x + threadIdx.x;
    if (i < n) b[i] = a[i];
}

// V = emb_nodes @ pre_Wn + pre_bn -> bf16
__global__ void k_vinit(const float* __restrict__ en, const float* __restrict__ Wn,
                        const float* __restrict__ bn, ushort* __restrict__ Vb) {
    int idx = blockIdx.x * blockDim.x + threadIdx.x;
    if (idx >= NN * HH) return;
    int i = idx >> 7, j = idx & 127;
    float v = fmaf(en[i * 3 + 0], Wn[j], bn[j]);
    v = fmaf(en[i * 3 + 1], Wn[HH + j], v);
    v = fmaf(en[i * 3 + 2], Wn[2 * HH + j], v);
    Vb[idx] = f2b(v);
}

// ---------------- weight transpose -> bf16, dest [n][K] ----------------
__global__ void k_wprep(const float* __restrict__ We1, const float* __restrict__ We2,
                        const float* __restrict__ Wx1, const float* __restrict__ Wh1,
                        const float* __restrict__ Wh2, ushort* __restrict__ Wb) {
    int idx = blockIdx.x * 256 + threadIdx.x;
    if (idx >= 344064) return;
    int layer = idx / 114688;
    int r = idx - layer * 114688;
    const float* src; int K; int roff;
    if (r < 32768)      { src = We1 + (size_t)layer * 33152; K = 256; roff = r; }
    else if (r < 49152) { src = We2 + (size_t)layer * 16384; K = 128; roff = r - 32768; }
    else if (r < 65536) { src = Wx1 + (size_t)layer * 16384; K = 128; roff = r - 49152; }
    else if (r < 98304) { src = Wh1 + (size_t)layer * 32768; K = 256; roff = r - 65536; }
    else                { src = Wh2 + (size_t)layer * 16384; K = 128; roff = r - 98304; }
    int n = roff / K, k = roff - n * K;
    Wb[idx] = f2b(src[k * 128 + n]);
}

// Wx2t: [layer][16][128] bf16, rows >=3 zero-padded
__global__ void k_wx2prep(const float* __restrict__ Wx2, ushort* __restrict__ Wx2b) {
    int idx = blockIdx.x * 256 + threadIdx.x;
    if (idx >= 3 * 16 * 128) return;
    int layer = idx / 2048;
    int r = idx - layer * 2048;
    int n = r >> 7, k = r & 127;
    Wx2b[idx] = (n < 3) ? f2b(Wx2[layer * 384 + k * 3 + n]) : (ushort)0;
}

// ---------------- CSR build ----------------
__global__ void k_hist(const int* __restrict__ dst, int* __restrict__ deg) {
    int e = blockIdx.x * blockDim.x + threadIdx.x;
    if (e < NE) atomicAdd(&deg[dst[e]], 1);
}
__global__ __launch_bounds__(256)
void k_scan(const int* __restrict__ deg, int* __restrict__ offs, int* __restrict__ cur) {
    __shared__ int part[256];
    const int t = threadIdx.x;
    const int s0 = t * 40, s1 = min(s0 + 40, NN);
    int s = 0;
    for (int i = s0; i < s1; ++i) s += deg[i];
    part[t] = s;
    __syncthreads();
    if (t == 0) {
        int r = 0;
        for (int i = 0; i < 256; ++i) { int v = part[i]; part[i] = r; r += v; }
    }
    __syncthreads();
    int r = part[t];
    for (int i = s0; i < s1; ++i) { offs[i] = r; cur[i] = r; r += deg[i]; }
    if (t == 255) offs[NN] = r;
}
__global__ void k_fill(const int* __restrict__ dst, int* __restrict__ cur, int* __restrict__ eid) {
    int e = blockIdx.x * blockDim.x + threadIdx.x;
    if (e < NE) {
        int p = atomicAdd(&cur[dst[e]], 1);
        eid[p] = e;
    }
}

// ================= mega edge kernel =================
// 128 edges/block, 512 thr (8 waves: 4 row-groups x 2 col-halves).
// Manual depth-1 software pipelining in every phase: compiler alone allocates 60 VGPR
// and serializes load->MFMA (measured MfmaUtil 6.7%); explicit next-step registers
// force overlap of loads with MFMAs.
__global__ __launch_bounds__(512, 2)
void k_efused(const ushort* __restrict__ Vb,
              const int* __restrict__ src, const int* __restrict__ dst,
              const float* __restrict__ coords, const float* __restrict__ ee,
              const ushort* __restrict__ W1b,   // We1t [128][256]
              const float* __restrict__ We1f, const float* __restrict__ be1,
              const ushort* __restrict__ W2b,   // We2t [128][128]
              const float* __restrict__ be2,
              const ushort* __restrict__ Wxb,   // Wx1t [128][128]
              const float* __restrict__ bx1,
              const ushort* __restrict__ Wx2b,  // Wx2t [16][128]
              const float* __restrict__ bx2,
              ushort* __restrict__ mijb, float4* __restrict__ cd4) {
    __shared__ ushort t1b[4][128][40];
    __shared__ float dd[128], eAa[128], eBb[128];
    __shared__ float d3[3][128];
    const int t = threadIdx.x;
    const int lane = t & 63;
    const int w = t >> 6;
    const int wr = w >> 1, wc = w & 1;
    const int e0 = blockIdx.x * 128;
    const int l15 = lane & 15, lq = lane >> 4;

    // per-lane gather rows (global, no LDS dependency on the address path)
    const int er0 = e0 + wr * 32 + l15;
    const int er1 = er0 + 16;
    const int rS0 = src[er0], rS1 = src[er1];
    const int rD0 = dst[er0], rD1 = dst[er1];

    // prefetch epilogue-A scalars for the 4 columns this thread owns
    float w256[4], w257[4], w258[4], bi1[4];
#pragma unroll
    for (int ni = 0; ni < 4; ++ni) {
        int col = wc * 64 + ni * 16 + l15;
        w256[ni] = We1f[256 * HH + col];
        w257[ni] = We1f[257 * HH + col];
        w258[ni] = We1f[258 * HH + col];
        bi1[ni]  = be1[col];
    }

    if (t < 128) {
        int e = e0 + t;
        int s = src[e], d = dst[e];
        float dx = coords[d * 3 + 0] - coords[s * 3 + 0];
        float dy = coords[d * 3 + 1] - coords[s * 3 + 1];
        float dz = coords[d * 3 + 2] - coords[s * 3 + 2];
        dd[t] = sqrtf(dx * dx + dy * dy + dz * dz);
        d3[0][t] = dx; d3[1][t] = dy; d3[2][t] = dz;
        eAa[t] = ee[2 * e]; eBb[t] = ee[2 * e + 1];
    }

    f32x4 acc[2][4];
#pragma unroll
    for (int i = 0; i < 2; ++i)
#pragma unroll
        for (int j = 0; j < 4; ++j) acc[i][j] = (f32x4){0.f, 0.f, 0.f, 0.f};

    // ---- phase A: K=256 over [V[src] | V[dst]], depth-1 pipelined ----
    const ushort* wb1 = W1b + (size_t)(wc * 64 + l15) * 256 + lq * 8;
    s8b a0 = ldg8(Vb + (size_t)rS0 * HH + lq * 8);
    s8b a1 = ldg8(Vb + (size_t)rS1 * HH + lq * 8);
    s8b b0 = ldg8(wb1);
    s8b b1 = ldg8(wb1 + 16 * 256);
    s8b b2 = ldg8(wb1 + 32 * 256);
    s8b b3 = ldg8(wb1 + 48 * 256);
#pragma unroll
    for (int s = 0; s < 8; ++s) {
        s8b na0, na1, nb0, nb1, nb2, nb3;
        if (s < 7) {
            const int sn = s + 1;
            const int kt = sn & 3;
            const int r0 = (sn < 4) ? rS0 : rD0;
            const int r1 = (sn < 4) ? rS1 : rD1;
            na0 = ldg8(Vb + (size_t)r0 * HH + kt * 32 + lq * 8);
            na1 = ldg8(Vb + (size_t)r1 * HH + kt * 32 + lq * 8);
            nb0 = ldg8(wb1 + sn * 32);
            nb1 = ldg8(wb1 + 16 * 256 + sn * 32);
            nb2 = ldg8(wb1 + 32 * 256 + sn * 32);
            nb3 = ldg8(wb1 + 48 * 256 + sn * 32);
        }
        acc[0][0] = MFMA16(a0, b0, acc[0][0], 0, 0, 0);
        acc[0][1] = MFMA16(a0, b1, acc[0][1], 0, 0, 0);
        acc[0][2] = MFMA16(a0, b2, acc[0][2], 0, 0, 0);
        acc[0][3] = MFMA16(a0, b3, acc[0][3], 0, 0, 0);
        acc[1][0] = MFMA16(a1, b0, acc[1][0], 0, 0, 0);
        acc[1][1] = MFMA16(a1, b1, acc[1][1], 0, 0, 0);
        acc[1][2] = MFMA16(a1, b2, acc[1][2], 0, 0, 0);
        acc[1][3] = MFMA16(a1, b3, acc[1][3], 0, 0, 0);
        if (s < 7) { a0 = na0; a1 = na1; b0 = nb0; b1 = nb1; b2 = nb2; b3 = nb3; }
    }
    __syncthreads();   // dd/eAa/eBb/d3 ready; t1b safe to write
    // ---- epilogue A: rank-1 fixups + bias + silu -> t1 (bf16 LDS) ----
#pragma unroll
    for (int mi = 0; mi < 2; ++mi)
#pragma unroll
        for (int ni = 0; ni < 4; ++ni) {
            int col = wc * 64 + ni * 16 + l15;
            int kt = col >> 5, c = col & 31;
#pragma unroll
            for (int r = 0; r < 4; ++r) {
                int m = wr * 32 + mi * 16 + lq * 4 + r;
                float v = acc[mi][ni][r] + bi1[ni];
                v = fmaf(dd[m], w256[ni], v);
                v = fmaf(eAa[m], w257[ni], v);
                v = fmaf(eBb[m], w258[ni], v);
                t1b[kt][m][c] = f2b(silu_f(v));
                acc[mi][ni][r] = 0.f;
            }
        }
    // prefetch phase-B step-0 weights (independent of t1b) before the barrier
    const ushort* wb2 = W2b + (size_t)(wc * 64 + l15) * 128 + lq * 8;
    b0 = ldg8(wb2);
    b1 = ldg8(wb2 + 16 * 128);
    b2 = ldg8(wb2 + 32 * 128);
    b3 = ldg8(wb2 + 48 * 128);
    __syncthreads();
    // ---- phase B: mij = silu(t1 @ We2 + be2), pipelined ----
#pragma unroll
    for (int kt = 0; kt < 4; ++kt) {
        s8b a0c = *(const s8b*)&t1b[kt][wr * 32 + l15][lq * 8];
        s8b a1c = *(const s8b*)&t1b[kt][wr * 32 + 16 + l15][lq * 8];
        s8b nb0, nb1, nb2, nb3;
        if (kt < 3) {
            nb0 = ldg8(wb2 + (kt + 1) * 32);
            nb1 = ldg8(wb2 + 16 * 128 + (kt + 1) * 32);
            nb2 = ldg8(wb2 + 32 * 128 + (kt + 1) * 32);
            nb3 = ldg8(wb2 + 48 * 128 + (kt + 1) * 32);
        }
        acc[0][0] = MFMA16(a0c, b0, acc[0][0], 0, 0, 0);
        acc[0][1] = MFMA16(a0c, b1, acc[0][1], 0, 0, 0);
        acc[0][2] = MFMA16(a0c, b2, acc[0][2], 0, 0, 0);
        acc[0][3] = MFMA16(a0c, b3, acc[0][3], 0, 0, 0);
        acc[1][0] = MFMA16(a1c, b0, acc[1][0], 0, 0, 0);
        acc[1][1] = MFMA16(a1c, b1, acc[1][1], 0, 0, 0);
        acc[1][2] = MFMA16(a1c, b2, acc[1][2], 0, 0, 0);
        acc[1][3] = MFMA16(a1c, b3, acc[1][3], 0, 0, 0);
        if (kt < 3) { b0 = nb0; b1 = nb1; b2 = nb2; b3 = nb3; }
    }
    __syncthreads();   // all t1 reads done before overwrite
    // ---- epilogue B: mij -> global + LDS ----
#pragma unroll
    for (int mi = 0; mi < 2; ++mi)
#pragma unroll
        for (int ni = 0; ni < 4; ++ni) {
            int col = wc * 64 + ni * 16 + l15;
            float bi = be2[col];
            int kt = col >> 5, c = col & 31;
#pragma unroll
            for (int r = 0; r < 4; ++r) {
                int m = wr * 32 + mi * 16 + lq * 4 + r;
                ushort mv = f2b(silu_f(acc[mi][ni][r] + bi));
                mijb[(size_t)(e0 + m) * HH + col] = mv;
                t1b[kt][m][c] = mv;
                acc[mi][ni][r] = 0.f;
            }
        }
    // prefetch phase-C step-0 weights before the barrier
    const ushort* wbx = Wxb + (size_t)(wc * 64 + l15) * 128 + lq * 8;
    b0 = ldg8(wbx);
    b1 = ldg8(wbx + 16 * 128);
    b2 = ldg8(wbx + 32 * 128);
    b3 = ldg8(wbx + 48 * 128);
    __syncthreads();
    // ---- phase C: t2 = silu(mij @ Wx1 + bx1), pipelined ----
#pragma unroll
    for (int kt = 0; kt < 4; ++kt) {
        s8b a0c = *(const s8b*)&t1b[kt][wr * 32 + l15][lq * 8];
        s8b a1c = *(const s8b*)&t1b[kt][wr * 32 + 16 + l15][lq * 8];
        s8b nb0, nb1, nb2, nb3;
        if (kt < 3) {
            nb0 = ldg8(wbx + (kt + 1) * 32);
            nb1 = ldg8(wbx + 16 * 128 + (kt + 1) * 32);
            nb2 = ldg8(wbx + 32 * 128 + (kt + 1) * 32);
            nb3 = ldg8(wbx + 48 * 128 + (kt + 1) * 32);
        }
        acc[0][0] = MFMA16(a0c, b0, acc[0][0], 0, 0, 0);
        acc[0][1] = MFMA16(a0c, b1, acc[0][1], 0, 0, 0);
        acc[0][2] = MFMA16(a0c, b2, acc[0][2], 0, 0, 0);
        acc[0][3] = MFMA16(a0c, b3, acc[0][3], 0, 0, 0);
        acc[1][0] = MFMA16(a1c, b0, acc[1][0], 0, 0, 0);
        acc[1][1] = MFMA16(a1c, b1, acc[1][1], 0, 0, 0);
        acc[1][2] = MFMA16(a1c, b2, acc[1][2], 0, 0, 0);
        acc[1][3] = MFMA16(a1c, b3, acc[1][3], 0, 0, 0);
        if (kt < 3) { b0 = nb0; b1 = nb1; b2 = nb2; b3 = nb3; }
    }
    __syncthreads();   // mij reads from t1b done
    // ---- epilogue C: t2 -> LDS ----
#pragma unroll
    for (int mi = 0; mi < 2; ++mi)
#pragma unroll
        for (int ni = 0; ni < 4; ++ni) {
            int col = wc * 64 + ni * 16 + l15;
            float bi = bx1[col];
            int kt = col >> 5, c = col & 31;
#pragma unroll
            for (int r = 0; r < 4; ++r) {
                int m = wr * 32 + mi * 16 + lq * 4 + r;
                t1b[kt][m][c] = f2b(silu_f(acc[mi][ni][r] + bi));
            }
        }
    __syncthreads();
    // ---- phase D: px = t2 @ Wx2 + bx2 ; cd4 = diff * px ----
    f32x4 accd = (f32x4){0.f, 0.f, 0.f, 0.f};
#pragma unroll
    for (int kt = 0; kt < 4; ++kt) {
        s8b a = *(const s8b*)&t1b[kt][w * 16 + l15][lq * 8];
        s8b b = ldg8(Wx2b + (size_t)l15 * 128 + kt * 32 + lq * 8);
        accd = MFMA16(a, b, accd, 0, 0, 0);
    }
    if (l15 < 3) {
        float bi = bx2[l15];
#pragma unroll
        for (int r = 0; r < 4; ++r) {
            int row = w * 16 + lq * 4 + r;
            float px = accd[r] + bi;
            ((float*)&cd4[e0 + row])[l15] = d3[l15][row] * px;
        }
    }
}

// ---------------- mi = segment_sum(mij, dst) via CSR gather ----------------
__global__ __launch_bounds__(128)
void k_mi(const ushort* __restrict__ mijb, const int* __restrict__ offs,
          const int* __restrict__ eid, ushort* __restrict__ mib) {
    const int n = blockIdx.x;
    const int t = threadIdx.x;
    const int b = offs[n], e = offs[n + 1];
    float s = 0.f;
    for (int j = b; j < e; ++j)
        s += bf2f(mijb[(size_t)eid[j] * HH + t]);
    mib[(size_t)n * HH + t] = f2b(s);
}

// ---------------- coords += CSR-gather(cd4)/(N-1) ----------------
__global__ void k_coordupd(float* __restrict__ coords, const float4* __restrict__ cd4,
                           const int* __restrict__ offs, const int* __restrict__ eid) {
    int idx = blockIdx.x * blockDim.x + threadIdx.x;
    if (idx >= NN * 3) return;
    int n = idx / 3, c = idx - 3 * n;
    int b = offs[n], e = offs[n + 1];
    float s = 0.f;
    for (int j = b; j < e; ++j)
        s += ((const float*)&cd4[eid[j]])[c];
    coords[idx] += s * (1.f / (NN - 1));
}

// ================= fused node kernel: 32 rows/block -> 313 blocks (was 157: half GPU idle) =================
// 256 thr, 4 waves (2 wr x 2 wc), wave tile 16 rows x 64 cols
__global__ __launch_bounds__(256, 4)
void k_nfused(const ushort* __restrict__ Vb, const ushort* __restrict__ mib,
              const ushort* __restrict__ Whb,   // Wh1t [128][256]
              const float* __restrict__ bh1,
              const ushort* __restrict__ Wgb,   // Wh2t [128][128]
              const float* __restrict__ bh2,
              float* __restrict__ X,
              float* __restrict__ ssum, float* __restrict__ ssq) {
    __shared__ ushort tb[4][32][40];
    const int t = threadIdx.x;
    const int lane = t & 63;
    const int w = t >> 6;
    const int wr = w >> 1, wc = w & 1;
    const int r0 = blockIdx.x * 32;
    const int l15 = lane & 15, lq = lane >> 4;
    int rowA = r0 + wr * 16 + l15;
    if (rowA >= NN) rowA = NN - 1;
    f32x4 acc[4];
#pragma unroll
    for (int j = 0; j < 4; ++j) acc[j] = (f32x4){0.f, 0.f, 0.f, 0.f};

    // phase A: K=256 over [V | mi], depth-1 pipelined
    const ushort* wbh = Whb + (size_t)(wc * 64 + l15) * 256 + lq * 8;
    s8b a0 = ldg8(Vb + (size_t)rowA * HH + lq * 8);
    s8b b0 = ldg8(wbh);
    s8b b1 = ldg8(wbh + 16 * 256);
    s8b b2 = ldg8(wbh + 32 * 256);
    s8b b3 = ldg8(wbh + 48 * 256);
#pragma unroll
    for (int s = 0; s < 8; ++s) {
        s8b na0, nb0, nb1, nb2, nb3;
        if (s < 7) {
            const int sn = s + 1;
            const ushort* Ap = (sn < 4) ? Vb : mib;
            const int k0 = (sn & 3) * 32;
            na0 = ldg8(Ap + (size_t)rowA * HH + k0 + lq * 8);
            nb0 = ldg8(wbh + sn * 32);
            nb1 = ldg8(wbh + 16 * 256 + sn * 32);
            nb2 = ldg8(wbh + 32 * 256 + sn * 32);
            nb3 = ldg8(wbh + 48 * 256 + sn * 32);
        }
        acc[0] = MFMA16(a0, b0, acc[0], 0, 0, 0);
        acc[1] = MFMA16(a0, b1, acc[1], 0, 0, 0);
        acc[2] = MFMA16(a0, b2, acc[2], 0, 0, 0);
        acc[3] = MFMA16(a0, b3, acc[3], 0, 0, 0);
        if (s < 7) { a0 = na0; b0 = nb0; b1 = nb1; b2 = nb2; b3 = nb3; }
    }
    // epilogue A: u -> LDS
#pragma unroll
    for (int ni = 0; ni < 4; ++ni) {
        int col = wc * 64 + ni * 16 + l15;
        float bi = bh1[col];
        int kt = col >> 5, c = col & 31;
#pragma unroll
        for (int r = 0; r < 4; ++r) {
            int m = wr * 16 + lq * 4 + r;
            tb[kt][m][c] = f2b(silu_f(acc[ni][r] + bi));
            acc[ni][r] = 0.f;
        }
    }
    const ushort* wbg = Wgb + (size_t)(wc * 64 + l15) * 128 + lq * 8;
    b0 = ldg8(wbg);
    b1 = ldg8(wbg + 16 * 128);
    b2 = ldg8(wbg + 32 * 128);
    b3 = ldg8(wbg + 48 * 128);
    __syncthreads();
    // phase B: X = elu(u @ Wh2 + bh2), pipelined
#pragma unroll
    for (int kt = 0; kt < 4; ++kt) {
        s8b a = *(const s8b*)&tb[kt][wr * 16 + l15][lq * 8];
        s8b nb0, nb1, nb2, nb3;
        if (kt < 3) {
            nb0 = ldg8(wbg + (kt + 1) * 32);
            nb1 = ldg8(wbg + 16 * 128 + (kt + 1) * 32);
            nb2 = ldg8(wbg + 32 * 128 + (kt + 1) * 32);
            nb3 = ldg8(wbg + 48 * 128 + (kt + 1) * 32);
        }
        acc[0] = MFMA16(a, b0, acc[0], 0, 0, 0);
        acc[1] = MFMA16(a, b1, acc[1], 0, 0, 0);
        acc[2] = MFMA16(a, b2, acc[2], 0, 0, 0);
        acc[3] = MFMA16(a, b3, acc[3], 0, 0, 0);
        if (kt < 3) { b0 = nb0; b1 = nb1; b2 = nb2; b3 = nb3; }
    }
    float s[4] = {0.f, 0.f, 0.f, 0.f}, q[4] = {0.f, 0.f, 0.f, 0.f};
#pragma unroll
    for (int ni = 0; ni < 4; ++ni) {
        int col = wc * 64 + ni * 16 + l15;
        float bi = bh2[col];
#pragma unroll
        for (int r = 0; r < 4; ++r) {
            int m = r0 + wr * 16 + lq * 4 + r;
            float v = elu_f(acc[ni][r] + bi);
            if (m < NN) {
                X[(size_t)m * HH + col] = v;
                s[ni] += v; q[ni] += v * v;
            }
        }
    }
#pragma unroll
    for (int j = 0; j < 4; ++j) {
        s[j] += __shfl_xor(s[j], 16);
        s[j] += __shfl_xor(s[j], 32);
        q[j] += __shfl_xor(q[j], 16);
        q[j] += __shfl_xor(q[j], 32);
    }
    if (lane < 16) {
#pragma unroll
        for (int j = 0; j < 4; ++j) {
            int col = wc * 64 + j * 16 + l15;
            atomicAdd(&ssum[col], s[j]);
            atomicAdd(&ssq[col], q[j]);
        }
    }
}

// ---------------- node batchnorm apply (-> bf16 V or fp32 out) ----------------
__global__ void k_bnorm_nodes(const float* __restrict__ X, const float* __restrict__ ssum,
                              const float* __restrict__ ssq, const float* __restrict__ gam,
                              const float* __restrict__ bet, float* __restrict__ outf,
                              ushort* __restrict__ outb, int writeb) {
    int idx = blockIdx.x * blockDim.x + threadIdx.x;
    if (idx >= NN * HH) return;
    int c = idx & 127;
    float mu = ssum[c] * (1.f / NN);
    float var = ssq[c] * (1.f / NN) - mu * mu;
    float v = fmaf(gam[c] * (X[idx] - mu), rsqrtf(var + EPSBN), bet[c]);
    if (writeb) outb[idx] = f2b(v);
    else        outf[idx] = v;
}

// ---------------- edge stats over elu(mij) (last layer only) ----------------
__global__ __launch_bounds__(256)
void k_estats(const ushort* __restrict__ mijb, float* __restrict__ ssum, float* __restrict__ ssq) {
    const int t = threadIdx.x;
    const int col = t & 127;
    const int half = t >> 7;
    const int rbase = blockIdx.x * 250;
    float s = 0.f, q = 0.f;
    for (int r = rbase + half; r < rbase + 250; r += 2) {
        float x = elu_f(bf2f(mijb[(size_t)r * HH + col]));
        s += x; q += x * x;
    }
    atomicAdd(&ssum[col], s);
    atomicAdd(&ssq[col], q);
}

// ---------------- edge batchnorm apply -> output E ----------------
__global__ void k_bnorm_edges(const ushort* __restrict__ mijb, const float* __restrict__ ssum,
                              const float* __restrict__ ssq, const float* __restrict__ gam,
                              const float* __restrict__ bet, float* __restrict__ out) {
    size_t stride = (size_t)gridDim.x * blockDim.x;
    for (size_t idx = (size_t)blockIdx.x * blockDim.x + threadIdx.x; idx < (size_t)NE * HH; idx += stride) {
        int c = (int)(idx & 127);
        float x = elu_f(bf2f(mijb[idx]));
        float mu = ssum[c] * (1.f / NE);
        float var = ssq[c] * (1.f / NE) - mu * mu;
        out[idx] = fmaf(gam[c] * (x - mu), rsqrtf(var + EPSBN), bet[c]);
    }
}

extern "C" void kernel_launch(void* const* d_in, const int* in_sizes, int n_in,
                              void* d_out, int out_size, void* d_ws, size_t ws_size,
                              hipStream_t stream) {
    (void)in_sizes; (void)n_in; (void)out_size; (void)ws_size;
    const float* emb_nodes = (const float*)d_in[0];
    const float* emb_edges = (const float*)d_in[1];
    const int*   eidx      = (const int*)d_in[2];
    const float* pre_Wn = (const float*)d_in[3];
    const float* pre_bn = (const float*)d_in[4];
    const float* We1 = (const float*)d_in[7];
    const float* be1 = (const float*)d_in[8];
    const float* We2 = (const float*)d_in[9];
    const float* be2 = (const float*)d_in[10];
    const float* Wx1 = (const float*)d_in[11];
    const float* bx1 = (const float*)d_in[12];
    const float* Wx2 = (const float*)d_in[13];
    const float* bx2 = (const float*)d_in[14];
    const float* Wh1 = (const float*)d_in[15];
    const float* bh1 = (const float*)d_in[16];
    const float* Wh2 = (const float*)d_in[17];
    const float* bh2 = (const float*)d_in[18];
    const float* gam_n = (const float*)d_in[19];
    const float* bet_n = (const float*)d_in[20];
    const float* gam_e = (const float*)d_in[21];
    const float* bet_e = (const float*)d_in[22];

    const int* src = eidx;
    const int* dst = eidx + NE;

    // Workspace layout (float offsets); bf16 buffers counted as elems/2 floats.
    float* ws = (float*)d_ws;
    float*   coords = ws;                         // [0, 30000)
    ushort*  Vb     = (ushort*)(ws + 30000);      // [30000, 670000)
    ushort*  mib    = (ushort*)(ws + 670000);     // [670000, 1310000)
    float*   X      = ws + 1310000;               // [1310000, 2590000)
    float4*  cd4    = (float4*)(ws + 2590000);    // [2590000, 3230000)
    ushort*  mijb   = (ushort*)(ws + 3230000);    // [3230000, 13470000)
    float*   statN  = ws + 13470000;              // [3][256]: per-layer sum(128)+sq(128)
    float*   statE  = ws + 13470768;              // [256]
    ushort*  Wb     = (ushort*)(ws + 13471024);   // 344064 ush
    ushort*  Wx2b   = (ushort*)(ws + 13643056);   // 6144 ush
    int*     I0     = (int*)(ws + 13646128);
    int*     deg    = I0;
    int*     offs   = I0 + 10000;
    int*     cur    = I0 + 20001;
    int*     eid    = I0 + 30001;

    float* outV = (float*)d_out;
    float* outE = (float*)d_out + (size_t)NN * HH;

    k_copy<<<(30000 + 255) / 256, 256, 0, stream>>>(emb_nodes, coords, 30000);
    k_vinit<<<(NN * HH + 255) / 256, 256, 0, stream>>>(emb_nodes, pre_Wn, pre_bn, Vb);
    k_wprep<<<1344, 256, 0, stream>>>(We1, We2, Wx1, Wh1, Wh2, Wb);
    k_wx2prep<<<24, 256, 0, stream>>>(Wx2, Wx2b);
    k_zero<<<4, 256, 0, stream>>>(statN, 1024);   // all stat slots (3 node layers + edge)

    k_zero_int<<<(NN + 255) / 256, 256, 0, stream>>>(deg, NN);
    k_hist<<<(NE + 255) / 256, 256, 0, stream>>>(dst, deg);
    k_scan<<<1, 256, 0, stream>>>(deg, offs, cur);
    k_fill<<<(NE + 255) / 256, 256, 0, stream>>>(dst, cur, eid);

    for (int l = 0; l < 3; ++l) {
        const float* We1l = We1 + (size_t)l * 259 * 128;
        const float* be1l = be1 + l * 128;
        const float* be2l = be2 + l * 128;
        const float* bx1l = bx1 + l * 128;
        const float* bx2l = bx2 + l * 3;
        const float* bh1l = bh1 + l * 128;
        const float* bh2l = bh2 + l * 128;
        const size_t L = (size_t)l * 114688;
        const ushort* W1b = Wb + L;              // We1t [128][256]
        const ushort* W2b = Wb + L + 32768;      // We2t [128][128]
        const ushort* Wxb = Wb + L + 49152;      // Wx1t [128][128]
        const ushort* Whb = Wb + L + 65536;      // Wh1t [128][256]
        const ushort* Wgb = Wb + L + 98304;      // Wh2t [128][128]
        const ushort* Wx2bl = Wx2b + (size_t)l * 2048;
        float* snN = statN + (size_t)l * 256;
        float* sqN = snN + 128;

        k_efused<<<NE / 128, 512, 0, stream>>>(Vb, src, dst, coords, emb_edges,
                                               W1b, We1l, be1l, W2b, be2l,
                                               Wxb, bx1l, Wx2bl, bx2l, mijb, cd4);
        k_mi<<<NN, 128, 0, stream>>>(mijb, offs, eid, mib);
        k_coordupd<<<(NN * 3 + 255) / 256, 256, 0, stream>>>(coords, cd4, offs, eid);
        k_nfused<<<(NN + 31) / 32, 256, 0, stream>>>(Vb, mib, Whb, bh1l, Wgb, bh2l, X, snN, sqN);
        k_bnorm_nodes<<<(NN * HH + 255) / 256, 256, 0, stream>>>(X, snN, sqN, gam_n + l * 128,
                                                                 bet_n + l * 128,
                                                                 outV, Vb, (l < 2) ? 1 : 0);
        if (l == 2) {
            k_estats<<<640, 256, 0, stream>>>(mijb, statE, statE + 128);
            k_bnorm_edges<<<4096, 256, 0, stream>>>(mijb, statE, statE + 128,
                                                    gam_e + l * 128, bet_e + l * 128, outE);
        }
    }
}